// Round 7
// baseline (65.840 us; speedup 1.0000x reference)
//
#include <hip/hip_runtime.h>

// IMU preintegration, B=32 batches, F=8192 steps. 3-kernel pipeline:
//  1 k_chunktot : wave=64-step chunk -> chunk quat totals (scratch in outv)
//  2 k_main2    : inline per-WG qpre scan + outq + vel/pos chunk partials (->ws)
//                 + cov composites (Phi 28 + S 45 unique floats per chunk ->ws)
//  3 k_final    : inline per-WG vpscan + final vel/pos emit
//                 + covcomb phase (WGs with wg==0, one per batch) -> 9x9 cov
// d_ws: cov 32*128*73 fl + vp 32*128*8 fl = 1,327,104 bytes.

#define BB 32
#define FF 8192
#define NCH 128
#define SLOT 73
#define GRAV 9.81007f
#define GCOV (0.0032f*0.0032f)
#define ACOV (0.08f*0.08f)

// ws float offsets
#define COV_OFF 0               // 32*128*73 = 299008 floats
#define VP_OFF  299008          // 32*128*8  = 32768 floats
// scratch offset inside outv region (floats)
#define QTOT_SOFF 0

struct Quat { float x, y, z, w; };

__device__ __forceinline__ Quat qmul(const Quat a, const Quat b) {
    Quat r;
    r.x = a.w*b.x + a.x*b.w + a.y*b.z - a.z*b.y;
    r.y = a.w*b.y - a.x*b.z + a.y*b.w + a.z*b.x;
    r.z = a.w*b.z + a.x*b.y - a.y*b.x + a.z*b.w;
    r.w = a.w*b.w - a.x*b.x - a.y*b.y - a.z*b.z;
    return r;
}

__device__ __forceinline__ Quat qshfl_up(const Quat a, int s) {
    Quat r;
    r.x=__shfl_up(a.x,s); r.y=__shfl_up(a.y,s);
    r.z=__shfl_up(a.z,s); r.w=__shfl_up(a.w,s);
    return r;
}

__device__ __forceinline__ Quat qexp3(float px, float py, float pz) {
    float th2 = px*px + py*py + pz*pz;
    float s, w;
    if (th2 < 1e-8f) {
        s = 0.5f - th2 * (1.0f/48.0f);
        w = 1.0f - th2 * 0.125f;
    } else {
        float th = sqrtf(th2);
        s = sinf(0.5f*th) / th;
        w = cosf(0.5f*th);
    }
    Quat q; q.x=px*s; q.y=py*s; q.z=pz*s; q.w=w; return q;
}

__device__ __forceinline__ void quat2mat(const Quat q, float* R) {
    float x=q.x, y=q.y, z=q.z, w=q.w;
    R[0]=1.0f-2.0f*(y*y+z*z); R[1]=2.0f*(x*y-z*w);       R[2]=2.0f*(x*z+y*w);
    R[3]=2.0f*(x*y+z*w);      R[4]=1.0f-2.0f*(x*x+z*z);  R[5]=2.0f*(y*z-x*w);
    R[6]=2.0f*(x*z-y*w);      R[7]=2.0f*(y*z+x*w);       R[8]=1.0f-2.0f*(x*x+y*y);
}

__device__ __forceinline__ void mm_nn(const float* A, const float* B, float* C) {
#pragma unroll
    for (int i=0;i<3;i++)
#pragma unroll
    for (int j=0;j<3;j++)
        C[3*i+j] = A[3*i+0]*B[0+j] + A[3*i+1]*B[3+j] + A[3*i+2]*B[6+j];
}

__device__ __forceinline__ void mm_nt(const float* A, const float* B, float* C) {
#pragma unroll
    for (int i=0;i<3;i++)
#pragma unroll
    for (int j=0;j<3;j++)
        C[3*i+j] = A[3*i+0]*B[3*j+0] + A[3*i+1]*B[3*j+1] + A[3*i+2]*B[3*j+2];
}

// entries (0,0)(0,1)(0,2)(1,1)(1,2)(2,2) of A*B^T
__device__ __forceinline__ void mm_nt_sym(const float* A, const float* B, float* O6) {
    O6[0]=A[0]*B[0]+A[1]*B[1]+A[2]*B[2];
    O6[1]=A[0]*B[3]+A[1]*B[4]+A[2]*B[5];
    O6[2]=A[0]*B[6]+A[1]*B[7]+A[2]*B[8];
    O6[3]=A[3]*B[3]+A[4]*B[4]+A[5]*B[5];
    O6[4]=A[3]*B[6]+A[4]*B[7]+A[5]*B[8];
    O6[5]=A[6]*B[6]+A[7]*B[7]+A[8]*B[8];
}

__device__ __forceinline__ void expand_sym(const float* t, float* M) {
    M[0]=t[0]; M[1]=t[1]; M[2]=t[2];
    M[3]=t[1]; M[4]=t[3]; M[5]=t[4];
    M[6]=t[2]; M[7]=t[4]; M[8]=t[5];
}

// ---------------------------------------------------------------------------
// 1: chunk quaternion totals. wave = one 64-step chunk.
// ---------------------------------------------------------------------------
__global__ __launch_bounds__(256) void k_chunktot(
    const float* __restrict__ dt, const float* __restrict__ gyro,
    float* __restrict__ qtot)
{
    const int bid=blockIdx.x, b=bid>>5, wg=bid&31;
    const int tid=threadIdx.x, lane=tid&63, wid=tid>>6;
    const int c=wg*4+wid;
    const long k=(long)b*FF+(long)c*64+lane;
    float d=dt[k];
    Quat inc=qexp3(gyro[3*k+0]*d, gyro[3*k+1]*d, gyro[3*k+2]*d);
#pragma unroll
    for (int s=1;s<64;s<<=1) {
        Quat p=qshfl_up(inc,s);
        if (lane>=s) inc=qmul(p,inc);
    }
    if (lane==63) {
        float4 o; o.x=inc.x; o.y=inc.y; o.z=inc.z; o.w=inc.w;
        reinterpret_cast<float4*>(qtot)[b*NCH+c]=o;
    }
}

// ---------------------------------------------------------------------------
// 2: main fused kernel. Inline per-WG qpre scan; writes outq, vp partials (ws),
//    cov chunk composites (Phi 28 + S 45 floats per chunk, ws).
// ---------------------------------------------------------------------------
#define RSTR 66
__global__ __launch_bounds__(256) void k_main2(
    const float* __restrict__ dt, const float* __restrict__ gyro,
    const float* __restrict__ acc, const float* __restrict__ qtot,
    float* __restrict__ outq, float* __restrict__ cov, float* __restrict__ vp)
{
    __shared__ float red[4][23][RSTR];   // 24,288 B
    __shared__ float4 qsc[NCH];          // 2,048 B
    __shared__ float4 w0q;
    const int bid=blockIdx.x, b=bid>>5, wg=bid&31;
    const int tid=threadIdx.x, lane=tid&63, wid=tid>>6;
    const int c=wg*4+wid;
    const long k=(long)b*FF+(long)c*64+lane;

    // ---- inline B: scan this batch's 128 chunk totals (threads 0..127) ----
    Quat binc;
    if (tid < NCH) {
        float4 t = reinterpret_cast<const float4*>(qtot)[b*NCH+tid];
        binc.x=t.x; binc.y=t.y; binc.z=t.z; binc.w=t.w;
#pragma unroll
        for (int s=1;s<64;s<<=1) {
            Quat p=qshfl_up(binc,s);
            if (lane>=s) binc=qmul(p,binc);
        }
        if (tid==63) { float4 o; o.x=binc.x;o.y=binc.y;o.z=binc.z;o.w=binc.w; w0q=o; }
    }
    __syncthreads();
    if (tid>=64 && tid<NCH) {
        Quat p; p.x=w0q.x; p.y=w0q.y; p.z=w0q.z; p.w=w0q.w;
        binc = qmul(p, binc);
    }
    if (tid < NCH) { float4 o; o.x=binc.x;o.y=binc.y;o.z=binc.z;o.w=binc.w; qsc[tid]=o; }
    __syncthreads();
    Quat qpre;
    if (c==0) { qpre.x=0.f; qpre.y=0.f; qpre.z=0.f; qpre.w=1.f; }
    else { float4 t=qsc[c-1]; qpre.x=t.x; qpre.y=t.y; qpre.z=t.z; qpre.w=t.w; }

    // ---- per-step pipeline ----
    const float d=dt[k];
    const float wx=gyro[3*k+0]*d, wy=gyro[3*k+1]*d, wz=gyro[3*k+2]*d;
    Quat dq=qexp3(wx,wy,wz);

    Quat qloc=dq;
#pragma unroll
    for (int s=1;s<64;s<<=1) {
        Quat p=qshfl_up(qloc,s);
        if (lane>=s) qloc=qmul(p,qloc);
    }
    Quat qi=qmul(qpre,qloc);
    { float4 o; o.x=qi.x;o.y=qi.y;o.z=qi.z;o.w=qi.w;
      reinterpret_cast<float4*>(outq)[k]=o; }

    Quat ql1=qshfl_up(qloc,1);
    Quat qp = (lane==0) ? qpre : qmul(qpre,ql1);

    float a0=acc[3*k+0]-GRAV*2.0f*(qi.x*qi.z-qi.y*qi.w);
    float a1=acc[3*k+1]-GRAV*2.0f*(qi.y*qi.z+qi.x*qi.w);
    float a2=acc[3*k+2]-GRAV*(1.0f-2.0f*(qi.x*qi.x+qi.y*qi.y));

    float Rp[9]; quat2mat(qp,Rp);
    float s0=(Rp[0]*a0+Rp[1]*a1+Rp[2]*a2)*d;
    float s1=(Rp[3]*a0+Rp[4]*a1+Rp[5]*a2)*d;
    float s2=(Rp[6]*a0+Rp[7]*a1+Rp[8]*a2)*d;

    float td=d, l0=s0, l1=s1, l2=s2;
#pragma unroll
    for (int s=1;s<64;s<<=1) {
        float p3=__shfl_up(td,s), p0=__shfl_up(l0,s), p1=__shfl_up(l1,s), p2=__shfl_up(l2,s);
        if (lane>=s) { td+=p3; l0+=p0; l1+=p1; l2+=p2; }
    }
    float w0=(l0-s0)*d+0.5f*s0*d;
    float w1=(l1-s1)*d+0.5f*s1*d;
    float w2=(l2-s2)*d+0.5f*s2*d;
#pragma unroll
    for (int m=1;m<64;m<<=1) {
        w0+=__shfl_xor(w0,m); w1+=__shfl_xor(w1,m); w2+=__shfl_xor(w2,m);
    }
    if (lane==63) {
        float* vpe=vp+(long)(b*NCH+c)*8;
        vpe[0]=l0; vpe[1]=l1; vpe[2]=l2; vpe[3]=w0; vpe[4]=w1; vpe[5]=w2; vpe[6]=td;
    }

    // ---- covariance composite ----
    float Rd[9]; quat2mat(dq,Rd);
    float D[9];
    D[0]=Rd[0]; D[1]=Rd[3]; D[2]=Rd[6];
    D[3]=Rd[1]; D[4]=Rd[4]; D[5]=Rd[7];
    D[6]=Rd[2]; D[7]=Rd[5]; D[8]=Rd[8];

    float P[9], Q[9];
#pragma unroll
    for (int i=0;i<3;i++) {
        float r0=Rp[3*i+0], r1=Rp[3*i+1], r2=Rp[3*i+2];
        float Ra0 = a2*r1 - a1*r2;
        float Ra1 = a0*r2 - a2*r0;
        float Ra2 = a1*r0 - a0*r1;
        P[3*i+0] = -d*Ra0; P[3*i+1] = -d*Ra1; P[3*i+2] = -d*Ra2;
        Q[3*i+0] = 0.5f*d*P[3*i+0]; Q[3*i+1] = 0.5f*d*P[3*i+1]; Q[3*i+2] = 0.5f*d*P[3*i+2];
    }
    float T = d;

    float th2 = wx*wx + wy*wy + wz*wz;
    float c1, c2;
    if (th2 < 1e-8f) { c1 = 0.5f - th2*(1.0f/24.0f); c2 = (1.0f/6.0f) - th2*(1.0f/120.0f); }
    else { float th = sqrtf(th2); c1 = (1.0f-cosf(th))/th2; c2 = (th - sinf(th))/(th2*th); }
    float J[9];
    {
        float dg = 1.0f - c2*th2;
        J[0]=dg + c2*wx*wx;      J[1]= c1*wz + c2*wx*wy;  J[2]=-c1*wy + c2*wx*wz;
        J[3]=-c1*wz + c2*wx*wy;  J[4]=dg + c2*wy*wy;      J[5]= c1*wx + c2*wy*wz;
        J[6]= c1*wy + c2*wx*wz;  J[7]=-c1*wx + c2*wy*wz;  J[8]=dg + c2*wz*wz;
    }
    float G[9]; mm_nt(J, J, G);
    {
        float gs = GCOV*d*d;
#pragma unroll
        for (int i=0;i<9;i++) G[i] *= gs;
    }
    const float av = ACOV*d*d;
    const float bv = 0.5f*ACOV*d*d*d;
    const float cv = 0.25f*ACOV*d*d*d*d;

    // wave inclusive suffix scan of (D,P,Q,T)
#pragma unroll
    for (int s=1;s<64;s<<=1) {
        float pD[9], pP[9], pQ[9], pT;
#pragma unroll
        for (int i=0;i<9;i++){ pD[i]=__shfl_down(D[i],s); pP[i]=__shfl_down(P[i],s); pQ[i]=__shfl_down(Q[i],s); }
        pT = __shfl_down(T, s);
        if (lane + s < 64) {
            float nD[9], nP[9], nQ[9];
            mm_nn(pD, D, nD); mm_nn(pP, D, nP); mm_nn(pQ, D, nQ);
#pragma unroll
            for (int i=0;i<9;i++){
                float np = nP[i] + P[i];
                float nq = nQ[i] + pT*P[i] + Q[i];
                D[i]=nD[i]; P[i]=np; Q[i]=nq;
            }
            T += pT;
        }
    }
    const long wsbase = ((long)b*NCH + c)*SLOT;
    if (lane==0) {
#pragma unroll
        for (int i=0;i<9;i++){ cov[wsbase+i]=D[i]; cov[wsbase+9+i]=P[i]; cov[wsbase+18+i]=Q[i]; }
        cov[wsbase+27] = T;
    }
    // exclusive suffix shift
    {
        float pD[9], pP[9], pQ[9], pT;
#pragma unroll
        for (int i=0;i<9;i++){ pD[i]=__shfl_down(D[i],1); pP[i]=__shfl_down(P[i],1); pQ[i]=__shfl_down(Q[i],1); }
        pT = __shfl_down(T, 1);
        if (lane==63) {
#pragma unroll
            for (int i=0;i<9;i++){ D[i]=(i%4==0)?1.f:0.f; P[i]=0.f; Q[i]=0.f; }
            T = 0.f;
        } else {
#pragma unroll
            for (int i=0;i<9;i++){ D[i]=pD[i]; P[i]=pP[i]; Q[i]=pQ[i]; }
            T = pT;
        }
    }
    // term = Psi N Psi^T, 45 unique elements:
    //  0-8 Arv | 9-17 Arp | 18-26 Avp | 27-32 Arr(tri) | 33-38 Avv(tri) | 39-44 App(tri)
    float S45[45];
    {
        float M1[9];
        mm_nn(D, G, M1);
        mm_nt_sym(M1, D, S45+27);       // Arr
        mm_nt(M1, P, S45+0);            // Arv
        mm_nt(M1, Q, S45+9);            // Arp
        mm_nn(P, G, M1);
        mm_nt_sym(M1, P, S45+33);       // Avv
        mm_nt(M1, Q, S45+18);           // Avp
        mm_nn(Q, G, M1);
        mm_nt_sym(M1, Q, S45+39);       // App
        S45[33]+=av; S45[36]+=av; S45[38]+=av;
        float vpd = av*T + bv;
        S45[18]+=vpd; S45[22]+=vpd; S45[26]+=vpd;
        float ppd = av*T*T + 2.0f*bv*T + cv;
        S45[39]+=ppd; S45[42]+=ppd; S45[44]+=ppd;
    }

    // per-wave LDS transpose reduction over lanes, two rounds (23 + 22 elems)
#pragma unroll
    for (int e=0;e<23;e++) red[wid][e][lane] = S45[e];
    __syncthreads();
    float r1 = 0.f;
    if (lane < 23) {
        const float* row = &red[wid][lane][0];
        float ax=0.f, ay=0.f;
#pragma unroll
        for (int i=0;i<32;i++) {
            float2 v = reinterpret_cast<const float2*>(row)[i];
            ax += v.x; ay += v.y;
        }
        r1 = ax + ay;
    }
    __syncthreads();
#pragma unroll
    for (int e=0;e<22;e++) red[wid][e][lane] = S45[23+e];
    __syncthreads();
    float r2 = 0.f;
    if (lane < 22) {
        const float* row = &red[wid][lane][0];
        float ax=0.f, ay=0.f;
#pragma unroll
        for (int i=0;i<32;i++) {
            float2 v = reinterpret_cast<const float2*>(row)[i];
            ax += v.x; ay += v.y;
        }
        r2 = ax + ay;
    }
    if (lane < 23) cov[wsbase+28+lane] = r1;
    if (lane < 22) cov[wsbase+28+23+lane] = r2;
}

// ---------------------------------------------------------------------------
// K4 combine math (compact layout). Phi[0..27]=D,P,Q,T.
// S (45): Arv0 Arp9 Avp18 Arr27t Avv33t App39t.
// ---------------------------------------------------------------------------
__device__ __forceinline__ void congr45(const float* Phi, const float* S, float* O)
{
    const float* D=Phi; const float* P=Phi+9; const float* Q=Phi+18; const float T=Phi[27];
    const float* Arv=S+0; const float* Arp=S+9; const float* Avp=S+18;
    float Arr[9], Avv[9], App[9];
    expand_sym(S+27,Arr); expand_sym(S+33,Avv); expand_sym(S+39,App);

    float M1[9], M2[9], M3[9], t1[9], t6[6];
    mm_nn(D,Arr,M1); mm_nn(D,Arv,M2); mm_nn(D,Arp,M3);
    mm_nt_sym(M1, D, O+27);                          // O_rr (tri)
    mm_nt(M1, P, t1);
#pragma unroll
    for (int i=0;i<9;i++) O[0+i] = t1[i] + M2[i];    // O_rv
    mm_nt(M1, Q, t1);
#pragma unroll
    for (int i=0;i<9;i++) O[9+i] = t1[i] + T*M2[i] + M3[i];  // O_rp

    float W1[9], W2[9], W3[9];
    mm_nn(P, Arr, W1);
#pragma unroll
    for (int i=0;i<3;i++)
#pragma unroll
    for (int j=0;j<3;j++) W1[3*i+j] += Arv[3*j+i];
    mm_nn(P, Arv, W2);
#pragma unroll
    for (int i=0;i<9;i++) W2[i] += Avv[i];
    mm_nn(P, Arp, W3);
#pragma unroll
    for (int i=0;i<9;i++) W3[i] += Avp[i];
    mm_nt_sym(W1, P, t6);                            // O_vv (tri)
    O[33+0]=t6[0]+W2[0]; O[33+1]=t6[1]+W2[1]; O[33+2]=t6[2]+W2[2];
    O[33+3]=t6[3]+W2[4]; O[33+4]=t6[4]+W2[5]; O[33+5]=t6[5]+W2[8];
    mm_nt(W1, Q, t1);
#pragma unroll
    for (int i=0;i<9;i++) O[18+i] = t1[i] + T*W2[i] + W3[i];  // O_vp

    float U1[9], U2[9], U3[9];
    mm_nn(Q, Arr, U1);
#pragma unroll
    for (int i=0;i<3;i++)
#pragma unroll
    for (int j=0;j<3;j++) U1[3*i+j] += T*Arv[3*j+i] + Arp[3*j+i];
    mm_nn(Q, Arv, U2);
#pragma unroll
    for (int i=0;i<3;i++)
#pragma unroll
    for (int j=0;j<3;j++) U2[3*i+j] += T*Avv[3*i+j] + Avp[3*j+i];
    mm_nn(Q, Arp, U3);
#pragma unroll
    for (int i=0;i<9;i++) U3[i] += T*Avp[i] + App[i];
    mm_nt_sym(U1, Q, t6);                            // O_pp (tri)
    O[39+0]=t6[0]+T*U2[0]+U3[0]; O[39+1]=t6[1]+T*U2[1]+U3[1]; O[39+2]=t6[2]+T*U2[2]+U3[2];
    O[39+3]=t6[3]+T*U2[4]+U3[4]; O[39+4]=t6[4]+T*U2[5]+U3[5]; O[39+5]=t6[5]+T*U2[8]+U3[8];
}

// ---------------------------------------------------------------------------
// 3: final kernel. Inline per-WG vpscan + vel/pos emit; WGs with wg==0 then
//    run the covcomb phase for their batch.
// ---------------------------------------------------------------------------
__global__ __launch_bounds__(256) void k_final(
    const float* __restrict__ dt, const float* __restrict__ acc,
    const float* __restrict__ q, const float* __restrict__ pos0,
    const float* __restrict__ vel0, const float* __restrict__ vp,
    const float* __restrict__ cov,
    float* __restrict__ outv, float* __restrict__ outp, float* __restrict__ outc)
{
    __shared__ float sh[NCH*SLOT];   // 37,376 B; reused across phases
    const int bid=blockIdx.x, b=bid>>5, wg=bid&31;
    const int tid=threadIdx.x, lane=tid&63, wid=tid>>6;
    const int c=wg*4+wid;
    const long k=(long)b*FF+(long)c*64+lane;

    // ---- inline D: scan this batch's 128 vp partials (threads 0..127) ----
    float* all3a = sh;            // [NCH*3]
    float* all3b = sh + NCH*3;    // [NCH*3]
    float* wt    = sh + NCH*6;    // [3]

    float i0=0.f,i1=0.f,i2=0.f, Td=0.f, Sw0=0.f,Sw1=0.f,Sw2=0.f;
    if (tid < NCH) {
        const float* vpe = vp + (long)(b*NCH+tid)*8;
        i0=vpe[0]; i1=vpe[1]; i2=vpe[2];
        Sw0=vpe[3]; Sw1=vpe[4]; Sw2=vpe[5]; Td=vpe[6];
#pragma unroll
        for (int s=1;s<64;s<<=1) {
            float p0=__shfl_up(i0,s),p1=__shfl_up(i1,s),p2=__shfl_up(i2,s);
            if (lane>=s){ i0+=p0; i1+=p1; i2+=p2; }
        }
        if (tid==63){ wt[0]=i0; wt[1]=i1; wt[2]=i2; }
    }
    __syncthreads();
    if (tid>=64 && tid<NCH){ i0+=wt[0]; i1+=wt[1]; i2+=wt[2]; }
    if (tid<NCH){ all3a[tid*3+0]=i0; all3a[tid*3+1]=i1; all3a[tid*3+2]=i2; }
    __syncthreads();
    float j0=0.f,j1=0.f,j2=0.f;
    if (tid < NCH) {
        float Ve0=(tid==0)?0.f:all3a[(tid-1)*3+0];
        float Ve1=(tid==0)?0.f:all3a[(tid-1)*3+1];
        float Ve2=(tid==0)?0.f:all3a[(tid-1)*3+2];
        j0=Ve0*Td+Sw0; j1=Ve1*Td+Sw1; j2=Ve2*Td+Sw2;
#pragma unroll
        for (int s=1;s<64;s<<=1) {
            float p0=__shfl_up(j0,s),p1=__shfl_up(j1,s),p2=__shfl_up(j2,s);
            if (lane>=s){ j0+=p0; j1+=p1; j2+=p2; }
        }
        if (tid==63){ wt[0]=j0; wt[1]=j1; wt[2]=j2; }
    }
    __syncthreads();
    if (tid>=64 && tid<NCH){ j0+=wt[0]; j1+=wt[1]; j2+=wt[2]; }
    if (tid<NCH){ all3b[tid*3+0]=j0; all3b[tid*3+1]=j1; all3b[tid*3+2]=j2; }
    __syncthreads();

    float V0=(c==0)?0.f:all3a[(c-1)*3+0];
    float V1=(c==0)?0.f:all3a[(c-1)*3+1];
    float V2=(c==0)?0.f:all3a[(c-1)*3+2];
    float P0=(c==0)?0.f:all3b[(c-1)*3+0];
    float P1=(c==0)?0.f:all3b[(c-1)*3+1];
    float P2=(c==0)?0.f:all3b[(c-1)*3+2];

    // ---- E: final vel/pos emit ----
    {
        const float d=dt[k];
        float4 tq=reinterpret_cast<const float4*>(q)[k];
        Quat qi; qi.x=tq.x; qi.y=tq.y; qi.z=tq.z; qi.w=tq.w;

        float a0=acc[3*k+0]-GRAV*2.0f*(qi.x*qi.z-qi.y*qi.w);
        float a1=acc[3*k+1]-GRAV*2.0f*(qi.y*qi.z+qi.x*qi.w);
        float a2=acc[3*k+2]-GRAV*(1.0f-2.0f*(qi.x*qi.x+qi.y*qi.y));

        Quat qp=qshfl_up(qi,1);
        if (lane==0) {
            if (c==0) { qp.x=0.f; qp.y=0.f; qp.z=0.f; qp.w=1.f; }
            else { float4 t2=reinterpret_cast<const float4*>(q)[k-1];
                   qp.x=t2.x; qp.y=t2.y; qp.z=t2.z; qp.w=t2.w; }
        }
        float Rp[9]; quat2mat(qp,Rp);
        float s0=(Rp[0]*a0+Rp[1]*a1+Rp[2]*a2)*d;
        float s1=(Rp[3]*a0+Rp[4]*a1+Rp[5]*a2)*d;
        float s2=(Rp[6]*a0+Rp[7]*a1+Rp[8]*a2)*d;

        float td=d, l0=s0, l1=s1, l2=s2;
#pragma unroll
        for (int s=1;s<64;s<<=1) {
            float p3=__shfl_up(td,s), p0=__shfl_up(l0,s), p1=__shfl_up(l1,s), p2=__shfl_up(l2,s);
            if (lane>=s) { td+=p3; l0+=p0; l1+=p1; l2+=p2; }
        }
        float w0=(l0-s0)*d+0.5f*s0*d;
        float w1=(l1-s1)*d+0.5f*s1*d;
        float w2=(l2-s2)*d+0.5f*s2*d;
        float sw0=w0, sw1=w1, sw2=w2;
#pragma unroll
        for (int s=1;s<64;s<<=1) {
            float p0=__shfl_up(sw0,s),p1=__shfl_up(sw1,s),p2=__shfl_up(sw2,s);
            if (lane>=s){ sw0+=p0; sw1+=p1; sw2+=p2; }
        }

        float v0x=vel0[3*b+0], v0y=vel0[3*b+1], v0z=vel0[3*b+2];
        float p0x=pos0[3*b+0], p0y=pos0[3*b+1], p0z=pos0[3*b+2];

        outv[3*k+0]=v0x+V0+l0;
        outv[3*k+1]=v0y+V1+l1;
        outv[3*k+2]=v0z+V2+l2;
        outp[3*k+0]=p0x+P0+V0*td+sw0;
        outp[3*k+1]=p0y+P1+V1*td+sw1;
        outp[3*k+2]=p0z+P2+V2*td+sw2;
    }

    // ---- covcomb phase: WGs with wg==0 only (WG-uniform branch) ----
    if (wg != 0) return;
    __syncthreads();   // sh reuse fence

    float* cp = sh;
    for (int idx=tid; idx<NCH*SLOT; idx+=256) cp[idx] = cov[(long)b*NCH*SLOT + idx];
    __syncthreads();

    // inclusive suffix scan of the Phi parts
    for (int s=1;s<NCH;s<<=1) {
        float aD[9],aP[9],aQ[9],aT=0.f;
        float bD[9],bP[9],bQ[9],bT=0.f;
        bool own = tid < NCH;
        bool act = own && (tid+s) < NCH;
        if (own) {
#pragma unroll
            for (int i=0;i<9;i++){ bD[i]=cp[tid*SLOT+i]; bP[i]=cp[tid*SLOT+9+i]; bQ[i]=cp[tid*SLOT+18+i]; }
            bT = cp[tid*SLOT+27];
        }
        if (act) {
#pragma unroll
            for (int i=0;i<9;i++){ aD[i]=cp[(tid+s)*SLOT+i]; aP[i]=cp[(tid+s)*SLOT+9+i]; aQ[i]=cp[(tid+s)*SLOT+18+i]; }
            aT = cp[(tid+s)*SLOT+27];
        }
        __syncthreads();
        if (act) {
            float nD[9], nP[9], nQ[9];
            mm_nn(aD, bD, nD); mm_nn(aP, bD, nP); mm_nn(aQ, bD, nQ);
#pragma unroll
            for (int i=0;i<9;i++){
                cp[tid*SLOT+i]    = nD[i];
                cp[tid*SLOT+9+i]  = nP[i] + bP[i];
                cp[tid*SLOT+18+i] = nQ[i] + aT*bP[i] + bQ[i];
            }
            cp[tid*SLOT+27] = aT + bT;
        }
        __syncthreads();
    }

    if (tid < NCH) {
        float Phi[28];
        if (tid < NCH-1) {
#pragma unroll
            for (int i=0;i<28;i++) Phi[i]=cp[(tid+1)*SLOT+i];
        } else {
#pragma unroll
            for (int i=0;i<9;i++){ Phi[i]=(i%4==0)?1.f:0.f; Phi[9+i]=0.f; Phi[18+i]=0.f; }
            Phi[27]=0.f;
        }
        float S[45], O[45];
#pragma unroll
        for (int i=0;i<45;i++) S[i] = cp[tid*SLOT+28+i];
        congr45(Phi, S, O);
#pragma unroll
        for (int i=0;i<45;i++) cp[tid*SLOT+28+i] = O[i];
    }
    __syncthreads();

    // tree sum of the 45-float terms
    for (int s=64;s>0;s>>=1) {
        if (tid < s) {
#pragma unroll
            for (int i=0;i<45;i++) cp[tid*SLOT+28+i] += cp[(tid+s)*SLOT+28+i];
        }
        __syncthreads();
    }

    if (tid < 81) {
        int i = tid/9, j = tid%9;
        int bi = i/3, ii = i%3, bj = j/3, jj = j%3;
        int lo = (ii<jj)?ii:jj, hi = (ii<jj)?jj:ii;
        int tix = (lo==0)?hi:((lo==1)?(2+hi):5);
        const float* S0 = &cp[28];
        float v;
        if      (bi==0 && bj==0) v = S0[27 + tix];        // Arr
        else if (bi==0 && bj==1) v = S0[0  + 3*ii + jj];  // Arv
        else if (bi==0 && bj==2) v = S0[9  + 3*ii + jj];  // Arp
        else if (bi==1 && bj==0) v = S0[0  + 3*jj + ii];  // Arv^T
        else if (bi==1 && bj==1) v = S0[33 + tix];        // Avv
        else if (bi==1 && bj==2) v = S0[18 + 3*ii + jj];  // Avp
        else if (bi==2 && bj==0) v = S0[9  + 3*jj + ii];  // Arp^T
        else if (bi==2 && bj==1) v = S0[18 + 3*jj + ii];  // Avp^T
        else                     v = S0[39 + tix];        // App
        outc[(long)b*81 + tid] = v;
    }
}

// ---------------------------------------------------------------------------
extern "C" void kernel_launch(void* const* d_in, const int* in_sizes, int n_in,
                              void* d_out, int out_size, void* d_ws, size_t ws_size,
                              hipStream_t stream)
{
    const float* dt   = (const float*)d_in[0];
    const float* gyro = (const float*)d_in[1];
    const float* acc  = (const float*)d_in[2];
    const float* pos0 = (const float*)d_in[3];
    const float* vel0 = (const float*)d_in[4];

    float* out  = (float*)d_out;
    float* outq = out;
    float* outv = out  + (long)BB*FF*4;
    float* outp = outv + (long)BB*FF*3;
    float* outc = outp + (long)BB*FF*3;

    float* ws   = (float*)d_ws;           // 1,327,104 bytes used
    float* cov  = ws + COV_OFF;
    float* vp   = ws + VP_OFF;
    float* qtot = outv + QTOT_SOFF;       // consumed by k_main2 before k_final writes outv

    hipLaunchKernelGGL(k_chunktot, dim3(BB*32), dim3(256), 0, stream, dt, gyro, qtot);
    hipLaunchKernelGGL(k_main2,    dim3(BB*32), dim3(256), 0, stream, dt, gyro, acc, qtot, outq, cov, vp);
    hipLaunchKernelGGL(k_final,    dim3(BB*32), dim3(256), 0, stream, dt, acc, outq, pos0, vel0, vp, cov, outv, outp, outc);
}

// Round 8
// 50.327 us; speedup vs baseline: 1.3082x; 1.3082x over previous
//
#include <hip/hip_runtime.h>

// IMU preintegration, B=32 batches, F=8192 steps. 5-kernel pipeline (R6 base):
//  A k_chunktot : wave=64-step chunk -> chunk quat totals      (scratch in outv)
//  B k_qpre     : per-batch exclusive scan of 128 chunk quats  (scratch in outv)
//  C k_main     : outq + vel/pos chunk partials + cov composites
//  D k_vpscan   : per-batch scans of vel/pos chunk partials -> (V,Pp) per chunk
//  E k_merged   : blocks 0-31 = covcomb (one per batch, runs CONCURRENT with
//                 emit blocks 32-1055) -> overlap instead of serial tail.
// d_ws: cov composites 32*128*73 fl + vpre 32*128*8 fl = 1,327,104 bytes.

#define BB 32
#define FF 8192
#define NCH 128
#define SLOT 73
#define GRAV 9.81007f
#define GCOV (0.0032f*0.0032f)
#define ACOV (0.08f*0.08f)

// ws float offsets
#define COV_OFF  0              // 32*128*73 = 299008 floats
#define VPRE_OFF 299008         // 32768 floats
// scratch offsets inside outv region (floats)
#define QTOT_SOFF 0
#define QPRE_SOFF 16384
#define VP_SOFF   32768

struct Quat { float x, y, z, w; };

__device__ __forceinline__ Quat qmul(const Quat a, const Quat b) {
    Quat r;
    r.x = a.w*b.x + a.x*b.w + a.y*b.z - a.z*b.y;
    r.y = a.w*b.y - a.x*b.z + a.y*b.w + a.z*b.x;
    r.z = a.w*b.z + a.x*b.y - a.y*b.x + a.z*b.w;
    r.w = a.w*b.w - a.x*b.x - a.y*b.y - a.z*b.z;
    return r;
}

__device__ __forceinline__ Quat qshfl_up(const Quat a, int s) {
    Quat r;
    r.x=__shfl_up(a.x,s); r.y=__shfl_up(a.y,s);
    r.z=__shfl_up(a.z,s); r.w=__shfl_up(a.w,s);
    return r;
}

__device__ __forceinline__ Quat qexp3(float px, float py, float pz) {
    float th2 = px*px + py*py + pz*pz;
    float s, w;
    if (th2 < 1e-8f) {
        s = 0.5f - th2 * (1.0f/48.0f);
        w = 1.0f - th2 * 0.125f;
    } else {
        float th = sqrtf(th2);
        s = sinf(0.5f*th) / th;
        w = cosf(0.5f*th);
    }
    Quat q; q.x=px*s; q.y=py*s; q.z=pz*s; q.w=w; return q;
}

__device__ __forceinline__ void quat2mat(const Quat q, float* R) {
    float x=q.x, y=q.y, z=q.z, w=q.w;
    R[0]=1.0f-2.0f*(y*y+z*z); R[1]=2.0f*(x*y-z*w);       R[2]=2.0f*(x*z+y*w);
    R[3]=2.0f*(x*y+z*w);      R[4]=1.0f-2.0f*(x*x+z*z);  R[5]=2.0f*(y*z-x*w);
    R[6]=2.0f*(x*z-y*w);      R[7]=2.0f*(y*z+x*w);       R[8]=1.0f-2.0f*(x*x+y*y);
}

__device__ __forceinline__ void mm_nn(const float* A, const float* B, float* C) {
#pragma unroll
    for (int i=0;i<3;i++)
#pragma unroll
    for (int j=0;j<3;j++)
        C[3*i+j] = A[3*i+0]*B[0+j] + A[3*i+1]*B[3+j] + A[3*i+2]*B[6+j];
}

__device__ __forceinline__ void mm_nt(const float* A, const float* B, float* C) {
#pragma unroll
    for (int i=0;i<3;i++)
#pragma unroll
    for (int j=0;j<3;j++)
        C[3*i+j] = A[3*i+0]*B[3*j+0] + A[3*i+1]*B[3*j+1] + A[3*i+2]*B[3*j+2];
}

// entries (0,0)(0,1)(0,2)(1,1)(1,2)(2,2) of A*B^T
__device__ __forceinline__ void mm_nt_sym(const float* A, const float* B, float* O6) {
    O6[0]=A[0]*B[0]+A[1]*B[1]+A[2]*B[2];
    O6[1]=A[0]*B[3]+A[1]*B[4]+A[2]*B[5];
    O6[2]=A[0]*B[6]+A[1]*B[7]+A[2]*B[8];
    O6[3]=A[3]*B[3]+A[4]*B[4]+A[5]*B[5];
    O6[4]=A[3]*B[6]+A[4]*B[7]+A[5]*B[8];
    O6[5]=A[6]*B[6]+A[7]*B[7]+A[8]*B[8];
}

__device__ __forceinline__ void expand_sym(const float* t, float* M) {
    M[0]=t[0]; M[1]=t[1]; M[2]=t[2];
    M[3]=t[1]; M[4]=t[3]; M[5]=t[4];
    M[6]=t[2]; M[7]=t[4]; M[8]=t[5];
}

// ---------------------------------------------------------------------------
// A: chunk quaternion totals. wave = one 64-step chunk.
// ---------------------------------------------------------------------------
__global__ __launch_bounds__(256) void k_chunktot(
    const float* __restrict__ dt, const float* __restrict__ gyro,
    float* __restrict__ scr)
{
    const int bid=blockIdx.x, b=bid>>5, wg=bid&31;
    const int tid=threadIdx.x, lane=tid&63, wid=tid>>6;
    const int c=wg*4+wid;
    const long k=(long)b*FF+(long)c*64+lane;
    float d=dt[k];
    Quat inc=qexp3(gyro[3*k+0]*d, gyro[3*k+1]*d, gyro[3*k+2]*d);
#pragma unroll
    for (int s=1;s<64;s<<=1) {
        Quat p=qshfl_up(inc,s);
        if (lane>=s) inc=qmul(p,inc);
    }
    if (lane==63) {
        float4 o; o.x=inc.x; o.y=inc.y; o.z=inc.z; o.w=inc.w;
        reinterpret_cast<float4*>(scr+QTOT_SOFF)[b*NCH+c]=o;
    }
}

// ---------------------------------------------------------------------------
// B: exclusive scan of 128 chunk quats per batch. 1 WG/batch, 128 threads.
// ---------------------------------------------------------------------------
__global__ __launch_bounds__(128) void k_qpre(float* __restrict__ scr)
{
    const int b=blockIdx.x, c=threadIdx.x, lane=c&63, w=c>>6;
    __shared__ float4 w0t;
    __shared__ float4 all[NCH];
    float4 t=reinterpret_cast<const float4*>(scr+QTOT_SOFF)[b*NCH+c];
    Quat inc; inc.x=t.x; inc.y=t.y; inc.z=t.z; inc.w=t.w;
#pragma unroll
    for (int s=1;s<64;s<<=1) {
        Quat p=qshfl_up(inc,s);
        if (lane>=s) inc=qmul(p,inc);
    }
    if (w==0 && lane==63) { float4 o; o.x=inc.x;o.y=inc.y;o.z=inc.z;o.w=inc.w; w0t=o; }
    __syncthreads();
    if (w==1) { Quat p; p.x=w0t.x;p.y=w0t.y;p.z=w0t.z;p.w=w0t.w; inc=qmul(p,inc); }
    { float4 o; o.x=inc.x;o.y=inc.y;o.z=inc.z;o.w=inc.w; all[c]=o; }
    __syncthreads();
    float4 pre;
    if (c==0) { pre.x=0.f;pre.y=0.f;pre.z=0.f;pre.w=1.f; }
    else pre=all[c-1];
    reinterpret_cast<float4*>(scr+QPRE_SOFF)[b*NCH+c]=pre;
}

// ---------------------------------------------------------------------------
// C: main fused kernel. wave = chunk. Writes outq, vel/pos chunk partials,
//    covariance chunk composites (Phi 28 + S 45 unique floats per chunk).
// ---------------------------------------------------------------------------
#define RSTR 66
__global__ __launch_bounds__(256) void k_main(
    const float* __restrict__ dt, const float* __restrict__ gyro,
    const float* __restrict__ acc, float* __restrict__ scr,
    float* __restrict__ outq, float* __restrict__ cov)
{
    __shared__ float red[4][23][RSTR];   // 24,288 B
    const int bid=blockIdx.x, b=bid>>5, wg=bid&31;
    const int tid=threadIdx.x, lane=tid&63, wid=tid>>6;
    const int c=wg*4+wid;
    const long k=(long)b*FF+(long)c*64+lane;

    const float d=dt[k];
    const float wx=gyro[3*k+0]*d, wy=gyro[3*k+1]*d, wz=gyro[3*k+2]*d;
    Quat dq=qexp3(wx,wy,wz);

    // within-chunk inclusive quat prefix
    Quat qloc=dq;
#pragma unroll
    for (int s=1;s<64;s<<=1) {
        Quat p=qshfl_up(qloc,s);
        if (lane>=s) qloc=qmul(p,qloc);
    }
    float4 tp=reinterpret_cast<const float4*>(scr+QPRE_SOFF)[b*NCH+c];
    Quat qpre; qpre.x=tp.x; qpre.y=tp.y; qpre.z=tp.z; qpre.w=tp.w;
    Quat qi=qmul(qpre,qloc);
    { float4 o; o.x=qi.x;o.y=qi.y;o.z=qi.z;o.w=qi.w;
      reinterpret_cast<float4*>(outq)[k]=o; }

    Quat ql1=qshfl_up(qloc,1);
    Quat qp = (lane==0) ? qpre : qmul(qpre,ql1);

    // a = acc - R(qi)^T g
    float a0=acc[3*k+0]-GRAV*2.0f*(qi.x*qi.z-qi.y*qi.w);
    float a1=acc[3*k+1]-GRAV*2.0f*(qi.y*qi.z+qi.x*qi.w);
    float a2=acc[3*k+2]-GRAV*(1.0f-2.0f*(qi.x*qi.x+qi.y*qi.y));

    float Rp[9]; quat2mat(qp,Rp);
    float s0=(Rp[0]*a0+Rp[1]*a1+Rp[2]*a2)*d;
    float s1=(Rp[3]*a0+Rp[4]*a1+Rp[5]*a2)*d;
    float s2=(Rp[6]*a0+Rp[7]*a1+Rp[8]*a2)*d;

    // chunk vel/pos partials
    float td=d, l0=s0, l1=s1, l2=s2;
#pragma unroll
    for (int s=1;s<64;s<<=1) {
        float p3=__shfl_up(td,s), p0=__shfl_up(l0,s), p1=__shfl_up(l1,s), p2=__shfl_up(l2,s);
        if (lane>=s) { td+=p3; l0+=p0; l1+=p1; l2+=p2; }
    }
    float w0=(l0-s0)*d+0.5f*s0*d;
    float w1=(l1-s1)*d+0.5f*s1*d;
    float w2=(l2-s2)*d+0.5f*s2*d;
#pragma unroll
    for (int m=1;m<64;m<<=1) {
        w0+=__shfl_xor(w0,m); w1+=__shfl_xor(w1,m); w2+=__shfl_xor(w2,m);
    }
    if (lane==63) {
        float* vp=scr+VP_SOFF+(long)(b*NCH+c)*8;
        vp[0]=l0; vp[1]=l1; vp[2]=l2; vp[3]=w0; vp[4]=w1; vp[5]=w2; vp[6]=td;
    }

    // ---- covariance composite ----
    float Rd[9]; quat2mat(dq,Rd);
    float D[9];
    D[0]=Rd[0]; D[1]=Rd[3]; D[2]=Rd[6];
    D[3]=Rd[1]; D[4]=Rd[4]; D[5]=Rd[7];
    D[6]=Rd[2]; D[7]=Rd[5]; D[8]=Rd[8];

    float P[9], Q[9];
#pragma unroll
    for (int i=0;i<3;i++) {
        float r0=Rp[3*i+0], r1=Rp[3*i+1], r2=Rp[3*i+2];
        float Ra0 = a2*r1 - a1*r2;
        float Ra1 = a0*r2 - a2*r0;
        float Ra2 = a1*r0 - a0*r1;
        P[3*i+0] = -d*Ra0; P[3*i+1] = -d*Ra1; P[3*i+2] = -d*Ra2;
        Q[3*i+0] = 0.5f*d*P[3*i+0]; Q[3*i+1] = 0.5f*d*P[3*i+1]; Q[3*i+2] = 0.5f*d*P[3*i+2];
    }
    float T = d;

    float th2 = wx*wx + wy*wy + wz*wz;
    float c1, c2;
    if (th2 < 1e-8f) { c1 = 0.5f - th2*(1.0f/24.0f); c2 = (1.0f/6.0f) - th2*(1.0f/120.0f); }
    else { float th = sqrtf(th2); c1 = (1.0f-cosf(th))/th2; c2 = (th - sinf(th))/(th2*th); }
    float J[9];
    {
        float dg = 1.0f - c2*th2;
        J[0]=dg + c2*wx*wx;      J[1]= c1*wz + c2*wx*wy;  J[2]=-c1*wy + c2*wx*wz;
        J[3]=-c1*wz + c2*wx*wy;  J[4]=dg + c2*wy*wy;      J[5]= c1*wx + c2*wy*wz;
        J[6]= c1*wy + c2*wx*wz;  J[7]=-c1*wx + c2*wy*wz;  J[8]=dg + c2*wz*wz;
    }
    float G[9]; mm_nt(J, J, G);
    {
        float gs = GCOV*d*d;
#pragma unroll
        for (int i=0;i<9;i++) G[i] *= gs;
    }
    const float av = ACOV*d*d;
    const float bv = 0.5f*ACOV*d*d*d;
    const float cv = 0.25f*ACOV*d*d*d*d;

    // wave inclusive suffix scan of (D,P,Q,T)
#pragma unroll
    for (int s=1;s<64;s<<=1) {
        float pD[9], pP[9], pQ[9], pT;
#pragma unroll
        for (int i=0;i<9;i++){ pD[i]=__shfl_down(D[i],s); pP[i]=__shfl_down(P[i],s); pQ[i]=__shfl_down(Q[i],s); }
        pT = __shfl_down(T, s);
        if (lane + s < 64) {
            float nD[9], nP[9], nQ[9];
            mm_nn(pD, D, nD); mm_nn(pP, D, nP); mm_nn(pQ, D, nQ);
#pragma unroll
            for (int i=0;i<9;i++){
                float np = nP[i] + P[i];
                float nq = nQ[i] + pT*P[i] + Q[i];
                D[i]=nD[i]; P[i]=np; Q[i]=nq;
            }
            T += pT;
        }
    }
    const long wsbase = ((long)b*NCH + c)*SLOT;
    if (lane==0) {
#pragma unroll
        for (int i=0;i<9;i++){ cov[wsbase+i]=D[i]; cov[wsbase+9+i]=P[i]; cov[wsbase+18+i]=Q[i]; }
        cov[wsbase+27] = T;
    }
    // exclusive suffix shift
    {
        float pD[9], pP[9], pQ[9], pT;
#pragma unroll
        for (int i=0;i<9;i++){ pD[i]=__shfl_down(D[i],1); pP[i]=__shfl_down(P[i],1); pQ[i]=__shfl_down(Q[i],1); }
        pT = __shfl_down(T, 1);
        if (lane==63) {
#pragma unroll
            for (int i=0;i<9;i++){ D[i]=(i%4==0)?1.f:0.f; P[i]=0.f; Q[i]=0.f; }
            T = 0.f;
        } else {
#pragma unroll
            for (int i=0;i<9;i++){ D[i]=pD[i]; P[i]=pP[i]; Q[i]=pQ[i]; }
            T = pT;
        }
    }
    // term = Psi N Psi^T, 45 unique elements:
    //  0-8 Arv | 9-17 Arp | 18-26 Avp | 27-32 Arr(tri) | 33-38 Avv(tri) | 39-44 App(tri)
    float S45[45];
    {
        float M1[9];
        mm_nn(D, G, M1);
        mm_nt_sym(M1, D, S45+27);       // Arr
        mm_nt(M1, P, S45+0);            // Arv
        mm_nt(M1, Q, S45+9);            // Arp
        mm_nn(P, G, M1);
        mm_nt_sym(M1, P, S45+33);       // Avv
        mm_nt(M1, Q, S45+18);           // Avp
        mm_nn(Q, G, M1);
        mm_nt_sym(M1, Q, S45+39);       // App
        S45[33]+=av; S45[36]+=av; S45[38]+=av;
        float vpd = av*T + bv;
        S45[18]+=vpd; S45[22]+=vpd; S45[26]+=vpd;
        float ppd = av*T*T + 2.0f*bv*T + cv;
        S45[39]+=ppd; S45[42]+=ppd; S45[44]+=ppd;
    }

    // per-wave LDS transpose reduction over lanes, two rounds (23 + 22 elems)
#pragma unroll
    for (int e=0;e<23;e++) red[wid][e][lane] = S45[e];
    __syncthreads();
    float r1 = 0.f;
    if (lane < 23) {
        const float* row = &red[wid][lane][0];
        float ax=0.f, ay=0.f;
#pragma unroll
        for (int i=0;i<32;i++) {
            float2 v = reinterpret_cast<const float2*>(row)[i];
            ax += v.x; ay += v.y;
        }
        r1 = ax + ay;
    }
    __syncthreads();
#pragma unroll
    for (int e=0;e<22;e++) red[wid][e][lane] = S45[23+e];
    __syncthreads();
    float r2 = 0.f;
    if (lane < 22) {
        const float* row = &red[wid][lane][0];
        float ax=0.f, ay=0.f;
#pragma unroll
        for (int i=0;i<32;i++) {
            float2 v = reinterpret_cast<const float2*>(row)[i];
            ax += v.x; ay += v.y;
        }
        r2 = ax + ay;
    }
    if (lane < 23) cov[wsbase+28+lane] = r1;
    if (lane < 22) cov[wsbase+28+23+lane] = r2;
}

// ---------------------------------------------------------------------------
// D: per-batch scans of vel/pos chunk partials -> exclusive (V, Pp) per chunk.
// ---------------------------------------------------------------------------
__global__ __launch_bounds__(128) void k_vpscan(
    const float* __restrict__ scr, float* __restrict__ vpre)
{
    const int b=blockIdx.x, c=threadIdx.x, lane=c&63, w=c>>6;
    __shared__ float w0t[3];
    __shared__ float all3[NCH][3];
    const float* vp=scr+VP_SOFF+(long)(b*NCH+c)*8;
    float Lv0=vp[0],Lv1=vp[1],Lv2=vp[2],Sw0=vp[3],Sw1=vp[4],Sw2=vp[5],Td=vp[6];

    float i0=Lv0,i1=Lv1,i2=Lv2;
#pragma unroll
    for (int s=1;s<64;s<<=1) {
        float p0=__shfl_up(i0,s),p1=__shfl_up(i1,s),p2=__shfl_up(i2,s);
        if (lane>=s){ i0+=p0; i1+=p1; i2+=p2; }
    }
    if (w==0 && lane==63){ w0t[0]=i0; w0t[1]=i1; w0t[2]=i2; }
    __syncthreads();
    if (w==1){ i0+=w0t[0]; i1+=w0t[1]; i2+=w0t[2]; }
    all3[c][0]=i0; all3[c][1]=i1; all3[c][2]=i2;
    __syncthreads();
    float V0=(c==0)?0.f:all3[c-1][0];
    float V1=(c==0)?0.f:all3[c-1][1];
    float V2=(c==0)?0.f:all3[c-1][2];
    __syncthreads();

    float u0=V0*Td+Sw0, u1=V1*Td+Sw1, u2=V2*Td+Sw2;
    i0=u0; i1=u1; i2=u2;
#pragma unroll
    for (int s=1;s<64;s<<=1) {
        float p0=__shfl_up(i0,s),p1=__shfl_up(i1,s),p2=__shfl_up(i2,s);
        if (lane>=s){ i0+=p0; i1+=p1; i2+=p2; }
    }
    if (w==0 && lane==63){ w0t[0]=i0; w0t[1]=i1; w0t[2]=i2; }
    __syncthreads();
    if (w==1){ i0+=w0t[0]; i1+=w0t[1]; i2+=w0t[2]; }
    all3[c][0]=i0; all3[c][1]=i1; all3[c][2]=i2;
    __syncthreads();
    float P0=(c==0)?0.f:all3[c-1][0];
    float P1=(c==0)?0.f:all3[c-1][1];
    float P2=(c==0)?0.f:all3[c-1][2];

    float* o=vpre+(long)(b*NCH+c)*8;
    o[0]=V0; o[1]=V1; o[2]=V2; o[3]=P0; o[4]=P1; o[5]=P2;
}

// ---------------------------------------------------------------------------
// K4 combine math (compact layout). Phi[0..27]=D,P,Q,T.
// S (45): Arv0 Arp9 Avp18 Arr27t Avv33t App39t.
// ---------------------------------------------------------------------------
__device__ __forceinline__ void congr45(const float* Phi, const float* S, float* O)
{
    const float* D=Phi; const float* P=Phi+9; const float* Q=Phi+18; const float T=Phi[27];
    const float* Arv=S+0; const float* Arp=S+9; const float* Avp=S+18;
    float Arr[9], Avv[9], App[9];
    expand_sym(S+27,Arr); expand_sym(S+33,Avv); expand_sym(S+39,App);

    float M1[9], M2[9], M3[9], t1[9], t6[6];
    mm_nn(D,Arr,M1); mm_nn(D,Arv,M2); mm_nn(D,Arp,M3);
    mm_nt_sym(M1, D, O+27);                          // O_rr (tri)
    mm_nt(M1, P, t1);
#pragma unroll
    for (int i=0;i<9;i++) O[0+i] = t1[i] + M2[i];    // O_rv
    mm_nt(M1, Q, t1);
#pragma unroll
    for (int i=0;i<9;i++) O[9+i] = t1[i] + T*M2[i] + M3[i];  // O_rp

    float W1[9], W2[9], W3[9];
    mm_nn(P, Arr, W1);
#pragma unroll
    for (int i=0;i<3;i++)
#pragma unroll
    for (int j=0;j<3;j++) W1[3*i+j] += Arv[3*j+i];
    mm_nn(P, Arv, W2);
#pragma unroll
    for (int i=0;i<9;i++) W2[i] += Avv[i];
    mm_nn(P, Arp, W3);
#pragma unroll
    for (int i=0;i<9;i++) W3[i] += Avp[i];
    mm_nt_sym(W1, P, t6);                            // O_vv (tri)
    O[33+0]=t6[0]+W2[0]; O[33+1]=t6[1]+W2[1]; O[33+2]=t6[2]+W2[2];
    O[33+3]=t6[3]+W2[4]; O[33+4]=t6[4]+W2[5]; O[33+5]=t6[5]+W2[8];
    mm_nt(W1, Q, t1);
#pragma unroll
    for (int i=0;i<9;i++) O[18+i] = t1[i] + T*W2[i] + W3[i];  // O_vp

    float U1[9], U2[9], U3[9];
    mm_nn(Q, Arr, U1);
#pragma unroll
    for (int i=0;i<3;i++)
#pragma unroll
    for (int j=0;j<3;j++) U1[3*i+j] += T*Arv[3*j+i] + Arp[3*j+i];
    mm_nn(Q, Arv, U2);
#pragma unroll
    for (int i=0;i<3;i++)
#pragma unroll
    for (int j=0;j<3;j++) U2[3*i+j] += T*Avv[3*i+j] + Avp[3*j+i];
    mm_nn(Q, Arp, U3);
#pragma unroll
    for (int i=0;i<9;i++) U3[i] += T*Avp[i] + App[i];
    mm_nt_sym(U1, Q, t6);                            // O_pp (tri)
    O[39+0]=t6[0]+T*U2[0]+U3[0]; O[39+1]=t6[1]+T*U2[1]+U3[1]; O[39+2]=t6[2]+T*U2[2]+U3[2];
    O[39+3]=t6[3]+T*U2[4]+U3[4]; O[39+4]=t6[4]+T*U2[5]+U3[5]; O[39+5]=t6[5]+T*U2[8]+U3[8];
}

// ---------------------------------------------------------------------------
// E (merged): blocks 0..31 covcomb (per batch); blocks 32..1055 emit.
// ---------------------------------------------------------------------------
__global__ __launch_bounds__(256) void k_merged(
    const float* __restrict__ dt, const float* __restrict__ acc,
    const float* __restrict__ q, const float* __restrict__ pos0,
    const float* __restrict__ vel0, const float* __restrict__ vpre,
    const float* __restrict__ cov,
    float* __restrict__ outv, float* __restrict__ outp, float* __restrict__ outc)
{
    __shared__ float cp[NCH*SLOT];   // 37,376 B (used by covcomb blocks only)
    const int bid=blockIdx.x;
    const int tid=threadIdx.x, lane=tid&63, wid=tid>>6;

    if (bid < BB) {
        // ---- covcomb for batch b = bid (256-thread port, validated in R7) ----
        const int b = bid;
        for (int idx=tid; idx<NCH*SLOT; idx+=256) cp[idx] = cov[(long)b*NCH*SLOT + idx];
        __syncthreads();

        for (int s=1;s<NCH;s<<=1) {
            float aD[9],aP[9],aQ[9],aT=0.f;
            float bD[9],bP[9],bQ[9],bT=0.f;
            bool own = tid < NCH;
            bool act = own && (tid+s) < NCH;
            if (own) {
#pragma unroll
                for (int i=0;i<9;i++){ bD[i]=cp[tid*SLOT+i]; bP[i]=cp[tid*SLOT+9+i]; bQ[i]=cp[tid*SLOT+18+i]; }
                bT = cp[tid*SLOT+27];
            }
            if (act) {
#pragma unroll
                for (int i=0;i<9;i++){ aD[i]=cp[(tid+s)*SLOT+i]; aP[i]=cp[(tid+s)*SLOT+9+i]; aQ[i]=cp[(tid+s)*SLOT+18+i]; }
                aT = cp[(tid+s)*SLOT+27];
            }
            __syncthreads();
            if (act) {
                float nD[9], nP[9], nQ[9];
                mm_nn(aD, bD, nD); mm_nn(aP, bD, nP); mm_nn(aQ, bD, nQ);
#pragma unroll
                for (int i=0;i<9;i++){
                    cp[tid*SLOT+i]    = nD[i];
                    cp[tid*SLOT+9+i]  = nP[i] + bP[i];
                    cp[tid*SLOT+18+i] = nQ[i] + aT*bP[i] + bQ[i];
                }
                cp[tid*SLOT+27] = aT + bT;
            }
            __syncthreads();
        }

        if (tid < NCH) {
            float Phi[28];
            if (tid < NCH-1) {
#pragma unroll
                for (int i=0;i<28;i++) Phi[i]=cp[(tid+1)*SLOT+i];
            } else {
#pragma unroll
                for (int i=0;i<9;i++){ Phi[i]=(i%4==0)?1.f:0.f; Phi[9+i]=0.f; Phi[18+i]=0.f; }
                Phi[27]=0.f;
            }
            float S[45], O[45];
#pragma unroll
            for (int i=0;i<45;i++) S[i] = cp[tid*SLOT+28+i];
            congr45(Phi, S, O);
#pragma unroll
            for (int i=0;i<45;i++) cp[tid*SLOT+28+i] = O[i];
        }
        __syncthreads();

        for (int s=64;s>0;s>>=1) {
            if (tid < s) {
#pragma unroll
                for (int i=0;i<45;i++) cp[tid*SLOT+28+i] += cp[(tid+s)*SLOT+28+i];
            }
            __syncthreads();
        }

        if (tid < 81) {
            int i = tid/9, j = tid%9;
            int bi = i/3, ii = i%3, bj = j/3, jj = j%3;
            int lo = (ii<jj)?ii:jj, hi = (ii<jj)?jj:ii;
            int tix = (lo==0)?hi:((lo==1)?(2+hi):5);
            const float* S0 = &cp[28];
            float v;
            if      (bi==0 && bj==0) v = S0[27 + tix];        // Arr
            else if (bi==0 && bj==1) v = S0[0  + 3*ii + jj];  // Arv
            else if (bi==0 && bj==2) v = S0[9  + 3*ii + jj];  // Arp
            else if (bi==1 && bj==0) v = S0[0  + 3*jj + ii];  // Arv^T
            else if (bi==1 && bj==1) v = S0[33 + tix];        // Avv
            else if (bi==1 && bj==2) v = S0[18 + 3*ii + jj];  // Avp
            else if (bi==2 && bj==0) v = S0[9  + 3*jj + ii];  // Arp^T
            else if (bi==2 && bj==1) v = S0[18 + 3*jj + ii];  // Avp^T
            else                     v = S0[39 + tix];        // App
            outc[(long)b*81 + tid] = v;
        }
        return;
    }

    // ---- emit (R6 k_emit verbatim, remapped block index) ----
    const int ebid = bid - BB;
    const int b = ebid>>5, wg = ebid&31;
    const int c = wg*4+wid;
    const long k = (long)b*FF+(long)c*64+lane;

    const float d=dt[k];
    float4 tq=reinterpret_cast<const float4*>(q)[k];
    Quat qi; qi.x=tq.x; qi.y=tq.y; qi.z=tq.z; qi.w=tq.w;

    float a0=acc[3*k+0]-GRAV*2.0f*(qi.x*qi.z-qi.y*qi.w);
    float a1=acc[3*k+1]-GRAV*2.0f*(qi.y*qi.z+qi.x*qi.w);
    float a2=acc[3*k+2]-GRAV*(1.0f-2.0f*(qi.x*qi.x+qi.y*qi.y));

    Quat qp=qshfl_up(qi,1);
    if (lane==0) {
        if (c==0) { qp.x=0.f; qp.y=0.f; qp.z=0.f; qp.w=1.f; }
        else { float4 t2=reinterpret_cast<const float4*>(q)[k-1];
               qp.x=t2.x; qp.y=t2.y; qp.z=t2.z; qp.w=t2.w; }
    }
    float Rp[9]; quat2mat(qp,Rp);
    float s0=(Rp[0]*a0+Rp[1]*a1+Rp[2]*a2)*d;
    float s1=(Rp[3]*a0+Rp[4]*a1+Rp[5]*a2)*d;
    float s2=(Rp[6]*a0+Rp[7]*a1+Rp[8]*a2)*d;

    float td=d, l0=s0, l1=s1, l2=s2;
#pragma unroll
    for (int s=1;s<64;s<<=1) {
        float p3=__shfl_up(td,s), p0=__shfl_up(l0,s), p1=__shfl_up(l1,s), p2=__shfl_up(l2,s);
        if (lane>=s) { td+=p3; l0+=p0; l1+=p1; l2+=p2; }
    }
    float w0=(l0-s0)*d+0.5f*s0*d;
    float w1=(l1-s1)*d+0.5f*s1*d;
    float w2=(l2-s2)*d+0.5f*s2*d;
    float sw0=w0, sw1=w1, sw2=w2;
#pragma unroll
    for (int s=1;s<64;s<<=1) {
        float p0=__shfl_up(sw0,s),p1=__shfl_up(sw1,s),p2=__shfl_up(sw2,s);
        if (lane>=s){ sw0+=p0; sw1+=p1; sw2+=p2; }
    }

    const float* vr=vpre+(long)(b*NCH+c)*8;
    float V0=vr[0],V1=vr[1],V2=vr[2],P0=vr[3],P1=vr[4],P2=vr[5];
    float v0x=vel0[3*b+0], v0y=vel0[3*b+1], v0z=vel0[3*b+2];
    float p0x=pos0[3*b+0], p0y=pos0[3*b+1], p0z=pos0[3*b+2];

    outv[3*k+0]=v0x+V0+l0;
    outv[3*k+1]=v0y+V1+l1;
    outv[3*k+2]=v0z+V2+l2;
    outp[3*k+0]=p0x+P0+V0*td+sw0;
    outp[3*k+1]=p0y+P1+V1*td+sw1;
    outp[3*k+2]=p0z+P2+V2*td+sw2;
}

// ---------------------------------------------------------------------------
extern "C" void kernel_launch(void* const* d_in, const int* in_sizes, int n_in,
                              void* d_out, int out_size, void* d_ws, size_t ws_size,
                              hipStream_t stream)
{
    const float* dt   = (const float*)d_in[0];
    const float* gyro = (const float*)d_in[1];
    const float* acc  = (const float*)d_in[2];
    const float* pos0 = (const float*)d_in[3];
    const float* vel0 = (const float*)d_in[4];

    float* out  = (float*)d_out;
    float* outq = out;
    float* outv = out  + (long)BB*FF*4;
    float* outp = outv + (long)BB*FF*3;
    float* outc = outp + (long)BB*FF*3;

    float* ws   = (float*)d_ws;           // 1,327,104 bytes used
    float* cov  = ws + COV_OFF;
    float* vpre = ws + VPRE_OFF;
    float* scr  = outv;                   // staging scratch, consumed before E

    hipLaunchKernelGGL(k_chunktot, dim3(BB*32),    dim3(256), 0, stream, dt, gyro, scr);
    hipLaunchKernelGGL(k_qpre,     dim3(BB),       dim3(128), 0, stream, scr);
    hipLaunchKernelGGL(k_main,     dim3(BB*32),    dim3(256), 0, stream, dt, gyro, acc, scr, outq, cov);
    hipLaunchKernelGGL(k_vpscan,   dim3(BB),       dim3(128), 0, stream, scr, vpre);
    hipLaunchKernelGGL(k_merged,   dim3(BB*32+BB), dim3(256), 0, stream, dt, acc, outq, pos0, vel0, vpre, cov, outv, outp, outc);
}

// Round 9
// 44.925 us; speedup vs baseline: 1.4655x; 1.1203x over previous
//
#include <hip/hip_runtime.h>

// IMU preintegration, B=32 batches, F=8192 steps. 5-kernel pipeline:
//  A k_chunktot : wave=64-step chunk -> chunk quat totals      (scratch in outv)
//  B k_qpre     : per-batch exclusive scan of 128 chunk quats  (scratch in outv)
//  C k_main     : outq + vel/pos chunk partials + cov composites via the
//                 FACTORED form: suffix composites reduce to 3-vector suffix
//                 sums (m, n) + quats; per-lane term = skew-products around
//                 G' = Rj G Rj^T. Outer chunk-constant rotations applied in
//                 covcomb load. ws slot: 45 core sums + 15 params = 60 (pad 61).
//  D k_vpscan   : per-batch scans of vel/pos chunk partials -> (V,Pp) per chunk
//  E k_merged   : blocks 0-31 covcomb (reconstruct Phi/S, then scan/congr/sum),
//                 blocks 32-1055 emit. Concurrent.
// d_ws: cov 32*128*61 fl + vpre 32*128*8 fl = 1,130,496 bytes.

#define BB 32
#define FF 8192
#define NCH 128
#define SLOT 61
#define GRAV 9.81007f
#define GCOV (0.0032f*0.0032f)
#define ACOV (0.08f*0.08f)

// ws float offsets
#define COV_OFF  0              // 32*128*61 = 249856 floats
#define VPRE_OFF 249856         // 32768 floats
// scratch offsets inside outv region (floats)
#define QTOT_SOFF 0
#define QPRE_SOFF 16384
#define VP_SOFF   32768

struct Quat { float x, y, z, w; };

__device__ __forceinline__ Quat qmul(const Quat a, const Quat b) {
    Quat r;
    r.x = a.w*b.x + a.x*b.w + a.y*b.z - a.z*b.y;
    r.y = a.w*b.y - a.x*b.z + a.y*b.w + a.z*b.x;
    r.z = a.w*b.z + a.x*b.y - a.y*b.x + a.z*b.w;
    r.w = a.w*b.w - a.x*b.x - a.y*b.y - a.z*b.z;
    return r;
}

__device__ __forceinline__ Quat qshfl_up(const Quat a, int s) {
    Quat r;
    r.x=__shfl_up(a.x,s); r.y=__shfl_up(a.y,s);
    r.z=__shfl_up(a.z,s); r.w=__shfl_up(a.w,s);
    return r;
}

__device__ __forceinline__ Quat qexp3(float px, float py, float pz) {
    float th2 = px*px + py*py + pz*pz;
    float s, w;
    if (th2 < 1e-8f) {
        s = 0.5f - th2 * (1.0f/48.0f);
        w = 1.0f - th2 * 0.125f;
    } else {
        float th = sqrtf(th2);
        s = sinf(0.5f*th) / th;
        w = cosf(0.5f*th);
    }
    Quat q; q.x=px*s; q.y=py*s; q.z=pz*s; q.w=w; return q;
}

__device__ __forceinline__ void quat2mat(const Quat q, float* R) {
    float x=q.x, y=q.y, z=q.z, w=q.w;
    R[0]=1.0f-2.0f*(y*y+z*z); R[1]=2.0f*(x*y-z*w);       R[2]=2.0f*(x*z+y*w);
    R[3]=2.0f*(x*y+z*w);      R[4]=1.0f-2.0f*(x*x+z*z);  R[5]=2.0f*(y*z-x*w);
    R[6]=2.0f*(x*z-y*w);      R[7]=2.0f*(y*z+x*w);       R[8]=1.0f-2.0f*(x*x+y*y);
}

__device__ __forceinline__ void mm_nn(const float* A, const float* B, float* C) {
#pragma unroll
    for (int i=0;i<3;i++)
#pragma unroll
    for (int j=0;j<3;j++)
        C[3*i+j] = A[3*i+0]*B[0+j] + A[3*i+1]*B[3+j] + A[3*i+2]*B[6+j];
}

__device__ __forceinline__ void mm_nt(const float* A, const float* B, float* C) {
#pragma unroll
    for (int i=0;i<3;i++)
#pragma unroll
    for (int j=0;j<3;j++)
        C[3*i+j] = A[3*i+0]*B[3*j+0] + A[3*i+1]*B[3*j+1] + A[3*i+2]*B[3*j+2];
}

__device__ __forceinline__ void mm_tn(const float* A, const float* B, float* C) {
#pragma unroll
    for (int i=0;i<3;i++)
#pragma unroll
    for (int j=0;j<3;j++)
        C[3*i+j] = A[0+i]*B[0+j] + A[3+i]*B[3+j] + A[6+i]*B[6+j];
}

// entries (0,0)(0,1)(0,2)(1,1)(1,2)(2,2) of A*B^T
__device__ __forceinline__ void mm_nt_sym(const float* A, const float* B, float* O6) {
    O6[0]=A[0]*B[0]+A[1]*B[1]+A[2]*B[2];
    O6[1]=A[0]*B[3]+A[1]*B[4]+A[2]*B[5];
    O6[2]=A[0]*B[6]+A[1]*B[7]+A[2]*B[8];
    O6[3]=A[3]*B[3]+A[4]*B[4]+A[5]*B[5];
    O6[4]=A[3]*B[6]+A[4]*B[7]+A[5]*B[8];
    O6[5]=A[6]*B[6]+A[7]*B[7]+A[8]*B[8];
}

// entries (0,0)(0,1)(0,2)(1,1)(1,2)(2,2) of A*B
__device__ __forceinline__ void mm_nn_sym(const float* A, const float* B, float* O6) {
    O6[0]=A[0]*B[0]+A[1]*B[3]+A[2]*B[6];
    O6[1]=A[0]*B[1]+A[1]*B[4]+A[2]*B[7];
    O6[2]=A[0]*B[2]+A[1]*B[5]+A[2]*B[8];
    O6[3]=A[3]*B[1]+A[4]*B[4]+A[5]*B[7];
    O6[4]=A[3]*B[2]+A[4]*B[5]+A[5]*B[8];
    O6[5]=A[6]*B[2]+A[7]*B[5]+A[8]*B[8];
}

__device__ __forceinline__ void expand_sym(const float* t, float* M) {
    M[0]=t[0]; M[1]=t[1]; M[2]=t[2];
    M[3]=t[1]; M[4]=t[3]; M[5]=t[4];
    M[6]=t[2]; M[7]=t[4]; M[8]=t[5];
}

// C = M * skew(v)
__device__ __forceinline__ void m_skew(const float* M, float v0, float v1, float v2, float* C) {
#pragma unroll
    for (int i=0;i<3;i++) {
        C[3*i+0] = M[3*i+1]*v2 - M[3*i+2]*v1;
        C[3*i+1] = M[3*i+2]*v0 - M[3*i+0]*v2;
        C[3*i+2] = M[3*i+0]*v1 - M[3*i+1]*v0;
    }
}

// C = skew(w) * M
__device__ __forceinline__ void skew_m(float w0, float w1, float w2, const float* M, float* C) {
#pragma unroll
    for (int j=0;j<3;j++) {
        C[0+j] = -w2*M[3+j] + w1*M[6+j];
        C[3+j] =  w2*M[0+j] - w0*M[6+j];
        C[6+j] = -w1*M[0+j] + w0*M[3+j];
    }
}

// ---------------------------------------------------------------------------
// A: chunk quaternion totals. wave = one 64-step chunk.
// ---------------------------------------------------------------------------
__global__ __launch_bounds__(256) void k_chunktot(
    const float* __restrict__ dt, const float* __restrict__ gyro,
    float* __restrict__ scr)
{
    const int bid=blockIdx.x, b=bid>>5, wg=bid&31;
    const int tid=threadIdx.x, lane=tid&63, wid=tid>>6;
    const int c=wg*4+wid;
    const long k=(long)b*FF+(long)c*64+lane;
    float d=dt[k];
    Quat inc=qexp3(gyro[3*k+0]*d, gyro[3*k+1]*d, gyro[3*k+2]*d);
#pragma unroll
    for (int s=1;s<64;s<<=1) {
        Quat p=qshfl_up(inc,s);
        if (lane>=s) inc=qmul(p,inc);
    }
    if (lane==63) {
        float4 o; o.x=inc.x; o.y=inc.y; o.z=inc.z; o.w=inc.w;
        reinterpret_cast<float4*>(scr+QTOT_SOFF)[b*NCH+c]=o;
    }
}

// ---------------------------------------------------------------------------
// B: exclusive scan of 128 chunk quats per batch. 1 WG/batch, 128 threads.
// ---------------------------------------------------------------------------
__global__ __launch_bounds__(128) void k_qpre(float* __restrict__ scr)
{
    const int b=blockIdx.x, c=threadIdx.x, lane=c&63, w=c>>6;
    __shared__ float4 w0t;
    __shared__ float4 all[NCH];
    float4 t=reinterpret_cast<const float4*>(scr+QTOT_SOFF)[b*NCH+c];
    Quat inc; inc.x=t.x; inc.y=t.y; inc.z=t.z; inc.w=t.w;
#pragma unroll
    for (int s=1;s<64;s<<=1) {
        Quat p=qshfl_up(inc,s);
        if (lane>=s) inc=qmul(p,inc);
    }
    if (w==0 && lane==63) { float4 o; o.x=inc.x;o.y=inc.y;o.z=inc.z;o.w=inc.w; w0t=o; }
    __syncthreads();
    if (w==1) { Quat p; p.x=w0t.x;p.y=w0t.y;p.z=w0t.z;p.w=w0t.w; inc=qmul(p,inc); }
    { float4 o; o.x=inc.x;o.y=inc.y;o.z=inc.z;o.w=inc.w; all[c]=o; }
    __syncthreads();
    float4 pre;
    if (c==0) { pre.x=0.f;pre.y=0.f;pre.z=0.f;pre.w=1.f; }
    else pre=all[c-1];
    reinterpret_cast<float4*>(scr+QPRE_SOFF)[b*NCH+c]=pre;
}

// ---------------------------------------------------------------------------
// C: main fused kernel (factored covariance composites).
// ---------------------------------------------------------------------------
#define RSTR 66
__global__ __launch_bounds__(256) void k_main(
    const float* __restrict__ dt, const float* __restrict__ gyro,
    const float* __restrict__ acc, float* __restrict__ scr,
    float* __restrict__ outq, float* __restrict__ cov)
{
    __shared__ float red[4][23][RSTR];   // 24,288 B
    const int bid=blockIdx.x, b=bid>>5, wg=bid&31;
    const int tid=threadIdx.x, lane=tid&63, wid=tid>>6;
    const int c=wg*4+wid;
    const long k=(long)b*FF+(long)c*64+lane;

    const float d=dt[k];
    const float wx=gyro[3*k+0]*d, wy=gyro[3*k+1]*d, wz=gyro[3*k+2]*d;
    Quat dq=qexp3(wx,wy,wz);

    // within-chunk inclusive quat prefix
    Quat qloc=dq;
#pragma unroll
    for (int s=1;s<64;s<<=1) {
        Quat p=qshfl_up(qloc,s);
        if (lane>=s) qloc=qmul(p,qloc);
    }
    float4 tp=reinterpret_cast<const float4*>(scr+QPRE_SOFF)[b*NCH+c];
    Quat qpre; qpre.x=tp.x; qpre.y=tp.y; qpre.z=tp.z; qpre.w=tp.w;
    Quat qi=qmul(qpre,qloc);
    { float4 o; o.x=qi.x;o.y=qi.y;o.z=qi.z;o.w=qi.w;
      reinterpret_cast<float4*>(outq)[k]=o; }

    Quat ql1=qshfl_up(qloc,1);
    if (lane==0) { ql1.x=0.f; ql1.y=0.f; ql1.z=0.f; ql1.w=1.f; }

    // a = acc - R(qi)^T g
    float a0=acc[3*k+0]-GRAV*2.0f*(qi.x*qi.z-qi.y*qi.w);
    float a1=acc[3*k+1]-GRAV*2.0f*(qi.y*qi.z+qi.x*qi.w);
    float a2=acc[3*k+2]-GRAV*(1.0f-2.0f*(qi.x*qi.x+qi.y*qi.y));

    // b = R(qloc_excl) * a ;  m = d*b
    float Rl[9]; quat2mat(ql1,Rl);
    float b0=Rl[0]*a0+Rl[1]*a1+Rl[2]*a2;
    float b1=Rl[3]*a0+Rl[4]*a1+Rl[5]*a2;
    float b2=Rl[6]*a0+Rl[7]*a1+Rl[8]*a2;
    float m0=d*b0, m1=d*b1, m2=d*b2;

    // inclusive prefix scans: td (dt), M (m)
    float td=d, M0=m0, M1=m1, M2=m2;
#pragma unroll
    for (int s=1;s<64;s<<=1) {
        float p3=__shfl_up(td,s), p0=__shfl_up(M0,s), p1=__shfl_up(M1,s), p2=__shfl_up(M2,s);
        if (lane>=s) { td+=p3; M0+=p0; M1+=p1; M2+=p2; }
    }
    float Dtot=__shfl(td,63);
    float tau = Dtot - td;                 // exclusive suffix dt sum
    float cn = 0.5f*d + tau;
    float n0=cn*m0, n1=cn*m1, n2=cn*m2;
    float N0=n0, N1=n1, N2=n2;
#pragma unroll
    for (int s=1;s<64;s<<=1) {
        float p0=__shfl_up(N0,s),p1=__shfl_up(N1,s),p2=__shfl_up(N2,s);
        if (lane>=s){ N0+=p0; N1+=p1; N2+=p2; }
    }
    // u for pos partial: u = (M - 0.5 m) * d  (prefix scan; lane63 = total)
    float u0=(M0-0.5f*m0)*d, u1=(M1-0.5f*m1)*d, u2=(M2-0.5f*m2)*d;
    float U0=u0, U1=u1, U2=u2;
#pragma unroll
    for (int s=1;s<64;s<<=1) {
        float p0=__shfl_up(U0,s),p1=__shfl_up(U1,s),p2=__shfl_up(U2,s);
        if (lane>=s){ U0+=p0; U1+=p1; U2+=p2; }
    }
    float Mt0=__shfl(M0,63), Mt1=__shfl(M1,63), Mt2=__shfl(M2,63);
    float Nt0=__shfl(N0,63), Nt1=__shfl(N1,63), Nt2=__shfl(N2,63);
    float mp0=Mt0-M0, mp1=Mt1-M1, mp2=Mt2-M2;   // m-psi (exclusive suffix)
    float np0=Nt0-N0, np1=Nt1-N1, np2=Nt2-N2;   // n-psi

    const long wsbase=((long)b*NCH+c)*SLOT;
    if (lane==63) {
        float Rp9[9]; quat2mat(qpre,Rp9);
        float* vp=scr+VP_SOFF+(long)(b*NCH+c)*8;
        vp[0]=Rp9[0]*M0+Rp9[1]*M1+Rp9[2]*M2;
        vp[1]=Rp9[3]*M0+Rp9[4]*M1+Rp9[5]*M2;
        vp[2]=Rp9[6]*M0+Rp9[7]*M1+Rp9[8]*M2;
        vp[3]=Rp9[0]*U0+Rp9[1]*U1+Rp9[2]*U2;
        vp[4]=Rp9[3]*U0+Rp9[4]*U1+Rp9[5]*U2;
        vp[5]=Rp9[6]*U0+Rp9[7]*U1+Rp9[8]*U2;
        vp[6]=td;
        // chunk params: qtot (= own qloc), qpre, Mtot, Ntot, Dtot
        cov[wsbase+45]=qloc.x; cov[wsbase+46]=qloc.y; cov[wsbase+47]=qloc.z; cov[wsbase+48]=qloc.w;
        cov[wsbase+49]=qpre.x; cov[wsbase+50]=qpre.y; cov[wsbase+51]=qpre.z; cov[wsbase+52]=qpre.w;
        cov[wsbase+53]=M0; cov[wsbase+54]=M1; cov[wsbase+55]=M2;
        cov[wsbase+56]=N0; cov[wsbase+57]=N1; cov[wsbase+58]=N2;
        cov[wsbase+59]=td;
    }

    // Jr -> G' = Rj * (gs J J^T) * Rj^T  (via H = Rj J)
    float th2 = wx*wx + wy*wy + wz*wz;
    float c1, c2;
    if (th2 < 1e-8f) { c1 = 0.5f - th2*(1.0f/24.0f); c2 = (1.0f/6.0f) - th2*(1.0f/120.0f); }
    else { float th = sqrtf(th2); c1 = (1.0f-cosf(th))/th2; c2 = (th - sinf(th))/(th2*th); }
    float J[9];
    {
        float dg = 1.0f - c2*th2;
        J[0]=dg + c2*wx*wx;      J[1]= c1*wz + c2*wx*wy;  J[2]=-c1*wy + c2*wx*wz;
        J[3]=-c1*wz + c2*wx*wy;  J[4]=dg + c2*wy*wy;      J[5]= c1*wx + c2*wy*wz;
        J[6]= c1*wy + c2*wx*wz;  J[7]=-c1*wx + c2*wy*wz;  J[8]=dg + c2*wz*wz;
    }
    float Rj[9]; quat2mat(qloc,Rj);
    float H[9]; mm_nn(Rj,J,H);
    const float gs = GCOV*d*d;
    float Gp[9];
    Gp[0]=gs*(H[0]*H[0]+H[1]*H[1]+H[2]*H[2]);
    Gp[1]=gs*(H[0]*H[3]+H[1]*H[4]+H[2]*H[5]);
    Gp[2]=gs*(H[0]*H[6]+H[1]*H[7]+H[2]*H[8]);
    Gp[4]=gs*(H[3]*H[3]+H[4]*H[4]+H[5]*H[5]);
    Gp[5]=gs*(H[3]*H[6]+H[4]*H[7]+H[5]*H[8]);
    Gp[8]=gs*(H[6]*H[6]+H[7]*H[7]+H[8]*H[8]);
    Gp[3]=Gp[1]; Gp[6]=Gp[2]; Gp[7]=Gp[5];

    const float av  = ACOV*d*d;
    const float bv  = 0.5f*ACOV*d*d*d;
    const float cv  = 0.25f*ACOV*d*d*d*d;
    const float vpd = av*tau + bv;
    const float ppd = av*tau*tau + 2.0f*bv*tau + cv;

    // core blocks
    float Crv[9], Crp[9], Cvv[9], Cvp[9], Cpp[9];
    m_skew(Gp, mp0,mp1,mp2, Crv);          // G' skew(m-psi)
    m_skew(Gp, np0,np1,np2, Crp);          // G' skew(n-psi)
    skew_m(-mp0,-mp1,-mp2, Crv, Cvv);      // skew(-m) G' skew(m)
    skew_m(-mp0,-mp1,-mp2, Crp, Cvp);
    skew_m(-np0,-np1,-np2, Crp, Cpp);

    float S45[45];
#pragma unroll
    for (int i=0;i<9;i++){ S45[i]=Crv[i]; S45[9+i]=Crp[i]; S45[18+i]=Cvp[i]; }
    S45[18]+=vpd; S45[22]+=vpd; S45[26]+=vpd;
    S45[27]=Gp[0];  S45[28]=Gp[1];  S45[29]=Gp[2];  S45[30]=Gp[4];  S45[31]=Gp[5];  S45[32]=Gp[8];
    S45[33]=Cvv[0]+av; S45[34]=Cvv[1]; S45[35]=Cvv[2]; S45[36]=Cvv[4]+av; S45[37]=Cvv[5]; S45[38]=Cvv[8]+av;
    S45[39]=Cpp[0]+ppd; S45[40]=Cpp[1]; S45[41]=Cpp[2]; S45[42]=Cpp[4]+ppd; S45[43]=Cpp[5]; S45[44]=Cpp[8]+ppd;

    // per-wave LDS transpose reduction over lanes, two rounds (23 + 22 elems)
#pragma unroll
    for (int e=0;e<23;e++) red[wid][e][lane] = S45[e];
    __syncthreads();
    float r1 = 0.f;
    if (lane < 23) {
        const float* row = &red[wid][lane][0];
        float ax=0.f, ay=0.f;
#pragma unroll
        for (int i=0;i<32;i++) {
            float2 v = reinterpret_cast<const float2*>(row)[i];
            ax += v.x; ay += v.y;
        }
        r1 = ax + ay;
    }
    __syncthreads();
#pragma unroll
    for (int e=0;e<22;e++) red[wid][e][lane] = S45[23+e];
    __syncthreads();
    float r2 = 0.f;
    if (lane < 22) {
        const float* row = &red[wid][lane][0];
        float ax=0.f, ay=0.f;
#pragma unroll
        for (int i=0;i<32;i++) {
            float2 v = reinterpret_cast<const float2*>(row)[i];
            ax += v.x; ay += v.y;
        }
        r2 = ax + ay;
    }
    if (lane < 23) cov[wsbase+lane] = r1;
    if (lane < 22) cov[wsbase+23+lane] = r2;
}

// ---------------------------------------------------------------------------
// D: per-batch scans of vel/pos chunk partials -> exclusive (V, Pp) per chunk.
// ---------------------------------------------------------------------------
__global__ __launch_bounds__(128) void k_vpscan(
    const float* __restrict__ scr, float* __restrict__ vpre)
{
    const int b=blockIdx.x, c=threadIdx.x, lane=c&63, w=c>>6;
    __shared__ float w0t[3];
    __shared__ float all3[NCH][3];
    const float* vp=scr+VP_SOFF+(long)(b*NCH+c)*8;
    float Lv0=vp[0],Lv1=vp[1],Lv2=vp[2],Sw0=vp[3],Sw1=vp[4],Sw2=vp[5],Td=vp[6];

    float i0=Lv0,i1=Lv1,i2=Lv2;
#pragma unroll
    for (int s=1;s<64;s<<=1) {
        float p0=__shfl_up(i0,s),p1=__shfl_up(i1,s),p2=__shfl_up(i2,s);
        if (lane>=s){ i0+=p0; i1+=p1; i2+=p2; }
    }
    if (w==0 && lane==63){ w0t[0]=i0; w0t[1]=i1; w0t[2]=i2; }
    __syncthreads();
    if (w==1){ i0+=w0t[0]; i1+=w0t[1]; i2+=w0t[2]; }
    all3[c][0]=i0; all3[c][1]=i1; all3[c][2]=i2;
    __syncthreads();
    float V0=(c==0)?0.f:all3[c-1][0];
    float V1=(c==0)?0.f:all3[c-1][1];
    float V2=(c==0)?0.f:all3[c-1][2];
    __syncthreads();

    float u0=V0*Td+Sw0, u1=V1*Td+Sw1, u2=V2*Td+Sw2;
    i0=u0; i1=u1; i2=u2;
#pragma unroll
    for (int s=1;s<64;s<<=1) {
        float p0=__shfl_up(i0,s),p1=__shfl_up(i1,s),p2=__shfl_up(i2,s);
        if (lane>=s){ i0+=p0; i1+=p1; i2+=p2; }
    }
    if (w==0 && lane==63){ w0t[0]=i0; w0t[1]=i1; w0t[2]=i2; }
    __syncthreads();
    if (w==1){ i0+=w0t[0]; i1+=w0t[1]; i2+=w0t[2]; }
    all3[c][0]=i0; all3[c][1]=i1; all3[c][2]=i2;
    __syncthreads();
    float P0=(c==0)?0.f:all3[c-1][0];
    float P1=(c==0)?0.f:all3[c-1][1];
    float P2=(c==0)?0.f:all3[c-1][2];

    float* o=vpre+(long)(b*NCH+c)*8;
    o[0]=V0; o[1]=V1; o[2]=V2; o[3]=P0; o[4]=P1; o[5]=P2;
}

// ---------------------------------------------------------------------------
// K4 combine math (compact layout). Phi[0..27]=D,P,Q,T.
// S (45): Arv0 Arp9 Avp18 Arr27t Avv33t App39t.
// ---------------------------------------------------------------------------
__device__ __forceinline__ void congr45(const float* Phi, const float* S, float* O)
{
    const float* D=Phi; const float* P=Phi+9; const float* Q=Phi+18; const float T=Phi[27];
    const float* Arv=S+0; const float* Arp=S+9; const float* Avp=S+18;
    float Arr[9], Avv[9], App[9];
    expand_sym(S+27,Arr); expand_sym(S+33,Avv); expand_sym(S+39,App);

    float M1[9], M2[9], M3[9], t1[9], t6[6];
    mm_nn(D,Arr,M1); mm_nn(D,Arv,M2); mm_nn(D,Arp,M3);
    mm_nt_sym(M1, D, O+27);                          // O_rr (tri)
    mm_nt(M1, P, t1);
#pragma unroll
    for (int i=0;i<9;i++) O[0+i] = t1[i] + M2[i];    // O_rv
    mm_nt(M1, Q, t1);
#pragma unroll
    for (int i=0;i<9;i++) O[9+i] = t1[i] + T*M2[i] + M3[i];  // O_rp

    float W1[9], W2[9], W3[9];
    mm_nn(P, Arr, W1);
#pragma unroll
    for (int i=0;i<3;i++)
#pragma unroll
    for (int j=0;j<3;j++) W1[3*i+j] += Arv[3*j+i];
    mm_nn(P, Arv, W2);
#pragma unroll
    for (int i=0;i<9;i++) W2[i] += Avv[i];
    mm_nn(P, Arp, W3);
#pragma unroll
    for (int i=0;i<9;i++) W3[i] += Avp[i];
    mm_nt_sym(W1, P, t6);                            // O_vv (tri)
    O[33+0]=t6[0]+W2[0]; O[33+1]=t6[1]+W2[1]; O[33+2]=t6[2]+W2[2];
    O[33+3]=t6[3]+W2[4]; O[33+4]=t6[4]+W2[5]; O[33+5]=t6[5]+W2[8];
    mm_nt(W1, Q, t1);
#pragma unroll
    for (int i=0;i<9;i++) O[18+i] = t1[i] + T*W2[i] + W3[i];  // O_vp

    float U1[9], U2[9], U3[9];
    mm_nn(Q, Arr, U1);
#pragma unroll
    for (int i=0;i<3;i++)
#pragma unroll
    for (int j=0;j<3;j++) U1[3*i+j] += T*Arv[3*j+i] + Arp[3*j+i];
    mm_nn(Q, Arv, U2);
#pragma unroll
    for (int i=0;i<3;i++)
#pragma unroll
    for (int j=0;j<3;j++) U2[3*i+j] += T*Avv[3*i+j] + Avp[3*j+i];
    mm_nn(Q, Arp, U3);
#pragma unroll
    for (int i=0;i<9;i++) U3[i] += T*Avp[i] + App[i];
    mm_nt_sym(U1, Q, t6);                            // O_pp (tri)
    O[39+0]=t6[0]+T*U2[0]+U3[0]; O[39+1]=t6[1]+T*U2[1]+U3[1]; O[39+2]=t6[2]+T*U2[2]+U3[2];
    O[39+3]=t6[3]+T*U2[4]+U3[4]; O[39+4]=t6[4]+T*U2[5]+U3[5]; O[39+5]=t6[5]+T*U2[8]+U3[8];
}

// ---------------------------------------------------------------------------
// E (merged): blocks 0..31 covcomb (per batch); blocks 32..1055 emit.
// ---------------------------------------------------------------------------
__global__ __launch_bounds__(256) void k_merged(
    const float* __restrict__ dt, const float* __restrict__ acc,
    const float* __restrict__ q, const float* __restrict__ pos0,
    const float* __restrict__ vel0, const float* __restrict__ vpre,
    const float* __restrict__ cov,
    float* __restrict__ outv, float* __restrict__ outp, float* __restrict__ outc)
{
    __shared__ float cp[NCH*73];     // 37,376 B (covcomb blocks only)
    const int bid=blockIdx.x;
    const int tid=threadIdx.x, lane=tid&63, wid=tid>>6;

    if (bid < BB) {
        const int b = bid;
        // ---- load + reconstruct Phi/S from compact 61-slot ----
        if (tid < NCH) {
            const float* g = cov + (long)b*NCH*SLOT + (long)tid*SLOT;
            float Crv[9],Crp[9],Cvp9[9];
            float Crr6[6],Cvv6[6],Cpp6[6];
#pragma unroll
            for (int i=0;i<9;i++){ Crv[i]=g[i]; Crp[i]=g[9+i]; Cvp9[i]=g[18+i]; }
#pragma unroll
            for (int i=0;i<6;i++){ Crr6[i]=g[27+i]; Cvv6[i]=g[33+i]; Cpp6[i]=g[39+i]; }
            Quat qt; qt.x=g[45]; qt.y=g[46]; qt.z=g[47]; qt.w=g[48];
            Quat qp; qp.x=g[49]; qp.y=g[50]; qp.z=g[51]; qp.w=g[52];
            float Mt0=g[53],Mt1=g[54],Mt2=g[55];
            float Nt0=g[56],Nt1=g[57],Nt2=g[58];
            float Tt=g[59];
            float Rt[9]; quat2mat(qt,Rt);
            float Rp[9]; quat2mat(qp,Rp);

            float* slot = &cp[tid*73];
            // Phi: D = Rt^T, P = Rp skew(-Mt), Q = Rp skew(-Nt), T
            slot[0]=Rt[0]; slot[1]=Rt[3]; slot[2]=Rt[6];
            slot[3]=Rt[1]; slot[4]=Rt[4]; slot[5]=Rt[7];
            slot[6]=Rt[2]; slot[7]=Rt[5]; slot[8]=Rt[8];
            float Pc[9]; m_skew(Rp, -Mt0,-Mt1,-Mt2, Pc);
            float Qc[9]; m_skew(Rp, -Nt0,-Nt1,-Nt2, Qc);
#pragma unroll
            for (int i=0;i<9;i++){ slot[9+i]=Pc[i]; slot[18+i]=Qc[i]; }
            slot[27]=Tt;
            // S blocks with outer rotations
            float t9[9], o9[9], e9[9], o6[6];
            mm_tn(Rt, Crv, t9); mm_nt(t9, Rp, o9);      // Arv
#pragma unroll
            for (int i=0;i<9;i++) slot[28+i]=o9[i];
            mm_tn(Rt, Crp, t9); mm_nt(t9, Rp, o9);      // Arp
#pragma unroll
            for (int i=0;i<9;i++) slot[28+9+i]=o9[i];
            mm_nn(Rp, Cvp9, t9); mm_nt(t9, Rp, o9);     // Avp
#pragma unroll
            for (int i=0;i<9;i++) slot[28+18+i]=o9[i];
            expand_sym(Crr6, e9); mm_tn(Rt, e9, t9); mm_nn_sym(t9, Rt, o6);  // Arr tri
#pragma unroll
            for (int i=0;i<6;i++) slot[28+27+i]=o6[i];
            expand_sym(Cvv6, e9); mm_nn(Rp, e9, t9); mm_nt_sym(t9, Rp, o6);  // Avv tri
#pragma unroll
            for (int i=0;i<6;i++) slot[28+33+i]=o6[i];
            expand_sym(Cpp6, e9); mm_nn(Rp, e9, t9); mm_nt_sym(t9, Rp, o6);  // App tri
#pragma unroll
            for (int i=0;i<6;i++) slot[28+39+i]=o6[i];
        }
        __syncthreads();

        // ---- inclusive suffix scan of Phi parts (73-stride LDS) ----
        for (int s=1;s<NCH;s<<=1) {
            float aD[9],aP[9],aQ[9],aT=0.f;
            float bD[9],bP[9],bQ[9],bT=0.f;
            bool own = tid < NCH;
            bool act = own && (tid+s) < NCH;
            if (own) {
#pragma unroll
                for (int i=0;i<9;i++){ bD[i]=cp[tid*73+i]; bP[i]=cp[tid*73+9+i]; bQ[i]=cp[tid*73+18+i]; }
                bT = cp[tid*73+27];
            }
            if (act) {
#pragma unroll
                for (int i=0;i<9;i++){ aD[i]=cp[(tid+s)*73+i]; aP[i]=cp[(tid+s)*73+9+i]; aQ[i]=cp[(tid+s)*73+18+i]; }
                aT = cp[(tid+s)*73+27];
            }
            __syncthreads();
            if (act) {
                float nD[9], nP[9], nQ[9];
                mm_nn(aD, bD, nD); mm_nn(aP, bD, nP); mm_nn(aQ, bD, nQ);
#pragma unroll
                for (int i=0;i<9;i++){
                    cp[tid*73+i]    = nD[i];
                    cp[tid*73+9+i]  = nP[i] + bP[i];
                    cp[tid*73+18+i] = nQ[i] + aT*bP[i] + bQ[i];
                }
                cp[tid*73+27] = aT + bT;
            }
            __syncthreads();
        }

        if (tid < NCH) {
            float Phi[28];
            if (tid < NCH-1) {
#pragma unroll
                for (int i=0;i<28;i++) Phi[i]=cp[(tid+1)*73+i];
            } else {
#pragma unroll
                for (int i=0;i<9;i++){ Phi[i]=(i%4==0)?1.f:0.f; Phi[9+i]=0.f; Phi[18+i]=0.f; }
                Phi[27]=0.f;
            }
            float S[45], O[45];
#pragma unroll
            for (int i=0;i<45;i++) S[i] = cp[tid*73+28+i];
            congr45(Phi, S, O);
#pragma unroll
            for (int i=0;i<45;i++) cp[tid*73+28+i] = O[i];
        }
        __syncthreads();

        for (int s=64;s>0;s>>=1) {
            if (tid < s) {
#pragma unroll
                for (int i=0;i<45;i++) cp[tid*73+28+i] += cp[(tid+s)*73+28+i];
            }
            __syncthreads();
        }

        if (tid < 81) {
            int i = tid/9, j = tid%9;
            int bi = i/3, ii = i%3, bj = j/3, jj = j%3;
            int lo = (ii<jj)?ii:jj, hi = (ii<jj)?jj:ii;
            int tix = (lo==0)?hi:((lo==1)?(2+hi):5);
            const float* S0 = &cp[28];
            float v;
            if      (bi==0 && bj==0) v = S0[27 + tix];        // Arr
            else if (bi==0 && bj==1) v = S0[0  + 3*ii + jj];  // Arv
            else if (bi==0 && bj==2) v = S0[9  + 3*ii + jj];  // Arp
            else if (bi==1 && bj==0) v = S0[0  + 3*jj + ii];  // Arv^T
            else if (bi==1 && bj==1) v = S0[33 + tix];        // Avv
            else if (bi==1 && bj==2) v = S0[18 + 3*ii + jj];  // Avp
            else if (bi==2 && bj==0) v = S0[9  + 3*jj + ii];  // Arp^T
            else if (bi==2 && bj==1) v = S0[18 + 3*jj + ii];  // Avp^T
            else                     v = S0[39 + tix];        // App
            outc[(long)b*81 + tid] = v;
        }
        return;
    }

    // ---- emit (unchanged) ----
    const int ebid = bid - BB;
    const int b = ebid>>5, wg = ebid&31;
    const int c = wg*4+wid;
    const long k = (long)b*FF+(long)c*64+lane;

    const float d=dt[k];
    float4 tq=reinterpret_cast<const float4*>(q)[k];
    Quat qi; qi.x=tq.x; qi.y=tq.y; qi.z=tq.z; qi.w=tq.w;

    float a0=acc[3*k+0]-GRAV*2.0f*(qi.x*qi.z-qi.y*qi.w);
    float a1=acc[3*k+1]-GRAV*2.0f*(qi.y*qi.z+qi.x*qi.w);
    float a2=acc[3*k+2]-GRAV*(1.0f-2.0f*(qi.x*qi.x+qi.y*qi.y));

    Quat qp=qshfl_up(qi,1);
    if (lane==0) {
        if (c==0) { qp.x=0.f; qp.y=0.f; qp.z=0.f; qp.w=1.f; }
        else { float4 t2=reinterpret_cast<const float4*>(q)[k-1];
               qp.x=t2.x; qp.y=t2.y; qp.z=t2.z; qp.w=t2.w; }
    }
    float Rp[9]; quat2mat(qp,Rp);
    float s0=(Rp[0]*a0+Rp[1]*a1+Rp[2]*a2)*d;
    float s1=(Rp[3]*a0+Rp[4]*a1+Rp[5]*a2)*d;
    float s2=(Rp[6]*a0+Rp[7]*a1+Rp[8]*a2)*d;

    float td=d, l0=s0, l1=s1, l2=s2;
#pragma unroll
    for (int s=1;s<64;s<<=1) {
        float p3=__shfl_up(td,s), p0=__shfl_up(l0,s), p1=__shfl_up(l1,s), p2=__shfl_up(l2,s);
        if (lane>=s) { td+=p3; l0+=p0; l1+=p1; l2+=p2; }
    }
    float w0=(l0-s0)*d+0.5f*s0*d;
    float w1=(l1-s1)*d+0.5f*s1*d;
    float w2=(l2-s2)*d+0.5f*s2*d;
    float sw0=w0, sw1=w1, sw2=w2;
#pragma unroll
    for (int s=1;s<64;s<<=1) {
        float p0=__shfl_up(sw0,s),p1=__shfl_up(sw1,s),p2=__shfl_up(sw2,s);
        if (lane>=s){ sw0+=p0; sw1+=p1; sw2+=p2; }
    }

    const float* vr=vpre+(long)(b*NCH+c)*8;
    float V0=vr[0],V1=vr[1],V2=vr[2],P0=vr[3],P1=vr[4],P2=vr[5];
    float v0x=vel0[3*b+0], v0y=vel0[3*b+1], v0z=vel0[3*b+2];
    float p0x=pos0[3*b+0], p0y=pos0[3*b+1], p0z=pos0[3*b+2];

    outv[3*k+0]=v0x+V0+l0;
    outv[3*k+1]=v0y+V1+l1;
    outv[3*k+2]=v0z+V2+l2;
    outp[3*k+0]=p0x+P0+V0*td+sw0;
    outp[3*k+1]=p0y+P1+V1*td+sw1;
    outp[3*k+2]=p0z+P2+V2*td+sw2;
}

// ---------------------------------------------------------------------------
extern "C" void kernel_launch(void* const* d_in, const int* in_sizes, int n_in,
                              void* d_out, int out_size, void* d_ws, size_t ws_size,
                              hipStream_t stream)
{
    const float* dt   = (const float*)d_in[0];
    const float* gyro = (const float*)d_in[1];
    const float* acc  = (const float*)d_in[2];
    const float* pos0 = (const float*)d_in[3];
    const float* vel0 = (const float*)d_in[4];

    float* out  = (float*)d_out;
    float* outq = out;
    float* outv = out  + (long)BB*FF*4;
    float* outp = outv + (long)BB*FF*3;
    float* outc = outp + (long)BB*FF*3;

    float* ws   = (float*)d_ws;           // 1,130,496 bytes used
    float* cov  = ws + COV_OFF;
    float* vpre = ws + VPRE_OFF;
    float* scr  = outv;                   // staging scratch, consumed before E

    hipLaunchKernelGGL(k_chunktot, dim3(BB*32),    dim3(256), 0, stream, dt, gyro, scr);
    hipLaunchKernelGGL(k_qpre,     dim3(BB),       dim3(128), 0, stream, scr);
    hipLaunchKernelGGL(k_main,     dim3(BB*32),    dim3(256), 0, stream, dt, gyro, acc, scr, outq, cov);
    hipLaunchKernelGGL(k_vpscan,   dim3(BB),       dim3(128), 0, stream, scr, vpre);
    hipLaunchKernelGGL(k_merged,   dim3(BB*32+BB), dim3(256), 0, stream, dt, acc, outq, pos0, vel0, vpre, cov, outv, outp, outc);
}

// Round 10
// 40.589 us; speedup vs baseline: 1.6221x; 1.1068x over previous
//
#include <hip/hip_runtime.h>

// IMU preintegration, B=32 batches, F=8192 steps. 5-kernel pipeline:
//  A k_chunktot : wave=64-step chunk -> chunk quat totals          (ws)
//  B k_qpre     : per-batch exclusive scan of 128 chunk quats      (ws)
//  C k_main     : outq + PARTIAL outv/outp (R(qpre)*M, R(qpre)*U) +
//                 vel/pos chunk partials (ws) + factored cov composites (ws)
//  D k_vpscan   : per-batch scans of chunk partials -> (V,Pp) per chunk
//  E k_merged   : blocks 0-31 covcomb (SCALAR-factored Phi scan) ;
//                 blocks 32-1055 feather-weight emit (RMW of partials).
// d_ws: cov 32*128*61 + vpre 32*128*8 + qtot 16384 + qpre 16384 + vp 32768
//       = 348160 floats = 1,392,640 bytes.

#define BB 32
#define FF 8192
#define NCH 128
#define SLOT 61
#define GRAV 9.81007f
#define GCOV (0.0032f*0.0032f)
#define ACOV (0.08f*0.08f)

// ws float offsets
#define COV_OFF  0
#define VPRE_OFF 249856
#define QTOT_OFF 282624
#define QPRE_OFF 299008
#define VP_OFF   315392

struct Quat { float x, y, z, w; };

__device__ __forceinline__ Quat qmul(const Quat a, const Quat b) {
    Quat r;
    r.x = a.w*b.x + a.x*b.w + a.y*b.z - a.z*b.y;
    r.y = a.w*b.y - a.x*b.z + a.y*b.w + a.z*b.x;
    r.z = a.w*b.z + a.x*b.y - a.y*b.x + a.z*b.w;
    r.w = a.w*b.w - a.x*b.x - a.y*b.y - a.z*b.z;
    return r;
}

__device__ __forceinline__ Quat qshfl_up(const Quat a, int s) {
    Quat r;
    r.x=__shfl_up(a.x,s); r.y=__shfl_up(a.y,s);
    r.z=__shfl_up(a.z,s); r.w=__shfl_up(a.w,s);
    return r;
}

__device__ __forceinline__ Quat qexp3(float px, float py, float pz) {
    float th2 = px*px + py*py + pz*pz;
    float s, w;
    if (th2 < 1e-8f) {
        s = 0.5f - th2 * (1.0f/48.0f);
        w = 1.0f - th2 * 0.125f;
    } else {
        float th = sqrtf(th2);
        s = sinf(0.5f*th) / th;
        w = cosf(0.5f*th);
    }
    Quat q; q.x=px*s; q.y=py*s; q.z=pz*s; q.w=w; return q;
}

__device__ __forceinline__ void quat2mat(const Quat q, float* R) {
    float x=q.x, y=q.y, z=q.z, w=q.w;
    R[0]=1.0f-2.0f*(y*y+z*z); R[1]=2.0f*(x*y-z*w);       R[2]=2.0f*(x*z+y*w);
    R[3]=2.0f*(x*y+z*w);      R[4]=1.0f-2.0f*(x*x+z*z);  R[5]=2.0f*(y*z-x*w);
    R[6]=2.0f*(x*z-y*w);      R[7]=2.0f*(y*z+x*w);       R[8]=1.0f-2.0f*(x*x+y*y);
}

__device__ __forceinline__ void mm_nn(const float* A, const float* B, float* C) {
#pragma unroll
    for (int i=0;i<3;i++)
#pragma unroll
    for (int j=0;j<3;j++)
        C[3*i+j] = A[3*i+0]*B[0+j] + A[3*i+1]*B[3+j] + A[3*i+2]*B[6+j];
}

__device__ __forceinline__ void mm_nt(const float* A, const float* B, float* C) {
#pragma unroll
    for (int i=0;i<3;i++)
#pragma unroll
    for (int j=0;j<3;j++)
        C[3*i+j] = A[3*i+0]*B[3*j+0] + A[3*i+1]*B[3*j+1] + A[3*i+2]*B[3*j+2];
}

__device__ __forceinline__ void mm_tn(const float* A, const float* B, float* C) {
#pragma unroll
    for (int i=0;i<3;i++)
#pragma unroll
    for (int j=0;j<3;j++)
        C[3*i+j] = A[0+i]*B[0+j] + A[3+i]*B[3+j] + A[6+i]*B[6+j];
}

// entries (0,0)(0,1)(0,2)(1,1)(1,2)(2,2) of A*B^T
__device__ __forceinline__ void mm_nt_sym(const float* A, const float* B, float* O6) {
    O6[0]=A[0]*B[0]+A[1]*B[1]+A[2]*B[2];
    O6[1]=A[0]*B[3]+A[1]*B[4]+A[2]*B[5];
    O6[2]=A[0]*B[6]+A[1]*B[7]+A[2]*B[8];
    O6[3]=A[3]*B[3]+A[4]*B[4]+A[5]*B[5];
    O6[4]=A[3]*B[6]+A[4]*B[7]+A[5]*B[8];
    O6[5]=A[6]*B[6]+A[7]*B[7]+A[8]*B[8];
}

// entries (0,0)(0,1)(0,2)(1,1)(1,2)(2,2) of A*B
__device__ __forceinline__ void mm_nn_sym(const float* A, const float* B, float* O6) {
    O6[0]=A[0]*B[0]+A[1]*B[3]+A[2]*B[6];
    O6[1]=A[0]*B[1]+A[1]*B[4]+A[2]*B[7];
    O6[2]=A[0]*B[2]+A[1]*B[5]+A[2]*B[8];
    O6[3]=A[3]*B[1]+A[4]*B[4]+A[5]*B[7];
    O6[4]=A[3]*B[2]+A[4]*B[5]+A[5]*B[8];
    O6[5]=A[6]*B[2]+A[7]*B[5]+A[8]*B[8];
}

__device__ __forceinline__ void expand_sym(const float* t, float* M) {
    M[0]=t[0]; M[1]=t[1]; M[2]=t[2];
    M[3]=t[1]; M[4]=t[3]; M[5]=t[4];
    M[6]=t[2]; M[7]=t[4]; M[8]=t[5];
}

// C = M * skew(v)
__device__ __forceinline__ void m_skew(const float* M, float v0, float v1, float v2, float* C) {
#pragma unroll
    for (int i=0;i<3;i++) {
        C[3*i+0] = M[3*i+1]*v2 - M[3*i+2]*v1;
        C[3*i+1] = M[3*i+2]*v0 - M[3*i+0]*v2;
        C[3*i+2] = M[3*i+0]*v1 - M[3*i+1]*v0;
    }
}

// C = skew(w) * M
__device__ __forceinline__ void skew_m(float w0, float w1, float w2, const float* M, float* C) {
#pragma unroll
    for (int j=0;j<3;j++) {
        C[0+j] = -w2*M[3+j] + w1*M[6+j];
        C[3+j] =  w2*M[0+j] - w0*M[6+j];
        C[6+j] = -w1*M[0+j] + w0*M[3+j];
    }
}

// ---------------------------------------------------------------------------
// A: chunk quaternion totals. wave = one 64-step chunk.
// ---------------------------------------------------------------------------
__global__ __launch_bounds__(256) void k_chunktot(
    const float* __restrict__ dt, const float* __restrict__ gyro,
    float* __restrict__ qtot)
{
    const int bid=blockIdx.x, b=bid>>5, wg=bid&31;
    const int tid=threadIdx.x, lane=tid&63, wid=tid>>6;
    const int c=wg*4+wid;
    const long k=(long)b*FF+(long)c*64+lane;
    float d=dt[k];
    Quat inc=qexp3(gyro[3*k+0]*d, gyro[3*k+1]*d, gyro[3*k+2]*d);
#pragma unroll
    for (int s=1;s<64;s<<=1) {
        Quat p=qshfl_up(inc,s);
        if (lane>=s) inc=qmul(p,inc);
    }
    if (lane==63) {
        float4 o; o.x=inc.x; o.y=inc.y; o.z=inc.z; o.w=inc.w;
        reinterpret_cast<float4*>(qtot)[b*NCH+c]=o;
    }
}

// ---------------------------------------------------------------------------
// B: exclusive scan of 128 chunk quats per batch. 1 WG/batch, 128 threads.
// ---------------------------------------------------------------------------
__global__ __launch_bounds__(128) void k_qpre(
    const float* __restrict__ qtot, float* __restrict__ qpre)
{
    const int b=blockIdx.x, c=threadIdx.x, lane=c&63, w=c>>6;
    __shared__ float4 w0t;
    __shared__ float4 all[NCH];
    float4 t=reinterpret_cast<const float4*>(qtot)[b*NCH+c];
    Quat inc; inc.x=t.x; inc.y=t.y; inc.z=t.z; inc.w=t.w;
#pragma unroll
    for (int s=1;s<64;s<<=1) {
        Quat p=qshfl_up(inc,s);
        if (lane>=s) inc=qmul(p,inc);
    }
    if (w==0 && lane==63) { float4 o; o.x=inc.x;o.y=inc.y;o.z=inc.z;o.w=inc.w; w0t=o; }
    __syncthreads();
    if (w==1) { Quat p; p.x=w0t.x;p.y=w0t.y;p.z=w0t.z;p.w=w0t.w; inc=qmul(p,inc); }
    { float4 o; o.x=inc.x;o.y=inc.y;o.z=inc.z;o.w=inc.w; all[c]=o; }
    __syncthreads();
    float4 pre;
    if (c==0) { pre.x=0.f;pre.y=0.f;pre.z=0.f;pre.w=1.f; }
    else pre=all[c-1];
    reinterpret_cast<float4*>(qpre)[b*NCH+c]=pre;
}

// ---------------------------------------------------------------------------
// C: main fused kernel (factored covariance composites + partial outv/outp).
// ---------------------------------------------------------------------------
#define RSTR 66
__global__ __launch_bounds__(256) void k_main(
    const float* __restrict__ dt, const float* __restrict__ gyro,
    const float* __restrict__ acc, const float* __restrict__ qpre_g,
    float* __restrict__ outq, float* __restrict__ cov, float* __restrict__ vp_g,
    float* __restrict__ outv, float* __restrict__ outp)
{
    __shared__ float red[4][23][RSTR];   // 24,288 B
    const int bid=blockIdx.x, b=bid>>5, wg=bid&31;
    const int tid=threadIdx.x, lane=tid&63, wid=tid>>6;
    const int c=wg*4+wid;
    const long k=(long)b*FF+(long)c*64+lane;

    const float d=dt[k];
    const float wx=gyro[3*k+0]*d, wy=gyro[3*k+1]*d, wz=gyro[3*k+2]*d;
    Quat dq=qexp3(wx,wy,wz);

    // within-chunk inclusive quat prefix
    Quat qloc=dq;
#pragma unroll
    for (int s=1;s<64;s<<=1) {
        Quat p=qshfl_up(qloc,s);
        if (lane>=s) qloc=qmul(p,qloc);
    }
    float4 tp=reinterpret_cast<const float4*>(qpre_g)[b*NCH+c];
    Quat qpre; qpre.x=tp.x; qpre.y=tp.y; qpre.z=tp.z; qpre.w=tp.w;
    Quat qi=qmul(qpre,qloc);
    { float4 o; o.x=qi.x;o.y=qi.y;o.z=qi.z;o.w=qi.w;
      reinterpret_cast<float4*>(outq)[k]=o; }

    Quat ql1=qshfl_up(qloc,1);
    if (lane==0) { ql1.x=0.f; ql1.y=0.f; ql1.z=0.f; ql1.w=1.f; }

    // a = acc - R(qi)^T g
    float a0=acc[3*k+0]-GRAV*2.0f*(qi.x*qi.z-qi.y*qi.w);
    float a1=acc[3*k+1]-GRAV*2.0f*(qi.y*qi.z+qi.x*qi.w);
    float a2=acc[3*k+2]-GRAV*(1.0f-2.0f*(qi.x*qi.x+qi.y*qi.y));

    // b = R(qloc_excl) * a ;  m = d*b
    float Rl[9]; quat2mat(ql1,Rl);
    float b0=Rl[0]*a0+Rl[1]*a1+Rl[2]*a2;
    float b1=Rl[3]*a0+Rl[4]*a1+Rl[5]*a2;
    float b2=Rl[6]*a0+Rl[7]*a1+Rl[8]*a2;
    float m0=d*b0, m1=d*b1, m2=d*b2;

    // inclusive prefix scans: td (dt), M (m)
    float td=d, M0=m0, M1=m1, M2=m2;
#pragma unroll
    for (int s=1;s<64;s<<=1) {
        float p3=__shfl_up(td,s), p0=__shfl_up(M0,s), p1=__shfl_up(M1,s), p2=__shfl_up(M2,s);
        if (lane>=s) { td+=p3; M0+=p0; M1+=p1; M2+=p2; }
    }
    float Dtot=__shfl(td,63);
    float tau = Dtot - td;                 // exclusive suffix dt sum
    float cn = 0.5f*d + tau;
    float n0=cn*m0, n1=cn*m1, n2=cn*m2;
    float N0=n0, N1=n1, N2=n2;
#pragma unroll
    for (int s=1;s<64;s<<=1) {
        float p0=__shfl_up(N0,s),p1=__shfl_up(N1,s),p2=__shfl_up(N2,s);
        if (lane>=s){ N0+=p0; N1+=p1; N2+=p2; }
    }
    // u for pos partial: u = (M - 0.5 m) * d  (prefix scan)
    float u0=(M0-0.5f*m0)*d, u1=(M1-0.5f*m1)*d, u2=(M2-0.5f*m2)*d;
    float U0=u0, U1=u1, U2=u2;
#pragma unroll
    for (int s=1;s<64;s<<=1) {
        float p0=__shfl_up(U0,s),p1=__shfl_up(U1,s),p2=__shfl_up(U2,s);
        if (lane>=s){ U0+=p0; U1+=p1; U2+=p2; }
    }
    float Mt0=__shfl(M0,63), Mt1=__shfl(M1,63), Mt2=__shfl(M2,63);
    float Nt0=__shfl(N0,63), Nt1=__shfl(N1,63), Nt2=__shfl(N2,63);
    float mp0=Mt0-M0, mp1=Mt1-M1, mp2=Mt2-M2;   // m-psi (exclusive suffix)
    float np0=Nt0-N0, np1=Nt1-N1, np2=Nt2-N2;   // n-psi

    // partial outputs: outv = R(qpre)*M, outp = R(qpre)*U  (emit adds offsets)
    float Rp9[9]; quat2mat(qpre,Rp9);
    float pv0=Rp9[0]*M0+Rp9[1]*M1+Rp9[2]*M2;
    float pv1=Rp9[3]*M0+Rp9[4]*M1+Rp9[5]*M2;
    float pv2=Rp9[6]*M0+Rp9[7]*M1+Rp9[8]*M2;
    float pp0=Rp9[0]*U0+Rp9[1]*U1+Rp9[2]*U2;
    float pp1=Rp9[3]*U0+Rp9[4]*U1+Rp9[5]*U2;
    float pp2=Rp9[6]*U0+Rp9[7]*U1+Rp9[8]*U2;
    outv[3*k+0]=pv0; outv[3*k+1]=pv1; outv[3*k+2]=pv2;
    outp[3*k+0]=pp0; outp[3*k+1]=pp1; outp[3*k+2]=pp2;

    const long wsbase=((long)b*NCH+c)*SLOT;
    if (lane==63) {
        float* vp=vp_g+(long)(b*NCH+c)*8;
        vp[0]=pv0; vp[1]=pv1; vp[2]=pv2;
        vp[3]=pp0; vp[4]=pp1; vp[5]=pp2;
        vp[6]=td;
        // chunk params: qtot (= own qloc), qpre, Mtot, Ntot, Dtot
        cov[wsbase+45]=qloc.x; cov[wsbase+46]=qloc.y; cov[wsbase+47]=qloc.z; cov[wsbase+48]=qloc.w;
        cov[wsbase+49]=qpre.x; cov[wsbase+50]=qpre.y; cov[wsbase+51]=qpre.z; cov[wsbase+52]=qpre.w;
        cov[wsbase+53]=M0; cov[wsbase+54]=M1; cov[wsbase+55]=M2;
        cov[wsbase+56]=N0; cov[wsbase+57]=N1; cov[wsbase+58]=N2;
        cov[wsbase+59]=td;
    }

    // Jr -> G' = Rj * (gs J J^T) * Rj^T  (via H = Rj J)
    float th2 = wx*wx + wy*wy + wz*wz;
    float c1, c2;
    if (th2 < 1e-8f) { c1 = 0.5f - th2*(1.0f/24.0f); c2 = (1.0f/6.0f) - th2*(1.0f/120.0f); }
    else { float th = sqrtf(th2); c1 = (1.0f-cosf(th))/th2; c2 = (th - sinf(th))/(th2*th); }
    float J[9];
    {
        float dg = 1.0f - c2*th2;
        J[0]=dg + c2*wx*wx;      J[1]= c1*wz + c2*wx*wy;  J[2]=-c1*wy + c2*wx*wz;
        J[3]=-c1*wz + c2*wx*wy;  J[4]=dg + c2*wy*wy;      J[5]= c1*wx + c2*wy*wz;
        J[6]= c1*wy + c2*wx*wz;  J[7]=-c1*wx + c2*wy*wz;  J[8]=dg + c2*wz*wz;
    }
    float Rj[9]; quat2mat(qloc,Rj);
    float H[9]; mm_nn(Rj,J,H);
    const float gs = GCOV*d*d;
    float Gp[9];
    Gp[0]=gs*(H[0]*H[0]+H[1]*H[1]+H[2]*H[2]);
    Gp[1]=gs*(H[0]*H[3]+H[1]*H[4]+H[2]*H[5]);
    Gp[2]=gs*(H[0]*H[6]+H[1]*H[7]+H[2]*H[8]);
    Gp[4]=gs*(H[3]*H[3]+H[4]*H[4]+H[5]*H[5]);
    Gp[5]=gs*(H[3]*H[6]+H[4]*H[7]+H[5]*H[8]);
    Gp[8]=gs*(H[6]*H[6]+H[7]*H[7]+H[8]*H[8]);
    Gp[3]=Gp[1]; Gp[6]=Gp[2]; Gp[7]=Gp[5];

    const float av  = ACOV*d*d;
    const float bv  = 0.5f*ACOV*d*d*d;
    const float cv  = 0.25f*ACOV*d*d*d*d;
    const float vpd = av*tau + bv;
    const float ppd = av*tau*tau + 2.0f*bv*tau + cv;

    // core blocks
    float Crv[9], Crp[9], Cvv[9], Cvp[9], Cpp[9];
    m_skew(Gp, mp0,mp1,mp2, Crv);          // G' skew(m-psi)
    m_skew(Gp, np0,np1,np2, Crp);          // G' skew(n-psi)
    skew_m(-mp0,-mp1,-mp2, Crv, Cvv);      // skew(-m) G' skew(m)
    skew_m(-mp0,-mp1,-mp2, Crp, Cvp);
    skew_m(-np0,-np1,-np2, Crp, Cpp);

    float S45[45];
#pragma unroll
    for (int i=0;i<9;i++){ S45[i]=Crv[i]; S45[9+i]=Crp[i]; S45[18+i]=Cvp[i]; }
    S45[18]+=vpd; S45[22]+=vpd; S45[26]+=vpd;
    S45[27]=Gp[0];  S45[28]=Gp[1];  S45[29]=Gp[2];  S45[30]=Gp[4];  S45[31]=Gp[5];  S45[32]=Gp[8];
    S45[33]=Cvv[0]+av; S45[34]=Cvv[1]; S45[35]=Cvv[2]; S45[36]=Cvv[4]+av; S45[37]=Cvv[5]; S45[38]=Cvv[8]+av;
    S45[39]=Cpp[0]+ppd; S45[40]=Cpp[1]; S45[41]=Cpp[2]; S45[42]=Cpp[4]+ppd; S45[43]=Cpp[5]; S45[44]=Cpp[8]+ppd;

    // per-wave LDS transpose reduction over lanes, two rounds (23 + 22 elems)
#pragma unroll
    for (int e=0;e<23;e++) red[wid][e][lane] = S45[e];
    __syncthreads();
    float r1 = 0.f;
    if (lane < 23) {
        const float* row = &red[wid][lane][0];
        float ax=0.f, ay=0.f;
#pragma unroll
        for (int i=0;i<32;i++) {
            float2 v = reinterpret_cast<const float2*>(row)[i];
            ax += v.x; ay += v.y;
        }
        r1 = ax + ay;
    }
    __syncthreads();
#pragma unroll
    for (int e=0;e<22;e++) red[wid][e][lane] = S45[23+e];
    __syncthreads();
    float r2 = 0.f;
    if (lane < 22) {
        const float* row = &red[wid][lane][0];
        float ax=0.f, ay=0.f;
#pragma unroll
        for (int i=0;i<32;i++) {
            float2 v = reinterpret_cast<const float2*>(row)[i];
            ax += v.x; ay += v.y;
        }
        r2 = ax + ay;
    }
    if (lane < 23) cov[wsbase+lane] = r1;
    if (lane < 22) cov[wsbase+23+lane] = r2;
}

// ---------------------------------------------------------------------------
// D: per-batch scans of vel/pos chunk partials -> exclusive (V, Pp) per chunk.
// ---------------------------------------------------------------------------
__global__ __launch_bounds__(128) void k_vpscan(
    const float* __restrict__ vp_g, float* __restrict__ vpre)
{
    const int b=blockIdx.x, c=threadIdx.x, lane=c&63, w=c>>6;
    __shared__ float w0t[3];
    __shared__ float all3[NCH][3];
    const float* vp=vp_g+(long)(b*NCH+c)*8;
    float Lv0=vp[0],Lv1=vp[1],Lv2=vp[2],Sw0=vp[3],Sw1=vp[4],Sw2=vp[5],Td=vp[6];

    float i0=Lv0,i1=Lv1,i2=Lv2;
#pragma unroll
    for (int s=1;s<64;s<<=1) {
        float p0=__shfl_up(i0,s),p1=__shfl_up(i1,s),p2=__shfl_up(i2,s);
        if (lane>=s){ i0+=p0; i1+=p1; i2+=p2; }
    }
    if (w==0 && lane==63){ w0t[0]=i0; w0t[1]=i1; w0t[2]=i2; }
    __syncthreads();
    if (w==1){ i0+=w0t[0]; i1+=w0t[1]; i2+=w0t[2]; }
    all3[c][0]=i0; all3[c][1]=i1; all3[c][2]=i2;
    __syncthreads();
    float V0=(c==0)?0.f:all3[c-1][0];
    float V1=(c==0)?0.f:all3[c-1][1];
    float V2=(c==0)?0.f:all3[c-1][2];
    __syncthreads();

    float u0=V0*Td+Sw0, u1=V1*Td+Sw1, u2=V2*Td+Sw2;
    i0=u0; i1=u1; i2=u2;
#pragma unroll
    for (int s=1;s<64;s<<=1) {
        float p0=__shfl_up(i0,s),p1=__shfl_up(i1,s),p2=__shfl_up(i2,s);
        if (lane>=s){ i0+=p0; i1+=p1; i2+=p2; }
    }
    if (w==0 && lane==63){ w0t[0]=i0; w0t[1]=i1; w0t[2]=i2; }
    __syncthreads();
    if (w==1){ i0+=w0t[0]; i1+=w0t[1]; i2+=w0t[2]; }
    all3[c][0]=i0; all3[c][1]=i1; all3[c][2]=i2;
    __syncthreads();
    float P0=(c==0)?0.f:all3[c-1][0];
    float P1=(c==0)?0.f:all3[c-1][1];
    float P2=(c==0)?0.f:all3[c-1][2];

    float* o=vpre+(long)(b*NCH+c)*8;
    o[0]=V0; o[1]=V1; o[2]=V2; o[3]=P0; o[4]=P1; o[5]=P2;
}

// ---------------------------------------------------------------------------
// K4 combine math (compact layout). Phi[0..27]=D,P,Q,T.
// S (45): Arv0 Arp9 Avp18 Arr27t Avv33t App39t.
// ---------------------------------------------------------------------------
__device__ __forceinline__ void congr45(const float* Phi, const float* S, float* O)
{
    const float* D=Phi; const float* P=Phi+9; const float* Q=Phi+18; const float T=Phi[27];
    const float* Arv=S+0; const float* Arp=S+9; const float* Avp=S+18;
    float Arr[9], Avv[9], App[9];
    expand_sym(S+27,Arr); expand_sym(S+33,Avv); expand_sym(S+39,App);

    float M1[9], M2[9], M3[9], t1[9], t6[6];
    mm_nn(D,Arr,M1); mm_nn(D,Arv,M2); mm_nn(D,Arp,M3);
    mm_nt_sym(M1, D, O+27);                          // O_rr (tri)
    mm_nt(M1, P, t1);
#pragma unroll
    for (int i=0;i<9;i++) O[0+i] = t1[i] + M2[i];    // O_rv
    mm_nt(M1, Q, t1);
#pragma unroll
    for (int i=0;i<9;i++) O[9+i] = t1[i] + T*M2[i] + M3[i];  // O_rp

    float W1[9], W2[9], W3[9];
    mm_nn(P, Arr, W1);
#pragma unroll
    for (int i=0;i<3;i++)
#pragma unroll
    for (int j=0;j<3;j++) W1[3*i+j] += Arv[3*j+i];
    mm_nn(P, Arv, W2);
#pragma unroll
    for (int i=0;i<9;i++) W2[i] += Avv[i];
    mm_nn(P, Arp, W3);
#pragma unroll
    for (int i=0;i<9;i++) W3[i] += Avp[i];
    mm_nt_sym(W1, P, t6);                            // O_vv (tri)
    O[33+0]=t6[0]+W2[0]; O[33+1]=t6[1]+W2[1]; O[33+2]=t6[2]+W2[2];
    O[33+3]=t6[3]+W2[4]; O[33+4]=t6[4]+W2[5]; O[33+5]=t6[5]+W2[8];
    mm_nt(W1, Q, t1);
#pragma unroll
    for (int i=0;i<9;i++) O[18+i] = t1[i] + T*W2[i] + W3[i];  // O_vp

    float U1[9], U2[9], U3[9];
    mm_nn(Q, Arr, U1);
#pragma unroll
    for (int i=0;i<3;i++)
#pragma unroll
    for (int j=0;j<3;j++) U1[3*i+j] += T*Arv[3*j+i] + Arp[3*j+i];
    mm_nn(Q, Arv, U2);
#pragma unroll
    for (int i=0;i<3;i++)
#pragma unroll
    for (int j=0;j<3;j++) U2[3*i+j] += T*Avv[3*i+j] + Avp[3*j+i];
    mm_nn(Q, Arp, U3);
#pragma unroll
    for (int i=0;i<9;i++) U3[i] += T*Avp[i] + App[i];
    mm_nt_sym(U1, Q, t6);                            // O_pp (tri)
    O[39+0]=t6[0]+T*U2[0]+U3[0]; O[39+1]=t6[1]+T*U2[1]+U3[1]; O[39+2]=t6[2]+T*U2[2]+U3[2];
    O[39+3]=t6[3]+T*U2[4]+U3[4]; O[39+4]=t6[4]+T*U2[5]+U3[5]; O[39+5]=t6[5]+T*U2[8]+U3[8];
}

// ---------------------------------------------------------------------------
// E (merged): blocks 0..31 covcomb (scalar-factored Phi scan);
//             blocks 32..1055 feather-weight emit.
// ---------------------------------------------------------------------------
__global__ __launch_bounds__(256) void k_merged(
    const float* __restrict__ dt, const float* __restrict__ pos0,
    const float* __restrict__ vel0, const float* __restrict__ vpre,
    const float* __restrict__ cov,
    float* __restrict__ outv, float* __restrict__ outp, float* __restrict__ outc)
{
    __shared__ float stg[NCH*SLOT];  // 31,232 B compact slots (covcomb only)
    __shared__ float sc[NCH][13];    //  6,656 B scalar scan area (q,M,N,T)
    const int bid=blockIdx.x;
    const int tid=threadIdx.x, lane=tid&63, wid=tid>>6;

    if (bid < BB) {
        const int b = bid;
        // coalesced load of compact slots
        for (int idx=tid; idx<NCH*SLOT; idx+=256) stg[idx] = cov[(long)b*NCH*SLOT + idx];
        __syncthreads();

        // init scalar scan area from chunk params
        if (tid < NCH) {
            const float* g = &stg[tid*SLOT];
            sc[tid][0]=g[45]; sc[tid][1]=g[46]; sc[tid][2]=g[47]; sc[tid][3]=g[48];  // qtot
            sc[tid][4]=g[53]; sc[tid][5]=g[54]; sc[tid][6]=g[55];                    // M
            sc[tid][7]=g[56]; sc[tid][8]=g[57]; sc[tid][9]=g[58];                    // N
            sc[tid][10]=g[59];                                                       // T
        }
        __syncthreads();

        // inclusive suffix scan of factored (q,M,N,T):
        //  q' = q_b (x) q_a ; M' = M_b + R_b M_a ; N' = N_b + R_b N_a + T_a M_b
        for (int s=1;s<NCH;s<<=1) {
            bool own = tid < NCH;
            bool act = own && (tid+s) < NCH;
            Quat qb, qa; float Mb[3],Nb[3],Tb=0.f, Ma[3],Na[3],Ta=0.f;
            if (own) {
                qb.x=sc[tid][0]; qb.y=sc[tid][1]; qb.z=sc[tid][2]; qb.w=sc[tid][3];
                Mb[0]=sc[tid][4]; Mb[1]=sc[tid][5]; Mb[2]=sc[tid][6];
                Nb[0]=sc[tid][7]; Nb[1]=sc[tid][8]; Nb[2]=sc[tid][9];
                Tb=sc[tid][10];
            }
            if (act) {
                qa.x=sc[tid+s][0]; qa.y=sc[tid+s][1]; qa.z=sc[tid+s][2]; qa.w=sc[tid+s][3];
                Ma[0]=sc[tid+s][4]; Ma[1]=sc[tid+s][5]; Ma[2]=sc[tid+s][6];
                Na[0]=sc[tid+s][7]; Na[1]=sc[tid+s][8]; Na[2]=sc[tid+s][9];
                Ta=sc[tid+s][10];
            }
            __syncthreads();
            if (act) {
                Quat qc=qmul(qb,qa);
                float Rb[9]; quat2mat(qb,Rb);
                float Mc0=Mb[0]+Rb[0]*Ma[0]+Rb[1]*Ma[1]+Rb[2]*Ma[2];
                float Mc1=Mb[1]+Rb[3]*Ma[0]+Rb[4]*Ma[1]+Rb[5]*Ma[2];
                float Mc2=Mb[2]+Rb[6]*Ma[0]+Rb[7]*Ma[1]+Rb[8]*Ma[2];
                float Nc0=Nb[0]+Rb[0]*Na[0]+Rb[1]*Na[1]+Rb[2]*Na[2]+Ta*Mb[0];
                float Nc1=Nb[1]+Rb[3]*Na[0]+Rb[4]*Na[1]+Rb[5]*Na[2]+Ta*Mb[1];
                float Nc2=Nb[2]+Rb[6]*Na[0]+Rb[7]*Na[1]+Rb[8]*Na[2]+Ta*Mb[2];
                sc[tid][0]=qc.x; sc[tid][1]=qc.y; sc[tid][2]=qc.z; sc[tid][3]=qc.w;
                sc[tid][4]=Mc0; sc[tid][5]=Mc1; sc[tid][6]=Mc2;
                sc[tid][7]=Nc0; sc[tid][8]=Nc1; sc[tid][9]=Nc2;
                sc[tid][10]=Ta+Tb;
            }
            __syncthreads();
        }

        // per-chunk: build exclusive-suffix Phi + reconstruct S, congr, store O
        if (tid < NCH) {
            const float* g = &stg[tid*SLOT];
            Quat qt; qt.x=g[45]; qt.y=g[46]; qt.z=g[47]; qt.w=g[48];
            Quat qp; qp.x=g[49]; qp.y=g[50]; qp.z=g[51]; qp.w=g[52];

            float Phi[28];
            if (tid < NCH-1) {
                Quat qs; qs.x=sc[tid+1][0]; qs.y=sc[tid+1][1]; qs.z=sc[tid+1][2]; qs.w=sc[tid+1][3];
                float Ms0=sc[tid+1][4], Ms1=sc[tid+1][5], Ms2=sc[tid+1][6];
                float Ns0=sc[tid+1][7], Ns1=sc[tid+1][8], Ns2=sc[tid+1][9];
                float Ts=sc[tid+1][10];
                float Rs[9]; quat2mat(qs,Rs);
                Phi[0]=Rs[0]; Phi[1]=Rs[3]; Phi[2]=Rs[6];
                Phi[3]=Rs[1]; Phi[4]=Rs[4]; Phi[5]=Rs[7];
                Phi[6]=Rs[2]; Phi[7]=Rs[5]; Phi[8]=Rs[8];
                Quat qp1=qmul(qp,qt);                 // qpre of chunk tid+1
                float Rp1[9]; quat2mat(qp1,Rp1);
                float Pc[9]; m_skew(Rp1, -Ms0,-Ms1,-Ms2, Pc);
                float Qc[9]; m_skew(Rp1, -Ns0,-Ns1,-Ns2, Qc);
#pragma unroll
                for (int i=0;i<9;i++){ Phi[9+i]=Pc[i]; Phi[18+i]=Qc[i]; }
                Phi[27]=Ts;
            } else {
#pragma unroll
                for (int i=0;i<9;i++){ Phi[i]=(i%4==0)?1.f:0.f; Phi[9+i]=0.f; Phi[18+i]=0.f; }
                Phi[27]=0.f;
            }

            // reconstruct S blocks with outer rotations (from own compact slot)
            float Rt[9]; quat2mat(qt,Rt);
            float Rp[9]; quat2mat(qp,Rp);
            float S[45];
            {
                float Crv[9],Crp[9],Cvp9[9], e9[9], t9[9], o9[9], o6[6];
#pragma unroll
                for (int i=0;i<9;i++){ Crv[i]=g[i]; Crp[i]=g[9+i]; Cvp9[i]=g[18+i]; }
                mm_tn(Rt, Crv, t9); mm_nt(t9, Rp, o9);
#pragma unroll
                for (int i=0;i<9;i++) S[i]=o9[i];
                mm_tn(Rt, Crp, t9); mm_nt(t9, Rp, o9);
#pragma unroll
                for (int i=0;i<9;i++) S[9+i]=o9[i];
                mm_nn(Rp, Cvp9, t9); mm_nt(t9, Rp, o9);
#pragma unroll
                for (int i=0;i<9;i++) S[18+i]=o9[i];
                expand_sym(g+27, e9); mm_tn(Rt, e9, t9); mm_nn_sym(t9, Rt, o6);
#pragma unroll
                for (int i=0;i<6;i++) S[27+i]=o6[i];
                expand_sym(g+33, e9); mm_nn(Rp, e9, t9); mm_nt_sym(t9, Rp, o6);
#pragma unroll
                for (int i=0;i<6;i++) S[33+i]=o6[i];
                expand_sym(g+39, e9); mm_nn(Rp, e9, t9); mm_nt_sym(t9, Rp, o6);
#pragma unroll
                for (int i=0;i<6;i++) S[39+i]=o6[i];
            }
            float O[45];
            congr45(Phi, S, O);
            float* w = &stg[tid*SLOT];
#pragma unroll
            for (int i=0;i<45;i++) w[i] = O[i];
        }
        __syncthreads();

        // tree sum of the 45-float terms (stride 61, odd -> conflict-free)
        for (int s=64;s>0;s>>=1) {
            if (tid < s) {
#pragma unroll
                for (int i=0;i<45;i++) stg[tid*SLOT+i] += stg[(tid+s)*SLOT+i];
            }
            __syncthreads();
        }

        if (tid < 81) {
            int i = tid/9, j = tid%9;
            int bi = i/3, ii = i%3, bj = j/3, jj = j%3;
            int lo = (ii<jj)?ii:jj, hi = (ii<jj)?jj:ii;
            int tix = (lo==0)?hi:((lo==1)?(2+hi):5);
            const float* S0 = &stg[0];
            float v;
            if      (bi==0 && bj==0) v = S0[27 + tix];        // Arr
            else if (bi==0 && bj==1) v = S0[0  + 3*ii + jj];  // Arv
            else if (bi==0 && bj==2) v = S0[9  + 3*ii + jj];  // Arp
            else if (bi==1 && bj==0) v = S0[0  + 3*jj + ii];  // Arv^T
            else if (bi==1 && bj==1) v = S0[33 + tix];        // Avv
            else if (bi==1 && bj==2) v = S0[18 + 3*ii + jj];  // Avp
            else if (bi==2 && bj==0) v = S0[9  + 3*jj + ii];  // Arp^T
            else if (bi==2 && bj==1) v = S0[18 + 3*jj + ii];  // Avp^T
            else                     v = S0[39 + tix];        // App
            outc[(long)b*81 + tid] = v;
        }
        return;
    }

    // ---- feather-weight emit: RMW partials with chunk offsets ----
    const int ebid = bid - BB;
    const int b = ebid>>5, wg = ebid&31;
    const int c = wg*4+wid;
    const long k = (long)b*FF+(long)c*64+lane;

    float td = dt[k];
#pragma unroll
    for (int s=1;s<64;s<<=1) {
        float p=__shfl_up(td,s);
        if (lane>=s) td+=p;
    }

    const float* vr=vpre+(long)(b*NCH+c)*8;
    float V0=vr[0],V1=vr[1],V2=vr[2],P0=vr[3],P1=vr[4],P2=vr[5];
    float v0x=vel0[3*b+0], v0y=vel0[3*b+1], v0z=vel0[3*b+2];
    float p0x=pos0[3*b+0], p0y=pos0[3*b+1], p0z=pos0[3*b+2];

    float pv0=outv[3*k+0], pv1=outv[3*k+1], pv2=outv[3*k+2];
    float pp0=outp[3*k+0], pp1=outp[3*k+1], pp2=outp[3*k+2];

    outv[3*k+0]=v0x+V0+pv0;
    outv[3*k+1]=v0y+V1+pv1;
    outv[3*k+2]=v0z+V2+pv2;
    outp[3*k+0]=p0x+P0+V0*td+pp0;
    outp[3*k+1]=p0y+P1+V1*td+pp1;
    outp[3*k+2]=p0z+P2+V2*td+pp2;
}

// ---------------------------------------------------------------------------
extern "C" void kernel_launch(void* const* d_in, const int* in_sizes, int n_in,
                              void* d_out, int out_size, void* d_ws, size_t ws_size,
                              hipStream_t stream)
{
    const float* dt   = (const float*)d_in[0];
    const float* gyro = (const float*)d_in[1];
    const float* acc  = (const float*)d_in[2];
    const float* pos0 = (const float*)d_in[3];
    const float* vel0 = (const float*)d_in[4];

    float* out  = (float*)d_out;
    float* outq = out;
    float* outv = out  + (long)BB*FF*4;
    float* outp = outv + (long)BB*FF*3;
    float* outc = outp + (long)BB*FF*3;

    float* ws   = (float*)d_ws;           // 1,392,640 bytes used
    float* cov  = ws + COV_OFF;
    float* vpre = ws + VPRE_OFF;
    float* qtot = ws + QTOT_OFF;
    float* qpre = ws + QPRE_OFF;
    float* vp   = ws + VP_OFF;

    hipLaunchKernelGGL(k_chunktot, dim3(BB*32),    dim3(256), 0, stream, dt, gyro, qtot);
    hipLaunchKernelGGL(k_qpre,     dim3(BB),       dim3(128), 0, stream, qtot, qpre);
    hipLaunchKernelGGL(k_main,     dim3(BB*32),    dim3(256), 0, stream, dt, gyro, acc, qpre, outq, cov, vp, outv, outp);
    hipLaunchKernelGGL(k_vpscan,   dim3(BB),       dim3(128), 0, stream, vp, vpre);
    hipLaunchKernelGGL(k_merged,   dim3(BB*32+BB), dim3(256), 0, stream, dt, pos0, vel0, vpre, cov, outv, outp, outc);
}

// Round 11
// 39.640 us; speedup vs baseline: 1.6609x; 1.0239x over previous
//
#include <hip/hip_runtime.h>

// IMU preintegration, B=32 batches, F=8192 steps. 5-kernel pipeline:
//  A k_chunktot : per-step qexp + chunk-local quat prefix -> qloc staged in
//                 outq region (all lanes) + chunk totals (ws)
//  B k_qpre     : per-batch exclusive scan of 128 chunk quats      (ws)
//  C k_main     : loads qloc (no sincos, no quat scan), RMW outq=qpre*qloc,
//                 partial outv/outp + chunk partials (ws) + factored cov
//                 composites (ws). Jr coeffs derived from dq algebraically.
//  D k_vpscan   : per-batch scans of chunk partials -> (V,Pp) per chunk
//  E k_merged   : blocks 0-31 covcomb (scalar-factored Phi scan);
//                 blocks 32-1055 feather-weight emit (RMW of partials).
// d_ws: cov 32*128*61 + vpre 32*128*8 + qtot 16384 + qpre 16384 + vp 32768
//       = 348160 floats = 1,392,640 bytes.

#define BB 32
#define FF 8192
#define NCH 128
#define SLOT 61
#define GRAV 9.81007f
#define GCOV (0.0032f*0.0032f)
#define ACOV (0.08f*0.08f)

// ws float offsets
#define COV_OFF  0
#define VPRE_OFF 249856
#define QTOT_OFF 282624
#define QPRE_OFF 299008
#define VP_OFF   315392

struct Quat { float x, y, z, w; };

__device__ __forceinline__ Quat qmul(const Quat a, const Quat b) {
    Quat r;
    r.x = a.w*b.x + a.x*b.w + a.y*b.z - a.z*b.y;
    r.y = a.w*b.y - a.x*b.z + a.y*b.w + a.z*b.x;
    r.z = a.w*b.z + a.x*b.y - a.y*b.x + a.z*b.w;
    r.w = a.w*b.w - a.x*b.x - a.y*b.y - a.z*b.z;
    return r;
}

__device__ __forceinline__ Quat qshfl_up(const Quat a, int s) {
    Quat r;
    r.x=__shfl_up(a.x,s); r.y=__shfl_up(a.y,s);
    r.z=__shfl_up(a.z,s); r.w=__shfl_up(a.w,s);
    return r;
}

__device__ __forceinline__ Quat qexp3(float px, float py, float pz) {
    float th2 = px*px + py*py + pz*pz;
    float s, w;
    if (th2 < 1e-8f) {
        s = 0.5f - th2 * (1.0f/48.0f);
        w = 1.0f - th2 * 0.125f;
    } else {
        float th = sqrtf(th2);
        s = sinf(0.5f*th) / th;
        w = cosf(0.5f*th);
    }
    Quat q; q.x=px*s; q.y=py*s; q.z=pz*s; q.w=w; return q;
}

__device__ __forceinline__ void quat2mat(const Quat q, float* R) {
    float x=q.x, y=q.y, z=q.z, w=q.w;
    R[0]=1.0f-2.0f*(y*y+z*z); R[1]=2.0f*(x*y-z*w);       R[2]=2.0f*(x*z+y*w);
    R[3]=2.0f*(x*y+z*w);      R[4]=1.0f-2.0f*(x*x+z*z);  R[5]=2.0f*(y*z-x*w);
    R[6]=2.0f*(x*z-y*w);      R[7]=2.0f*(y*z+x*w);       R[8]=1.0f-2.0f*(x*x+y*y);
}

__device__ __forceinline__ void mm_nn(const float* A, const float* B, float* C) {
#pragma unroll
    for (int i=0;i<3;i++)
#pragma unroll
    for (int j=0;j<3;j++)
        C[3*i+j] = A[3*i+0]*B[0+j] + A[3*i+1]*B[3+j] + A[3*i+2]*B[6+j];
}

__device__ __forceinline__ void mm_nt(const float* A, const float* B, float* C) {
#pragma unroll
    for (int i=0;i<3;i++)
#pragma unroll
    for (int j=0;j<3;j++)
        C[3*i+j] = A[3*i+0]*B[3*j+0] + A[3*i+1]*B[3*j+1] + A[3*i+2]*B[3*j+2];
}

__device__ __forceinline__ void mm_tn(const float* A, const float* B, float* C) {
#pragma unroll
    for (int i=0;i<3;i++)
#pragma unroll
    for (int j=0;j<3;j++)
        C[3*i+j] = A[0+i]*B[0+j] + A[3+i]*B[3+j] + A[6+i]*B[6+j];
}

// entries (0,0)(0,1)(0,2)(1,1)(1,2)(2,2) of A*B^T
__device__ __forceinline__ void mm_nt_sym(const float* A, const float* B, float* O6) {
    O6[0]=A[0]*B[0]+A[1]*B[1]+A[2]*B[2];
    O6[1]=A[0]*B[3]+A[1]*B[4]+A[2]*B[5];
    O6[2]=A[0]*B[6]+A[1]*B[7]+A[2]*B[8];
    O6[3]=A[3]*B[3]+A[4]*B[4]+A[5]*B[5];
    O6[4]=A[3]*B[6]+A[4]*B[7]+A[5]*B[8];
    O6[5]=A[6]*B[6]+A[7]*B[7]+A[8]*B[8];
}

// entries (0,0)(0,1)(0,2)(1,1)(1,2)(2,2) of A*B
__device__ __forceinline__ void mm_nn_sym(const float* A, const float* B, float* O6) {
    O6[0]=A[0]*B[0]+A[1]*B[3]+A[2]*B[6];
    O6[1]=A[0]*B[1]+A[1]*B[4]+A[2]*B[7];
    O6[2]=A[0]*B[2]+A[1]*B[5]+A[2]*B[8];
    O6[3]=A[3]*B[1]+A[4]*B[4]+A[5]*B[7];
    O6[4]=A[3]*B[2]+A[4]*B[5]+A[5]*B[8];
    O6[5]=A[6]*B[2]+A[7]*B[5]+A[8]*B[8];
}

__device__ __forceinline__ void expand_sym(const float* t, float* M) {
    M[0]=t[0]; M[1]=t[1]; M[2]=t[2];
    M[3]=t[1]; M[4]=t[3]; M[5]=t[4];
    M[6]=t[2]; M[7]=t[4]; M[8]=t[5];
}

// C = M * skew(v)
__device__ __forceinline__ void m_skew(const float* M, float v0, float v1, float v2, float* C) {
#pragma unroll
    for (int i=0;i<3;i++) {
        C[3*i+0] = M[3*i+1]*v2 - M[3*i+2]*v1;
        C[3*i+1] = M[3*i+2]*v0 - M[3*i+0]*v2;
        C[3*i+2] = M[3*i+0]*v1 - M[3*i+1]*v0;
    }
}

// C = skew(w) * M
__device__ __forceinline__ void skew_m(float w0, float w1, float w2, const float* M, float* C) {
#pragma unroll
    for (int j=0;j<3;j++) {
        C[0+j] = -w2*M[3+j] + w1*M[6+j];
        C[3+j] =  w2*M[0+j] - w0*M[6+j];
        C[6+j] = -w1*M[0+j] + w0*M[3+j];
    }
}

// ---------------------------------------------------------------------------
// A: chunk quat prefix. Writes per-lane qloc to outq region + lane63 totals.
// ---------------------------------------------------------------------------
__global__ __launch_bounds__(256) void k_chunktot(
    const float* __restrict__ dt, const float* __restrict__ gyro,
    float* __restrict__ qtot, float* __restrict__ outq)
{
    const int bid=blockIdx.x, b=bid>>5, wg=bid&31;
    const int tid=threadIdx.x, lane=tid&63, wid=tid>>6;
    const int c=wg*4+wid;
    const long k=(long)b*FF+(long)c*64+lane;
    float d=dt[k];
    Quat inc=qexp3(gyro[3*k+0]*d, gyro[3*k+1]*d, gyro[3*k+2]*d);
#pragma unroll
    for (int s=1;s<64;s<<=1) {
        Quat p=qshfl_up(inc,s);
        if (lane>=s) inc=qmul(p,inc);
    }
    { float4 o; o.x=inc.x; o.y=inc.y; o.z=inc.z; o.w=inc.w;
      reinterpret_cast<float4*>(outq)[k]=o; }
    if (lane==63) {
        float4 o; o.x=inc.x; o.y=inc.y; o.z=inc.z; o.w=inc.w;
        reinterpret_cast<float4*>(qtot)[b*NCH+c]=o;
    }
}

// ---------------------------------------------------------------------------
// B: exclusive scan of 128 chunk quats per batch. 1 WG/batch, 128 threads.
// ---------------------------------------------------------------------------
__global__ __launch_bounds__(128) void k_qpre(
    const float* __restrict__ qtot, float* __restrict__ qpre)
{
    const int b=blockIdx.x, c=threadIdx.x, lane=c&63, w=c>>6;
    __shared__ float4 w0t;
    __shared__ float4 all[NCH];
    float4 t=reinterpret_cast<const float4*>(qtot)[b*NCH+c];
    Quat inc; inc.x=t.x; inc.y=t.y; inc.z=t.z; inc.w=t.w;
#pragma unroll
    for (int s=1;s<64;s<<=1) {
        Quat p=qshfl_up(inc,s);
        if (lane>=s) inc=qmul(p,inc);
    }
    if (w==0 && lane==63) { float4 o; o.x=inc.x;o.y=inc.y;o.z=inc.z;o.w=inc.w; w0t=o; }
    __syncthreads();
    if (w==1) { Quat p; p.x=w0t.x;p.y=w0t.y;p.z=w0t.z;p.w=w0t.w; inc=qmul(p,inc); }
    { float4 o; o.x=inc.x;o.y=inc.y;o.z=inc.z;o.w=inc.w; all[c]=o; }
    __syncthreads();
    float4 pre;
    if (c==0) { pre.x=0.f;pre.y=0.f;pre.z=0.f;pre.w=1.f; }
    else pre=all[c-1];
    reinterpret_cast<float4*>(qpre)[b*NCH+c]=pre;
}

// ---------------------------------------------------------------------------
// C: main fused kernel. Loads staged qloc; no transcendentals, no quat scan.
// ---------------------------------------------------------------------------
#define RSTR 66
__global__ __launch_bounds__(256) void k_main(
    const float* __restrict__ dt, const float* __restrict__ gyro,
    const float* __restrict__ acc, const float* __restrict__ qpre_g,
    float* __restrict__ outq, float* __restrict__ cov, float* __restrict__ vp_g,
    float* __restrict__ outv, float* __restrict__ outp)
{
    __shared__ float red[4][23][RSTR];   // 24,288 B
    const int bid=blockIdx.x, b=bid>>5, wg=bid&31;
    const int tid=threadIdx.x, lane=tid&63, wid=tid>>6;
    const int c=wg*4+wid;
    const long k=(long)b*FF+(long)c*64+lane;

    const float d=dt[k];
    const float wx=gyro[3*k+0]*d, wy=gyro[3*k+1]*d, wz=gyro[3*k+2]*d;

    // staged within-chunk inclusive quat prefix
    Quat qloc;
    { float4 t=reinterpret_cast<const float4*>(outq)[k];
      qloc.x=t.x; qloc.y=t.y; qloc.z=t.z; qloc.w=t.w; }
    float4 tp=reinterpret_cast<const float4*>(qpre_g)[b*NCH+c];
    Quat qpre; qpre.x=tp.x; qpre.y=tp.y; qpre.z=tp.z; qpre.w=tp.w;
    Quat qi=qmul(qpre,qloc);
    { float4 o; o.x=qi.x;o.y=qi.y;o.z=qi.z;o.w=qi.w;
      reinterpret_cast<float4*>(outq)[k]=o; }

    Quat ql1=qshfl_up(qloc,1);
    if (lane==0) { ql1.x=0.f; ql1.y=0.f; ql1.z=0.f; ql1.w=1.f; }
    // dq = conj(ql1) (x) qloc   (per-step increment, for Jr coeffs)
    Quat cq; cq.x=-ql1.x; cq.y=-ql1.y; cq.z=-ql1.z; cq.w=ql1.w;
    Quat dqq=qmul(cq,qloc);

    // a = acc - R(qi)^T g
    float a0=acc[3*k+0]-GRAV*2.0f*(qi.x*qi.z-qi.y*qi.w);
    float a1=acc[3*k+1]-GRAV*2.0f*(qi.y*qi.z+qi.x*qi.w);
    float a2=acc[3*k+2]-GRAV*(1.0f-2.0f*(qi.x*qi.x+qi.y*qi.y));

    // b = R(qloc_excl) * a ;  m = d*b
    float Rl[9]; quat2mat(ql1,Rl);
    float b0=Rl[0]*a0+Rl[1]*a1+Rl[2]*a2;
    float b1=Rl[3]*a0+Rl[4]*a1+Rl[5]*a2;
    float b2=Rl[6]*a0+Rl[7]*a1+Rl[8]*a2;
    float m0=d*b0, m1=d*b1, m2=d*b2;

    // inclusive prefix scans: td (dt), M (m)
    float td=d, M0=m0, M1=m1, M2=m2;
#pragma unroll
    for (int s=1;s<64;s<<=1) {
        float p3=__shfl_up(td,s), p0=__shfl_up(M0,s), p1=__shfl_up(M1,s), p2=__shfl_up(M2,s);
        if (lane>=s) { td+=p3; M0+=p0; M1+=p1; M2+=p2; }
    }
    float Dtot=__shfl(td,63);
    float tau = Dtot - td;                 // exclusive suffix dt sum
    float cn = 0.5f*d + tau;
    float n0=cn*m0, n1=cn*m1, n2=cn*m2;
    float N0=n0, N1=n1, N2=n2;
#pragma unroll
    for (int s=1;s<64;s<<=1) {
        float p0=__shfl_up(N0,s),p1=__shfl_up(N1,s),p2=__shfl_up(N2,s);
        if (lane>=s){ N0+=p0; N1+=p1; N2+=p2; }
    }
    // u for pos partial: u = (M - 0.5 m) * d  (prefix scan)
    float u0=(M0-0.5f*m0)*d, u1=(M1-0.5f*m1)*d, u2=(M2-0.5f*m2)*d;
    float U0=u0, U1=u1, U2=u2;
#pragma unroll
    for (int s=1;s<64;s<<=1) {
        float p0=__shfl_up(U0,s),p1=__shfl_up(U1,s),p2=__shfl_up(U2,s);
        if (lane>=s){ U0+=p0; U1+=p1; U2+=p2; }
    }
    float Mt0=__shfl(M0,63), Mt1=__shfl(M1,63), Mt2=__shfl(M2,63);
    float Nt0=__shfl(N0,63), Nt1=__shfl(N1,63), Nt2=__shfl(N2,63);
    float mp0=Mt0-M0, mp1=Mt1-M1, mp2=Mt2-M2;   // m-psi (exclusive suffix)
    float np0=Nt0-N0, np1=Nt1-N1, np2=Nt2-N2;   // n-psi

    // partial outputs: outv = R(qpre)*M, outp = R(qpre)*U  (emit adds offsets)
    float Rp9[9]; quat2mat(qpre,Rp9);
    float pv0=Rp9[0]*M0+Rp9[1]*M1+Rp9[2]*M2;
    float pv1=Rp9[3]*M0+Rp9[4]*M1+Rp9[5]*M2;
    float pv2=Rp9[6]*M0+Rp9[7]*M1+Rp9[8]*M2;
    float pp0=Rp9[0]*U0+Rp9[1]*U1+Rp9[2]*U2;
    float pp1=Rp9[3]*U0+Rp9[4]*U1+Rp9[5]*U2;
    float pp2=Rp9[6]*U0+Rp9[7]*U1+Rp9[8]*U2;
    outv[3*k+0]=pv0; outv[3*k+1]=pv1; outv[3*k+2]=pv2;
    outp[3*k+0]=pp0; outp[3*k+1]=pp1; outp[3*k+2]=pp2;

    const long wsbase=((long)b*NCH+c)*SLOT;
    if (lane==63) {
        float* vp=vp_g+(long)(b*NCH+c)*8;
        vp[0]=pv0; vp[1]=pv1; vp[2]=pv2;
        vp[3]=pp0; vp[4]=pp1; vp[5]=pp2;
        vp[6]=td;
        // chunk params: qtot (= own qloc), qpre, Mtot, Ntot, Dtot
        cov[wsbase+45]=qloc.x; cov[wsbase+46]=qloc.y; cov[wsbase+47]=qloc.z; cov[wsbase+48]=qloc.w;
        cov[wsbase+49]=qpre.x; cov[wsbase+50]=qpre.y; cov[wsbase+51]=qpre.z; cov[wsbase+52]=qpre.w;
        cov[wsbase+53]=M0; cov[wsbase+54]=M1; cov[wsbase+55]=M2;
        cov[wsbase+56]=N0; cov[wsbase+57]=N1; cov[wsbase+58]=N2;
        cov[wsbase+59]=td;
    }

    // Jr coeffs from dq (no transcendentals):
    //  sin^2(th/2)=|dq.xyz|^2 ; c1=2*that/th2 ; sin(th)=2*|dq.xyz|*dq.w
    float th2 = wx*wx + wy*wy + wz*wz;
    float c1, c2;
    if (th2 < 1e-8f) { c1 = 0.5f - th2*(1.0f/24.0f); c2 = (1.0f/6.0f) - th2*(1.0f/120.0f); }
    else {
        float s2q = dqq.x*dqq.x + dqq.y*dqq.y + dqq.z*dqq.z;
        c1 = 2.0f*s2q/th2;
        float th = sqrtf(th2);
        float snt = 2.0f*sqrtf(s2q)*dqq.w;
        c2 = (th - snt)/(th2*th);
    }
    float J[9];
    {
        float dg = 1.0f - c2*th2;
        J[0]=dg + c2*wx*wx;      J[1]= c1*wz + c2*wx*wy;  J[2]=-c1*wy + c2*wx*wz;
        J[3]=-c1*wz + c2*wx*wy;  J[4]=dg + c2*wy*wy;      J[5]= c1*wx + c2*wy*wz;
        J[6]= c1*wy + c2*wx*wz;  J[7]=-c1*wx + c2*wy*wz;  J[8]=dg + c2*wz*wz;
    }
    float Rj[9]; quat2mat(qloc,Rj);
    float H[9]; mm_nn(Rj,J,H);
    const float gs = GCOV*d*d;
    float Gp[9];
    Gp[0]=gs*(H[0]*H[0]+H[1]*H[1]+H[2]*H[2]);
    Gp[1]=gs*(H[0]*H[3]+H[1]*H[4]+H[2]*H[5]);
    Gp[2]=gs*(H[0]*H[6]+H[1]*H[7]+H[2]*H[8]);
    Gp[4]=gs*(H[3]*H[3]+H[4]*H[4]+H[5]*H[5]);
    Gp[5]=gs*(H[3]*H[6]+H[4]*H[7]+H[5]*H[8]);
    Gp[8]=gs*(H[6]*H[6]+H[7]*H[7]+H[8]*H[8]);
    Gp[3]=Gp[1]; Gp[6]=Gp[2]; Gp[7]=Gp[5];

    const float av  = ACOV*d*d;
    const float bv  = 0.5f*ACOV*d*d*d;
    const float cv  = 0.25f*ACOV*d*d*d*d;
    const float vpd = av*tau + bv;
    const float ppd = av*tau*tau + 2.0f*bv*tau + cv;

    // core blocks
    float Crv[9], Crp[9], Cvv[9], Cvp[9], Cpp[9];
    m_skew(Gp, mp0,mp1,mp2, Crv);          // G' skew(m-psi)
    m_skew(Gp, np0,np1,np2, Crp);          // G' skew(n-psi)
    skew_m(-mp0,-mp1,-mp2, Crv, Cvv);      // skew(-m) G' skew(m)
    skew_m(-mp0,-mp1,-mp2, Crp, Cvp);
    skew_m(-np0,-np1,-np2, Crp, Cpp);

    float S45[45];
#pragma unroll
    for (int i=0;i<9;i++){ S45[i]=Crv[i]; S45[9+i]=Crp[i]; S45[18+i]=Cvp[i]; }
    S45[18]+=vpd; S45[22]+=vpd; S45[26]+=vpd;
    S45[27]=Gp[0];  S45[28]=Gp[1];  S45[29]=Gp[2];  S45[30]=Gp[4];  S45[31]=Gp[5];  S45[32]=Gp[8];
    S45[33]=Cvv[0]+av; S45[34]=Cvv[1]; S45[35]=Cvv[2]; S45[36]=Cvv[4]+av; S45[37]=Cvv[5]; S45[38]=Cvv[8]+av;
    S45[39]=Cpp[0]+ppd; S45[40]=Cpp[1]; S45[41]=Cpp[2]; S45[42]=Cpp[4]+ppd; S45[43]=Cpp[5]; S45[44]=Cpp[8]+ppd;

    // per-wave LDS transpose reduction over lanes, two rounds (23 + 22 elems)
#pragma unroll
    for (int e=0;e<23;e++) red[wid][e][lane] = S45[e];
    __syncthreads();
    float r1 = 0.f;
    if (lane < 23) {
        const float* row = &red[wid][lane][0];
        float ax=0.f, ay=0.f;
#pragma unroll
        for (int i=0;i<32;i++) {
            float2 v = reinterpret_cast<const float2*>(row)[i];
            ax += v.x; ay += v.y;
        }
        r1 = ax + ay;
    }
    __syncthreads();
#pragma unroll
    for (int e=0;e<22;e++) red[wid][e][lane] = S45[23+e];
    __syncthreads();
    float r2 = 0.f;
    if (lane < 22) {
        const float* row = &red[wid][lane][0];
        float ax=0.f, ay=0.f;
#pragma unroll
        for (int i=0;i<32;i++) {
            float2 v = reinterpret_cast<const float2*>(row)[i];
            ax += v.x; ay += v.y;
        }
        r2 = ax + ay;
    }
    if (lane < 23) cov[wsbase+lane] = r1;
    if (lane < 22) cov[wsbase+23+lane] = r2;
}

// ---------------------------------------------------------------------------
// D: per-batch scans of vel/pos chunk partials -> exclusive (V, Pp) per chunk.
// ---------------------------------------------------------------------------
__global__ __launch_bounds__(128) void k_vpscan(
    const float* __restrict__ vp_g, float* __restrict__ vpre)
{
    const int b=blockIdx.x, c=threadIdx.x, lane=c&63, w=c>>6;
    __shared__ float w0t[3];
    __shared__ float all3[NCH][3];
    const float* vp=vp_g+(long)(b*NCH+c)*8;
    float Lv0=vp[0],Lv1=vp[1],Lv2=vp[2],Sw0=vp[3],Sw1=vp[4],Sw2=vp[5],Td=vp[6];

    float i0=Lv0,i1=Lv1,i2=Lv2;
#pragma unroll
    for (int s=1;s<64;s<<=1) {
        float p0=__shfl_up(i0,s),p1=__shfl_up(i1,s),p2=__shfl_up(i2,s);
        if (lane>=s){ i0+=p0; i1+=p1; i2+=p2; }
    }
    if (w==0 && lane==63){ w0t[0]=i0; w0t[1]=i1; w0t[2]=i2; }
    __syncthreads();
    if (w==1){ i0+=w0t[0]; i1+=w0t[1]; i2+=w0t[2]; }
    all3[c][0]=i0; all3[c][1]=i1; all3[c][2]=i2;
    __syncthreads();
    float V0=(c==0)?0.f:all3[c-1][0];
    float V1=(c==0)?0.f:all3[c-1][1];
    float V2=(c==0)?0.f:all3[c-1][2];
    __syncthreads();

    float u0=V0*Td+Sw0, u1=V1*Td+Sw1, u2=V2*Td+Sw2;
    i0=u0; i1=u1; i2=u2;
#pragma unroll
    for (int s=1;s<64;s<<=1) {
        float p0=__shfl_up(i0,s),p1=__shfl_up(i1,s),p2=__shfl_up(i2,s);
        if (lane>=s){ i0+=p0; i1+=p1; i2+=p2; }
    }
    if (w==0 && lane==63){ w0t[0]=i0; w0t[1]=i1; w0t[2]=i2; }
    __syncthreads();
    if (w==1){ i0+=w0t[0]; i1+=w0t[1]; i2+=w0t[2]; }
    all3[c][0]=i0; all3[c][1]=i1; all3[c][2]=i2;
    __syncthreads();
    float P0=(c==0)?0.f:all3[c-1][0];
    float P1=(c==0)?0.f:all3[c-1][1];
    float P2=(c==0)?0.f:all3[c-1][2];

    float* o=vpre+(long)(b*NCH+c)*8;
    o[0]=V0; o[1]=V1; o[2]=V2; o[3]=P0; o[4]=P1; o[5]=P2;
}

// ---------------------------------------------------------------------------
// K4 combine math (compact layout). Phi[0..27]=D,P,Q,T.
// S (45): Arv0 Arp9 Avp18 Arr27t Avv33t App39t.
// ---------------------------------------------------------------------------
__device__ __forceinline__ void congr45(const float* Phi, const float* S, float* O)
{
    const float* D=Phi; const float* P=Phi+9; const float* Q=Phi+18; const float T=Phi[27];
    const float* Arv=S+0; const float* Arp=S+9; const float* Avp=S+18;
    float Arr[9], Avv[9], App[9];
    expand_sym(S+27,Arr); expand_sym(S+33,Avv); expand_sym(S+39,App);

    float M1[9], M2[9], M3[9], t1[9], t6[6];
    mm_nn(D,Arr,M1); mm_nn(D,Arv,M2); mm_nn(D,Arp,M3);
    mm_nt_sym(M1, D, O+27);                          // O_rr (tri)
    mm_nt(M1, P, t1);
#pragma unroll
    for (int i=0;i<9;i++) O[0+i] = t1[i] + M2[i];    // O_rv
    mm_nt(M1, Q, t1);
#pragma unroll
    for (int i=0;i<9;i++) O[9+i] = t1[i] + T*M2[i] + M3[i];  // O_rp

    float W1[9], W2[9], W3[9];
    mm_nn(P, Arr, W1);
#pragma unroll
    for (int i=0;i<3;i++)
#pragma unroll
    for (int j=0;j<3;j++) W1[3*i+j] += Arv[3*j+i];
    mm_nn(P, Arv, W2);
#pragma unroll
    for (int i=0;i<9;i++) W2[i] += Avv[i];
    mm_nn(P, Arp, W3);
#pragma unroll
    for (int i=0;i<9;i++) W3[i] += Avp[i];
    mm_nt_sym(W1, P, t6);                            // O_vv (tri)
    O[33+0]=t6[0]+W2[0]; O[33+1]=t6[1]+W2[1]; O[33+2]=t6[2]+W2[2];
    O[33+3]=t6[3]+W2[4]; O[33+4]=t6[4]+W2[5]; O[33+5]=t6[5]+W2[8];
    mm_nt(W1, Q, t1);
#pragma unroll
    for (int i=0;i<9;i++) O[18+i] = t1[i] + T*W2[i] + W3[i];  // O_vp

    float U1[9], U2[9], U3[9];
    mm_nn(Q, Arr, U1);
#pragma unroll
    for (int i=0;i<3;i++)
#pragma unroll
    for (int j=0;j<3;j++) U1[3*i+j] += T*Arv[3*j+i] + Arp[3*j+i];
    mm_nn(Q, Arv, U2);
#pragma unroll
    for (int i=0;i<3;i++)
#pragma unroll
    for (int j=0;j<3;j++) U2[3*i+j] += T*Avv[3*i+j] + Avp[3*j+i];
    mm_nn(Q, Arp, U3);
#pragma unroll
    for (int i=0;i<9;i++) U3[i] += T*Avp[i] + App[i];
    mm_nt_sym(U1, Q, t6);                            // O_pp (tri)
    O[39+0]=t6[0]+T*U2[0]+U3[0]; O[39+1]=t6[1]+T*U2[1]+U3[1]; O[39+2]=t6[2]+T*U2[2]+U3[2];
    O[39+3]=t6[3]+T*U2[4]+U3[4]; O[39+4]=t6[4]+T*U2[5]+U3[5]; O[39+5]=t6[5]+T*U2[8]+U3[8];
}

// ---------------------------------------------------------------------------
// E (merged): blocks 0..31 covcomb (scalar-factored Phi scan);
//             blocks 32..1055 feather-weight emit.
// ---------------------------------------------------------------------------
__global__ __launch_bounds__(256) void k_merged(
    const float* __restrict__ dt, const float* __restrict__ pos0,
    const float* __restrict__ vel0, const float* __restrict__ vpre,
    const float* __restrict__ cov,
    float* __restrict__ outv, float* __restrict__ outp, float* __restrict__ outc)
{
    __shared__ float stg[NCH*SLOT];  // 31,232 B compact slots (covcomb only)
    __shared__ float sc[NCH][13];    //  6,656 B scalar scan area (q,M,N,T)
    const int bid=blockIdx.x;
    const int tid=threadIdx.x, lane=tid&63, wid=tid>>6;

    if (bid < BB) {
        const int b = bid;
        // coalesced load of compact slots
        for (int idx=tid; idx<NCH*SLOT; idx+=256) stg[idx] = cov[(long)b*NCH*SLOT + idx];
        __syncthreads();

        // init scalar scan area from chunk params
        if (tid < NCH) {
            const float* g = &stg[tid*SLOT];
            sc[tid][0]=g[45]; sc[tid][1]=g[46]; sc[tid][2]=g[47]; sc[tid][3]=g[48];  // qtot
            sc[tid][4]=g[53]; sc[tid][5]=g[54]; sc[tid][6]=g[55];                    // M
            sc[tid][7]=g[56]; sc[tid][8]=g[57]; sc[tid][9]=g[58];                    // N
            sc[tid][10]=g[59];                                                       // T
        }
        __syncthreads();

        // inclusive suffix scan of factored (q,M,N,T):
        //  q' = q_b (x) q_a ; M' = M_b + R_b M_a ; N' = N_b + R_b N_a + T_a M_b
        for (int s=1;s<NCH;s<<=1) {
            bool own = tid < NCH;
            bool act = own && (tid+s) < NCH;
            Quat qb, qa; float Mb[3],Nb[3],Tb=0.f, Ma[3],Na[3],Ta=0.f;
            if (own) {
                qb.x=sc[tid][0]; qb.y=sc[tid][1]; qb.z=sc[tid][2]; qb.w=sc[tid][3];
                Mb[0]=sc[tid][4]; Mb[1]=sc[tid][5]; Mb[2]=sc[tid][6];
                Nb[0]=sc[tid][7]; Nb[1]=sc[tid][8]; Nb[2]=sc[tid][9];
                Tb=sc[tid][10];
            }
            if (act) {
                qa.x=sc[tid+s][0]; qa.y=sc[tid+s][1]; qa.z=sc[tid+s][2]; qa.w=sc[tid+s][3];
                Ma[0]=sc[tid+s][4]; Ma[1]=sc[tid+s][5]; Ma[2]=sc[tid+s][6];
                Na[0]=sc[tid+s][7]; Na[1]=sc[tid+s][8]; Na[2]=sc[tid+s][9];
                Ta=sc[tid+s][10];
            }
            __syncthreads();
            if (act) {
                Quat qc=qmul(qb,qa);
                float Rb[9]; quat2mat(qb,Rb);
                float Mc0=Mb[0]+Rb[0]*Ma[0]+Rb[1]*Ma[1]+Rb[2]*Ma[2];
                float Mc1=Mb[1]+Rb[3]*Ma[0]+Rb[4]*Ma[1]+Rb[5]*Ma[2];
                float Mc2=Mb[2]+Rb[6]*Ma[0]+Rb[7]*Ma[1]+Rb[8]*Ma[2];
                float Nc0=Nb[0]+Rb[0]*Na[0]+Rb[1]*Na[1]+Rb[2]*Na[2]+Ta*Mb[0];
                float Nc1=Nb[1]+Rb[3]*Na[0]+Rb[4]*Na[1]+Rb[5]*Na[2]+Ta*Mb[1];
                float Nc2=Nb[2]+Rb[6]*Na[0]+Rb[7]*Na[1]+Rb[8]*Na[2]+Ta*Mb[2];
                sc[tid][0]=qc.x; sc[tid][1]=qc.y; sc[tid][2]=qc.z; sc[tid][3]=qc.w;
                sc[tid][4]=Mc0; sc[tid][5]=Mc1; sc[tid][6]=Mc2;
                sc[tid][7]=Nc0; sc[tid][8]=Nc1; sc[tid][9]=Nc2;
                sc[tid][10]=Ta+Tb;
            }
            __syncthreads();
        }

        // per-chunk: build exclusive-suffix Phi + reconstruct S, congr, store O
        if (tid < NCH) {
            const float* g = &stg[tid*SLOT];
            Quat qt; qt.x=g[45]; qt.y=g[46]; qt.z=g[47]; qt.w=g[48];
            Quat qp; qp.x=g[49]; qp.y=g[50]; qp.z=g[51]; qp.w=g[52];

            float Phi[28];
            if (tid < NCH-1) {
                Quat qs; qs.x=sc[tid+1][0]; qs.y=sc[tid+1][1]; qs.z=sc[tid+1][2]; qs.w=sc[tid+1][3];
                float Ms0=sc[tid+1][4], Ms1=sc[tid+1][5], Ms2=sc[tid+1][6];
                float Ns0=sc[tid+1][7], Ns1=sc[tid+1][8], Ns2=sc[tid+1][9];
                float Ts=sc[tid+1][10];
                float Rs[9]; quat2mat(qs,Rs);
                Phi[0]=Rs[0]; Phi[1]=Rs[3]; Phi[2]=Rs[6];
                Phi[3]=Rs[1]; Phi[4]=Rs[4]; Phi[5]=Rs[7];
                Phi[6]=Rs[2]; Phi[7]=Rs[5]; Phi[8]=Rs[8];
                Quat qp1=qmul(qp,qt);                 // qpre of chunk tid+1
                float Rp1[9]; quat2mat(qp1,Rp1);
                float Pc[9]; m_skew(Rp1, -Ms0,-Ms1,-Ms2, Pc);
                float Qc[9]; m_skew(Rp1, -Ns0,-Ns1,-Ns2, Qc);
#pragma unroll
                for (int i=0;i<9;i++){ Phi[9+i]=Pc[i]; Phi[18+i]=Qc[i]; }
                Phi[27]=Ts;
            } else {
#pragma unroll
                for (int i=0;i<9;i++){ Phi[i]=(i%4==0)?1.f:0.f; Phi[9+i]=0.f; Phi[18+i]=0.f; }
                Phi[27]=0.f;
            }

            // reconstruct S blocks with outer rotations (from own compact slot)
            float Rt[9]; quat2mat(qt,Rt);
            float Rp[9]; quat2mat(qp,Rp);
            float S[45];
            {
                float Crv[9],Crp[9],Cvp9[9], e9[9], t9[9], o9[9], o6[6];
#pragma unroll
                for (int i=0;i<9;i++){ Crv[i]=g[i]; Crp[i]=g[9+i]; Cvp9[i]=g[18+i]; }
                mm_tn(Rt, Crv, t9); mm_nt(t9, Rp, o9);
#pragma unroll
                for (int i=0;i<9;i++) S[i]=o9[i];
                mm_tn(Rt, Crp, t9); mm_nt(t9, Rp, o9);
#pragma unroll
                for (int i=0;i<9;i++) S[9+i]=o9[i];
                mm_nn(Rp, Cvp9, t9); mm_nt(t9, Rp, o9);
#pragma unroll
                for (int i=0;i<9;i++) S[18+i]=o9[i];
                expand_sym(g+27, e9); mm_tn(Rt, e9, t9); mm_nn_sym(t9, Rt, o6);
#pragma unroll
                for (int i=0;i<6;i++) S[27+i]=o6[i];
                expand_sym(g+33, e9); mm_nn(Rp, e9, t9); mm_nt_sym(t9, Rp, o6);
#pragma unroll
                for (int i=0;i<6;i++) S[33+i]=o6[i];
                expand_sym(g+39, e9); mm_nn(Rp, e9, t9); mm_nt_sym(t9, Rp, o6);
#pragma unroll
                for (int i=0;i<6;i++) S[39+i]=o6[i];
            }
            float O[45];
            congr45(Phi, S, O);
            float* w = &stg[tid*SLOT];
#pragma unroll
            for (int i=0;i<45;i++) w[i] = O[i];
        }
        __syncthreads();

        // tree sum of the 45-float terms (stride 61, odd -> conflict-free)
        for (int s=64;s>0;s>>=1) {
            if (tid < s) {
#pragma unroll
                for (int i=0;i<45;i++) stg[tid*SLOT+i] += stg[(tid+s)*SLOT+i];
            }
            __syncthreads();
        }

        if (tid < 81) {
            int i = tid/9, j = tid%9;
            int bi = i/3, ii = i%3, bj = j/3, jj = j%3;
            int lo = (ii<jj)?ii:jj, hi = (ii<jj)?jj:ii;
            int tix = (lo==0)?hi:((lo==1)?(2+hi):5);
            const float* S0 = &stg[0];
            float v;
            if      (bi==0 && bj==0) v = S0[27 + tix];        // Arr
            else if (bi==0 && bj==1) v = S0[0  + 3*ii + jj];  // Arv
            else if (bi==0 && bj==2) v = S0[9  + 3*ii + jj];  // Arp
            else if (bi==1 && bj==0) v = S0[0  + 3*jj + ii];  // Arv^T
            else if (bi==1 && bj==1) v = S0[33 + tix];        // Avv
            else if (bi==1 && bj==2) v = S0[18 + 3*ii + jj];  // Avp
            else if (bi==2 && bj==0) v = S0[9  + 3*jj + ii];  // Arp^T
            else if (bi==2 && bj==1) v = S0[18 + 3*jj + ii];  // Avp^T
            else                     v = S0[39 + tix];        // App
            outc[(long)b*81 + tid] = v;
        }
        return;
    }

    // ---- feather-weight emit: RMW partials with chunk offsets ----
    const int ebid = bid - BB;
    const int b = ebid>>5, wg = ebid&31;
    const int c = wg*4+wid;
    const long k = (long)b*FF+(long)c*64+lane;

    float td = dt[k];
#pragma unroll
    for (int s=1;s<64;s<<=1) {
        float p=__shfl_up(td,s);
        if (lane>=s) td+=p;
    }

    const float* vr=vpre+(long)(b*NCH+c)*8;
    float V0=vr[0],V1=vr[1],V2=vr[2],P0=vr[3],P1=vr[4],P2=vr[5];
    float v0x=vel0[3*b+0], v0y=vel0[3*b+1], v0z=vel0[3*b+2];
    float p0x=pos0[3*b+0], p0y=pos0[3*b+1], p0z=pos0[3*b+2];

    float pv0=outv[3*k+0], pv1=outv[3*k+1], pv2=outv[3*k+2];
    float pp0=outp[3*k+0], pp1=outp[3*k+1], pp2=outp[3*k+2];

    outv[3*k+0]=v0x+V0+pv0;
    outv[3*k+1]=v0y+V1+pv1;
    outv[3*k+2]=v0z+V2+pv2;
    outp[3*k+0]=p0x+P0+V0*td+pp0;
    outp[3*k+1]=p0y+P1+V1*td+pp1;
    outp[3*k+2]=p0z+P2+V2*td+pp2;
}

// ---------------------------------------------------------------------------
extern "C" void kernel_launch(void* const* d_in, const int* in_sizes, int n_in,
                              void* d_out, int out_size, void* d_ws, size_t ws_size,
                              hipStream_t stream)
{
    const float* dt   = (const float*)d_in[0];
    const float* gyro = (const float*)d_in[1];
    const float* acc  = (const float*)d_in[2];
    const float* pos0 = (const float*)d_in[3];
    const float* vel0 = (const float*)d_in[4];

    float* out  = (float*)d_out;
    float* outq = out;
    float* outv = out  + (long)BB*FF*4;
    float* outp = outv + (long)BB*FF*3;
    float* outc = outp + (long)BB*FF*3;

    float* ws   = (float*)d_ws;           // 1,392,640 bytes used
    float* cov  = ws + COV_OFF;
    float* vpre = ws + VPRE_OFF;
    float* qtot = ws + QTOT_OFF;
    float* qpre = ws + QPRE_OFF;
    float* vp   = ws + VP_OFF;

    hipLaunchKernelGGL(k_chunktot, dim3(BB*32),    dim3(256), 0, stream, dt, gyro, qtot, outq);
    hipLaunchKernelGGL(k_qpre,     dim3(BB),       dim3(128), 0, stream, qtot, qpre);
    hipLaunchKernelGGL(k_main,     dim3(BB*32),    dim3(256), 0, stream, dt, gyro, acc, qpre, outq, cov, vp, outv, outp);
    hipLaunchKernelGGL(k_vpscan,   dim3(BB),       dim3(128), 0, stream, vp, vpre);
    hipLaunchKernelGGL(k_merged,   dim3(BB*32+BB), dim3(256), 0, stream, dt, pos0, vel0, vpre, cov, outv, outp, outc);
}

// Round 12
// 36.538 us; speedup vs baseline: 1.8020x; 1.0849x over previous
//
#include <hip/hip_runtime.h>

// IMU preintegration, B=32 batches, F=8192 steps. 5-kernel pipeline:
//  A k_chunktot : per-step qexp + chunk-local quat prefix -> qloc staged in
//                 outq region (all lanes) + chunk totals (ws)
//  B k_qpre     : per-batch exclusive scan of 128 chunk quats      (ws)
//  C k_main     : loads qloc (no sincos, no quat scan), RMW outq=qpre*qloc,
//                 partial outv/outp + chunk partials (ws) + factored cov
//                 composites (ws, 64-float slots).
//  D k_vpscan   : per-batch scans of chunk partials -> (V,Pp) per chunk
//  E k_merged   : blocks 0-31 covcomb (register shfl scan + butterfly reduce,
//                 float4 staging, 4 barriers); blocks 32-1055 feather emit.
// d_ws: cov 32*128*64 + vpre 32768 + qtot 16384 + qpre 16384 + vp 32768
//       = 360448 floats = 1,441,792 bytes.

#define BB 32
#define FF 8192
#define NCH 128
#define SLOT 64
#define GRAV 9.81007f
#define GCOV (0.0032f*0.0032f)
#define ACOV (0.08f*0.08f)

// ws float offsets
#define COV_OFF  0
#define VPRE_OFF 262144
#define QTOT_OFF 294912
#define QPRE_OFF 311296
#define VP_OFF   327680

struct Quat { float x, y, z, w; };

__device__ __forceinline__ Quat qmul(const Quat a, const Quat b) {
    Quat r;
    r.x = a.w*b.x + a.x*b.w + a.y*b.z - a.z*b.y;
    r.y = a.w*b.y - a.x*b.z + a.y*b.w + a.z*b.x;
    r.z = a.w*b.z + a.x*b.y - a.y*b.x + a.z*b.w;
    r.w = a.w*b.w - a.x*b.x - a.y*b.y - a.z*b.z;
    return r;
}

__device__ __forceinline__ Quat qshfl_up(const Quat a, int s) {
    Quat r;
    r.x=__shfl_up(a.x,s); r.y=__shfl_up(a.y,s);
    r.z=__shfl_up(a.z,s); r.w=__shfl_up(a.w,s);
    return r;
}

__device__ __forceinline__ Quat qexp3(float px, float py, float pz) {
    float th2 = px*px + py*py + pz*pz;
    float s, w;
    if (th2 < 1e-8f) {
        s = 0.5f - th2 * (1.0f/48.0f);
        w = 1.0f - th2 * 0.125f;
    } else {
        float th = sqrtf(th2);
        s = sinf(0.5f*th) / th;
        w = cosf(0.5f*th);
    }
    Quat q; q.x=px*s; q.y=py*s; q.z=pz*s; q.w=w; return q;
}

__device__ __forceinline__ void quat2mat(const Quat q, float* R) {
    float x=q.x, y=q.y, z=q.z, w=q.w;
    R[0]=1.0f-2.0f*(y*y+z*z); R[1]=2.0f*(x*y-z*w);       R[2]=2.0f*(x*z+y*w);
    R[3]=2.0f*(x*y+z*w);      R[4]=1.0f-2.0f*(x*x+z*z);  R[5]=2.0f*(y*z-x*w);
    R[6]=2.0f*(x*z-y*w);      R[7]=2.0f*(y*z+x*w);       R[8]=1.0f-2.0f*(x*x+y*y);
}

__device__ __forceinline__ void mm_nn(const float* A, const float* B, float* C) {
#pragma unroll
    for (int i=0;i<3;i++)
#pragma unroll
    for (int j=0;j<3;j++)
        C[3*i+j] = A[3*i+0]*B[0+j] + A[3*i+1]*B[3+j] + A[3*i+2]*B[6+j];
}

__device__ __forceinline__ void mm_nt(const float* A, const float* B, float* C) {
#pragma unroll
    for (int i=0;i<3;i++)
#pragma unroll
    for (int j=0;j<3;j++)
        C[3*i+j] = A[3*i+0]*B[3*j+0] + A[3*i+1]*B[3*j+1] + A[3*i+2]*B[3*j+2];
}

__device__ __forceinline__ void mm_tn(const float* A, const float* B, float* C) {
#pragma unroll
    for (int i=0;i<3;i++)
#pragma unroll
    for (int j=0;j<3;j++)
        C[3*i+j] = A[0+i]*B[0+j] + A[3+i]*B[3+j] + A[6+i]*B[6+j];
}

// entries (0,0)(0,1)(0,2)(1,1)(1,2)(2,2) of A*B^T
__device__ __forceinline__ void mm_nt_sym(const float* A, const float* B, float* O6) {
    O6[0]=A[0]*B[0]+A[1]*B[1]+A[2]*B[2];
    O6[1]=A[0]*B[3]+A[1]*B[4]+A[2]*B[5];
    O6[2]=A[0]*B[6]+A[1]*B[7]+A[2]*B[8];
    O6[3]=A[3]*B[3]+A[4]*B[4]+A[5]*B[5];
    O6[4]=A[3]*B[6]+A[4]*B[7]+A[5]*B[8];
    O6[5]=A[6]*B[6]+A[7]*B[7]+A[8]*B[8];
}

// entries (0,0)(0,1)(0,2)(1,1)(1,2)(2,2) of A*B
__device__ __forceinline__ void mm_nn_sym(const float* A, const float* B, float* O6) {
    O6[0]=A[0]*B[0]+A[1]*B[3]+A[2]*B[6];
    O6[1]=A[0]*B[1]+A[1]*B[4]+A[2]*B[7];
    O6[2]=A[0]*B[2]+A[1]*B[5]+A[2]*B[8];
    O6[3]=A[3]*B[1]+A[4]*B[4]+A[5]*B[7];
    O6[4]=A[3]*B[2]+A[4]*B[5]+A[5]*B[8];
    O6[5]=A[6]*B[2]+A[7]*B[5]+A[8]*B[8];
}

__device__ __forceinline__ void expand_sym(const float* t, float* M) {
    M[0]=t[0]; M[1]=t[1]; M[2]=t[2];
    M[3]=t[1]; M[4]=t[3]; M[5]=t[4];
    M[6]=t[2]; M[7]=t[4]; M[8]=t[5];
}

// C = M * skew(v)
__device__ __forceinline__ void m_skew(const float* M, float v0, float v1, float v2, float* C) {
#pragma unroll
    for (int i=0;i<3;i++) {
        C[3*i+0] = M[3*i+1]*v2 - M[3*i+2]*v1;
        C[3*i+1] = M[3*i+2]*v0 - M[3*i+0]*v2;
        C[3*i+2] = M[3*i+0]*v1 - M[3*i+1]*v0;
    }
}

// C = skew(w) * M
__device__ __forceinline__ void skew_m(float w0, float w1, float w2, const float* M, float* C) {
#pragma unroll
    for (int j=0;j<3;j++) {
        C[0+j] = -w2*M[3+j] + w1*M[6+j];
        C[3+j] =  w2*M[0+j] - w0*M[6+j];
        C[6+j] = -w1*M[0+j] + w0*M[3+j];
    }
}

// ---------------------------------------------------------------------------
// A: chunk quat prefix. Writes per-lane qloc to outq region + lane63 totals.
// ---------------------------------------------------------------------------
__global__ __launch_bounds__(256) void k_chunktot(
    const float* __restrict__ dt, const float* __restrict__ gyro,
    float* __restrict__ qtot, float* __restrict__ outq)
{
    const int bid=blockIdx.x, b=bid>>5, wg=bid&31;
    const int tid=threadIdx.x, lane=tid&63, wid=tid>>6;
    const int c=wg*4+wid;
    const long k=(long)b*FF+(long)c*64+lane;
    float d=dt[k];
    Quat inc=qexp3(gyro[3*k+0]*d, gyro[3*k+1]*d, gyro[3*k+2]*d);
#pragma unroll
    for (int s=1;s<64;s<<=1) {
        Quat p=qshfl_up(inc,s);
        if (lane>=s) inc=qmul(p,inc);
    }
    { float4 o; o.x=inc.x; o.y=inc.y; o.z=inc.z; o.w=inc.w;
      reinterpret_cast<float4*>(outq)[k]=o; }
    if (lane==63) {
        float4 o; o.x=inc.x; o.y=inc.y; o.z=inc.z; o.w=inc.w;
        reinterpret_cast<float4*>(qtot)[b*NCH+c]=o;
    }
}

// ---------------------------------------------------------------------------
// B: exclusive scan of 128 chunk quats per batch. 1 WG/batch, 128 threads.
// ---------------------------------------------------------------------------
__global__ __launch_bounds__(128) void k_qpre(
    const float* __restrict__ qtot, float* __restrict__ qpre)
{
    const int b=blockIdx.x, c=threadIdx.x, lane=c&63, w=c>>6;
    __shared__ float4 w0t;
    __shared__ float4 all[NCH];
    float4 t=reinterpret_cast<const float4*>(qtot)[b*NCH+c];
    Quat inc; inc.x=t.x; inc.y=t.y; inc.z=t.z; inc.w=t.w;
#pragma unroll
    for (int s=1;s<64;s<<=1) {
        Quat p=qshfl_up(inc,s);
        if (lane>=s) inc=qmul(p,inc);
    }
    if (w==0 && lane==63) { float4 o; o.x=inc.x;o.y=inc.y;o.z=inc.z;o.w=inc.w; w0t=o; }
    __syncthreads();
    if (w==1) { Quat p; p.x=w0t.x;p.y=w0t.y;p.z=w0t.z;p.w=w0t.w; inc=qmul(p,inc); }
    { float4 o; o.x=inc.x;o.y=inc.y;o.z=inc.z;o.w=inc.w; all[c]=o; }
    __syncthreads();
    float4 pre;
    if (c==0) { pre.x=0.f;pre.y=0.f;pre.z=0.f;pre.w=1.f; }
    else pre=all[c-1];
    reinterpret_cast<float4*>(qpre)[b*NCH+c]=pre;
}

// ---------------------------------------------------------------------------
// C: main fused kernel. Loads staged qloc; no transcendentals, no quat scan.
// ---------------------------------------------------------------------------
#define RSTR 66
__global__ __launch_bounds__(256) void k_main(
    const float* __restrict__ dt, const float* __restrict__ gyro,
    const float* __restrict__ acc, const float* __restrict__ qpre_g,
    float* __restrict__ outq, float* __restrict__ cov, float* __restrict__ vp_g,
    float* __restrict__ outv, float* __restrict__ outp)
{
    __shared__ float red[4][23][RSTR];   // 24,288 B
    const int bid=blockIdx.x, b=bid>>5, wg=bid&31;
    const int tid=threadIdx.x, lane=tid&63, wid=tid>>6;
    const int c=wg*4+wid;
    const long k=(long)b*FF+(long)c*64+lane;

    const float d=dt[k];
    const float wx=gyro[3*k+0]*d, wy=gyro[3*k+1]*d, wz=gyro[3*k+2]*d;

    // staged within-chunk inclusive quat prefix
    Quat qloc;
    { float4 t=reinterpret_cast<const float4*>(outq)[k];
      qloc.x=t.x; qloc.y=t.y; qloc.z=t.z; qloc.w=t.w; }
    float4 tp=reinterpret_cast<const float4*>(qpre_g)[b*NCH+c];
    Quat qpre; qpre.x=tp.x; qpre.y=tp.y; qpre.z=tp.z; qpre.w=tp.w;
    Quat qi=qmul(qpre,qloc);
    { float4 o; o.x=qi.x;o.y=qi.y;o.z=qi.z;o.w=qi.w;
      reinterpret_cast<float4*>(outq)[k]=o; }

    Quat ql1=qshfl_up(qloc,1);
    if (lane==0) { ql1.x=0.f; ql1.y=0.f; ql1.z=0.f; ql1.w=1.f; }
    // dq = conj(ql1) (x) qloc   (per-step increment, for Jr coeffs)
    Quat cq; cq.x=-ql1.x; cq.y=-ql1.y; cq.z=-ql1.z; cq.w=ql1.w;
    Quat dqq=qmul(cq,qloc);

    // a = acc - R(qi)^T g
    float a0=acc[3*k+0]-GRAV*2.0f*(qi.x*qi.z-qi.y*qi.w);
    float a1=acc[3*k+1]-GRAV*2.0f*(qi.y*qi.z+qi.x*qi.w);
    float a2=acc[3*k+2]-GRAV*(1.0f-2.0f*(qi.x*qi.x+qi.y*qi.y));

    // b = R(qloc_excl) * a ;  m = d*b
    float Rl[9]; quat2mat(ql1,Rl);
    float b0=Rl[0]*a0+Rl[1]*a1+Rl[2]*a2;
    float b1=Rl[3]*a0+Rl[4]*a1+Rl[5]*a2;
    float b2=Rl[6]*a0+Rl[7]*a1+Rl[8]*a2;
    float m0=d*b0, m1=d*b1, m2=d*b2;

    // inclusive prefix scans: td (dt), M (m)
    float td=d, M0=m0, M1=m1, M2=m2;
#pragma unroll
    for (int s=1;s<64;s<<=1) {
        float p3=__shfl_up(td,s), p0=__shfl_up(M0,s), p1=__shfl_up(M1,s), p2=__shfl_up(M2,s);
        if (lane>=s) { td+=p3; M0+=p0; M1+=p1; M2+=p2; }
    }
    float Dtot=__shfl(td,63);
    float tau = Dtot - td;                 // exclusive suffix dt sum
    float cn = 0.5f*d + tau;
    float n0=cn*m0, n1=cn*m1, n2=cn*m2;
    float N0=n0, N1=n1, N2=n2;
#pragma unroll
    for (int s=1;s<64;s<<=1) {
        float p0=__shfl_up(N0,s),p1=__shfl_up(N1,s),p2=__shfl_up(N2,s);
        if (lane>=s){ N0+=p0; N1+=p1; N2+=p2; }
    }
    // u for pos partial: u = (M - 0.5 m) * d  (prefix scan)
    float u0=(M0-0.5f*m0)*d, u1=(M1-0.5f*m1)*d, u2=(M2-0.5f*m2)*d;
    float U0=u0, U1=u1, U2=u2;
#pragma unroll
    for (int s=1;s<64;s<<=1) {
        float p0=__shfl_up(U0,s),p1=__shfl_up(U1,s),p2=__shfl_up(U2,s);
        if (lane>=s){ U0+=p0; U1+=p1; U2+=p2; }
    }
    float Mt0=__shfl(M0,63), Mt1=__shfl(M1,63), Mt2=__shfl(M2,63);
    float Nt0=__shfl(N0,63), Nt1=__shfl(N1,63), Nt2=__shfl(N2,63);
    float mp0=Mt0-M0, mp1=Mt1-M1, mp2=Mt2-M2;   // m-psi (exclusive suffix)
    float np0=Nt0-N0, np1=Nt1-N1, np2=Nt2-N2;   // n-psi

    // partial outputs: outv = R(qpre)*M, outp = R(qpre)*U  (emit adds offsets)
    float Rp9[9]; quat2mat(qpre,Rp9);
    float pv0=Rp9[0]*M0+Rp9[1]*M1+Rp9[2]*M2;
    float pv1=Rp9[3]*M0+Rp9[4]*M1+Rp9[5]*M2;
    float pv2=Rp9[6]*M0+Rp9[7]*M1+Rp9[8]*M2;
    float pp0=Rp9[0]*U0+Rp9[1]*U1+Rp9[2]*U2;
    float pp1=Rp9[3]*U0+Rp9[4]*U1+Rp9[5]*U2;
    float pp2=Rp9[6]*U0+Rp9[7]*U1+Rp9[8]*U2;
    outv[3*k+0]=pv0; outv[3*k+1]=pv1; outv[3*k+2]=pv2;
    outp[3*k+0]=pp0; outp[3*k+1]=pp1; outp[3*k+2]=pp2;

    const long wsbase=((long)b*NCH+c)*SLOT;
    if (lane==63) {
        float* vp=vp_g+(long)(b*NCH+c)*8;
        vp[0]=pv0; vp[1]=pv1; vp[2]=pv2;
        vp[3]=pp0; vp[4]=pp1; vp[5]=pp2;
        vp[6]=td;
        // chunk params: qtot (= own qloc), qpre, Mtot, Ntot, Dtot
        cov[wsbase+45]=qloc.x; cov[wsbase+46]=qloc.y; cov[wsbase+47]=qloc.z; cov[wsbase+48]=qloc.w;
        cov[wsbase+49]=qpre.x; cov[wsbase+50]=qpre.y; cov[wsbase+51]=qpre.z; cov[wsbase+52]=qpre.w;
        cov[wsbase+53]=M0; cov[wsbase+54]=M1; cov[wsbase+55]=M2;
        cov[wsbase+56]=N0; cov[wsbase+57]=N1; cov[wsbase+58]=N2;
        cov[wsbase+59]=td;
    }

    // Jr coeffs from dq (no transcendentals)
    float th2 = wx*wx + wy*wy + wz*wz;
    float c1, c2;
    if (th2 < 1e-8f) { c1 = 0.5f - th2*(1.0f/24.0f); c2 = (1.0f/6.0f) - th2*(1.0f/120.0f); }
    else {
        float s2q = dqq.x*dqq.x + dqq.y*dqq.y + dqq.z*dqq.z;
        c1 = 2.0f*s2q/th2;
        float th = sqrtf(th2);
        float snt = 2.0f*sqrtf(s2q)*dqq.w;
        c2 = (th - snt)/(th2*th);
    }
    float J[9];
    {
        float dg = 1.0f - c2*th2;
        J[0]=dg + c2*wx*wx;      J[1]= c1*wz + c2*wx*wy;  J[2]=-c1*wy + c2*wx*wz;
        J[3]=-c1*wz + c2*wx*wy;  J[4]=dg + c2*wy*wy;      J[5]= c1*wx + c2*wy*wz;
        J[6]= c1*wy + c2*wx*wz;  J[7]=-c1*wx + c2*wy*wz;  J[8]=dg + c2*wz*wz;
    }
    float Rj[9]; quat2mat(qloc,Rj);
    float H[9]; mm_nn(Rj,J,H);
    const float gs = GCOV*d*d;
    float Gp[9];
    Gp[0]=gs*(H[0]*H[0]+H[1]*H[1]+H[2]*H[2]);
    Gp[1]=gs*(H[0]*H[3]+H[1]*H[4]+H[2]*H[5]);
    Gp[2]=gs*(H[0]*H[6]+H[1]*H[7]+H[2]*H[8]);
    Gp[4]=gs*(H[3]*H[3]+H[4]*H[4]+H[5]*H[5]);
    Gp[5]=gs*(H[3]*H[6]+H[4]*H[7]+H[5]*H[8]);
    Gp[8]=gs*(H[6]*H[6]+H[7]*H[7]+H[8]*H[8]);
    Gp[3]=Gp[1]; Gp[6]=Gp[2]; Gp[7]=Gp[5];

    const float av  = ACOV*d*d;
    const float bv  = 0.5f*ACOV*d*d*d;
    const float cv  = 0.25f*ACOV*d*d*d*d;
    const float vpd = av*tau + bv;
    const float ppd = av*tau*tau + 2.0f*bv*tau + cv;

    // core blocks
    float Crv[9], Crp[9], Cvv[9], Cvp[9], Cpp[9];
    m_skew(Gp, mp0,mp1,mp2, Crv);          // G' skew(m-psi)
    m_skew(Gp, np0,np1,np2, Crp);          // G' skew(n-psi)
    skew_m(-mp0,-mp1,-mp2, Crv, Cvv);      // skew(-m) G' skew(m)
    skew_m(-mp0,-mp1,-mp2, Crp, Cvp);
    skew_m(-np0,-np1,-np2, Crp, Cpp);

    float S45[45];
#pragma unroll
    for (int i=0;i<9;i++){ S45[i]=Crv[i]; S45[9+i]=Crp[i]; S45[18+i]=Cvp[i]; }
    S45[18]+=vpd; S45[22]+=vpd; S45[26]+=vpd;
    S45[27]=Gp[0];  S45[28]=Gp[1];  S45[29]=Gp[2];  S45[30]=Gp[4];  S45[31]=Gp[5];  S45[32]=Gp[8];
    S45[33]=Cvv[0]+av; S45[34]=Cvv[1]; S45[35]=Cvv[2]; S45[36]=Cvv[4]+av; S45[37]=Cvv[5]; S45[38]=Cvv[8]+av;
    S45[39]=Cpp[0]+ppd; S45[40]=Cpp[1]; S45[41]=Cpp[2]; S45[42]=Cpp[4]+ppd; S45[43]=Cpp[5]; S45[44]=Cpp[8]+ppd;

    // per-wave LDS transpose reduction over lanes, two rounds (23 + 22 elems)
#pragma unroll
    for (int e=0;e<23;e++) red[wid][e][lane] = S45[e];
    __syncthreads();
    float r1 = 0.f;
    if (lane < 23) {
        const float* row = &red[wid][lane][0];
        float ax=0.f, ay=0.f;
#pragma unroll
        for (int i=0;i<32;i++) {
            float2 v = reinterpret_cast<const float2*>(row)[i];
            ax += v.x; ay += v.y;
        }
        r1 = ax + ay;
    }
    __syncthreads();
#pragma unroll
    for (int e=0;e<22;e++) red[wid][e][lane] = S45[23+e];
    __syncthreads();
    float r2 = 0.f;
    if (lane < 22) {
        const float* row = &red[wid][lane][0];
        float ax=0.f, ay=0.f;
#pragma unroll
        for (int i=0;i<32;i++) {
            float2 v = reinterpret_cast<const float2*>(row)[i];
            ax += v.x; ay += v.y;
        }
        r2 = ax + ay;
    }
    if (lane < 23) cov[wsbase+lane] = r1;
    if (lane < 22) cov[wsbase+23+lane] = r2;
}

// ---------------------------------------------------------------------------
// D: per-batch scans of vel/pos chunk partials -> exclusive (V, Pp) per chunk.
// ---------------------------------------------------------------------------
__global__ __launch_bounds__(128) void k_vpscan(
    const float* __restrict__ vp_g, float* __restrict__ vpre)
{
    const int b=blockIdx.x, c=threadIdx.x, lane=c&63, w=c>>6;
    __shared__ float w0t[3];
    __shared__ float all3[NCH][3];
    const float* vp=vp_g+(long)(b*NCH+c)*8;
    float Lv0=vp[0],Lv1=vp[1],Lv2=vp[2],Sw0=vp[3],Sw1=vp[4],Sw2=vp[5],Td=vp[6];

    float i0=Lv0,i1=Lv1,i2=Lv2;
#pragma unroll
    for (int s=1;s<64;s<<=1) {
        float p0=__shfl_up(i0,s),p1=__shfl_up(i1,s),p2=__shfl_up(i2,s);
        if (lane>=s){ i0+=p0; i1+=p1; i2+=p2; }
    }
    if (w==0 && lane==63){ w0t[0]=i0; w0t[1]=i1; w0t[2]=i2; }
    __syncthreads();
    if (w==1){ i0+=w0t[0]; i1+=w0t[1]; i2+=w0t[2]; }
    all3[c][0]=i0; all3[c][1]=i1; all3[c][2]=i2;
    __syncthreads();
    float V0=(c==0)?0.f:all3[c-1][0];
    float V1=(c==0)?0.f:all3[c-1][1];
    float V2=(c==0)?0.f:all3[c-1][2];
    __syncthreads();

    float u0=V0*Td+Sw0, u1=V1*Td+Sw1, u2=V2*Td+Sw2;
    i0=u0; i1=u1; i2=u2;
#pragma unroll
    for (int s=1;s<64;s<<=1) {
        float p0=__shfl_up(i0,s),p1=__shfl_up(i1,s),p2=__shfl_up(i2,s);
        if (lane>=s){ i0+=p0; i1+=p1; i2+=p2; }
    }
    if (w==0 && lane==63){ w0t[0]=i0; w0t[1]=i1; w0t[2]=i2; }
    __syncthreads();
    if (w==1){ i0+=w0t[0]; i1+=w0t[1]; i2+=w0t[2]; }
    all3[c][0]=i0; all3[c][1]=i1; all3[c][2]=i2;
    __syncthreads();
    float P0=(c==0)?0.f:all3[c-1][0];
    float P1=(c==0)?0.f:all3[c-1][1];
    float P2=(c==0)?0.f:all3[c-1][2];

    float* o=vpre+(long)(b*NCH+c)*8;
    o[0]=V0; o[1]=V1; o[2]=V2; o[3]=P0; o[4]=P1; o[5]=P2;
}

// ---------------------------------------------------------------------------
// K4 combine math (compact layout). Phi[0..27]=D,P,Q,T.
// S (45): Arv0 Arp9 Avp18 Arr27t Avv33t App39t.
// ---------------------------------------------------------------------------
__device__ __forceinline__ void congr45(const float* Phi, const float* S, float* O)
{
    const float* D=Phi; const float* P=Phi+9; const float* Q=Phi+18; const float T=Phi[27];
    const float* Arv=S+0; const float* Arp=S+9; const float* Avp=S+18;
    float Arr[9], Avv[9], App[9];
    expand_sym(S+27,Arr); expand_sym(S+33,Avv); expand_sym(S+39,App);

    float M1[9], M2[9], M3[9], t1[9], t6[6];
    mm_nn(D,Arr,M1); mm_nn(D,Arv,M2); mm_nn(D,Arp,M3);
    mm_nt_sym(M1, D, O+27);                          // O_rr (tri)
    mm_nt(M1, P, t1);
#pragma unroll
    for (int i=0;i<9;i++) O[0+i] = t1[i] + M2[i];    // O_rv
    mm_nt(M1, Q, t1);
#pragma unroll
    for (int i=0;i<9;i++) O[9+i] = t1[i] + T*M2[i] + M3[i];  // O_rp

    float W1[9], W2[9], W3[9];
    mm_nn(P, Arr, W1);
#pragma unroll
    for (int i=0;i<3;i++)
#pragma unroll
    for (int j=0;j<3;j++) W1[3*i+j] += Arv[3*j+i];
    mm_nn(P, Arv, W2);
#pragma unroll
    for (int i=0;i<9;i++) W2[i] += Avv[i];
    mm_nn(P, Arp, W3);
#pragma unroll
    for (int i=0;i<9;i++) W3[i] += Avp[i];
    mm_nt_sym(W1, P, t6);                            // O_vv (tri)
    O[33+0]=t6[0]+W2[0]; O[33+1]=t6[1]+W2[1]; O[33+2]=t6[2]+W2[2];
    O[33+3]=t6[3]+W2[4]; O[33+4]=t6[4]+W2[5]; O[33+5]=t6[5]+W2[8];
    mm_nt(W1, Q, t1);
#pragma unroll
    for (int i=0;i<9;i++) O[18+i] = t1[i] + T*W2[i] + W3[i];  // O_vp

    float U1[9], U2[9], U3[9];
    mm_nn(Q, Arr, U1);
#pragma unroll
    for (int i=0;i<3;i++)
#pragma unroll
    for (int j=0;j<3;j++) U1[3*i+j] += T*Arv[3*j+i] + Arp[3*j+i];
    mm_nn(Q, Arv, U2);
#pragma unroll
    for (int i=0;i<3;i++)
#pragma unroll
    for (int j=0;j<3;j++) U2[3*i+j] += T*Avv[3*i+j] + Avp[3*j+i];
    mm_nn(Q, Arp, U3);
#pragma unroll
    for (int i=0;i<9;i++) U3[i] += T*Avp[i] + App[i];
    mm_nt_sym(U1, Q, t6);                            // O_pp (tri)
    O[39+0]=t6[0]+T*U2[0]+U3[0]; O[39+1]=t6[1]+T*U2[1]+U3[1]; O[39+2]=t6[2]+T*U2[2]+U3[2];
    O[39+3]=t6[3]+T*U2[4]+U3[4]; O[39+4]=t6[4]+T*U2[5]+U3[5]; O[39+5]=t6[5]+T*U2[8]+U3[8];
}

// ---------------------------------------------------------------------------
// E (merged): blocks 0..31 covcomb (register shfl scan + butterfly reduce);
//             blocks 32..1055 feather-weight emit.
// ---------------------------------------------------------------------------
__global__ __launch_bounds__(256) void k_merged(
    const float* __restrict__ dt, const float* __restrict__ pos0,
    const float* __restrict__ vel0, const float* __restrict__ vpre,
    const float* __restrict__ cov,
    float* __restrict__ outv, float* __restrict__ outp, float* __restrict__ outc)
{
    __shared__ float stg[NCH*SLOT];  // 32,768 B compact slots (covcomb only)
    __shared__ float sc[NCH][12];    //  6,144 B published suffix params
    __shared__ float hand[12];       //  cross-wave handoff
    __shared__ float wsum[2][45];    //  wave partial sums
    const int bid=blockIdx.x;
    const int tid=threadIdx.x, lane=tid&63, wid=tid>>6;

    if (bid < BB) {
        const int b = bid;
        // vectorized coalesced load: 8192 floats = 2048 float4 (8/thread)
        const float4* src=reinterpret_cast<const float4*>(cov + (long)b*NCH*SLOT);
        float4* dst=reinterpret_cast<float4*>(stg);
#pragma unroll
        for (int j=0;j<8;j++) dst[j*256+tid]=src[j*256+tid];
        __syncthreads();

        const bool own = tid < NCH;   // waves 0,1 own chunks

        // register suffix scan of factored (q,M,N,T)
        float q0,q1,q2,q3, Mv0,Mv1,Mv2, Nv0,Nv1,Nv2, Tv;
        if (own) {
            const float* g=&stg[tid*SLOT];
            q0=g[45]; q1=g[46]; q2=g[47]; q3=g[48];
            Mv0=g[53]; Mv1=g[54]; Mv2=g[55];
            Nv0=g[56]; Nv1=g[57]; Nv2=g[58];
            Tv=g[59];
        } else { q0=q1=q2=0.f; q3=1.f; Mv0=Mv1=Mv2=Nv0=Nv1=Nv2=0.f; Tv=0.f; }

        if (own) {
            // in-wave suffix scan: combine b=self(earlier) with a=lane+s(later)
#pragma unroll
            for (int s=1;s<64;s<<=1) {
                float a0=__shfl_down(q0,s), a1=__shfl_down(q1,s), a2=__shfl_down(q2,s), a3=__shfl_down(q3,s);
                float am0=__shfl_down(Mv0,s), am1=__shfl_down(Mv1,s), am2=__shfl_down(Mv2,s);
                float an0=__shfl_down(Nv0,s), an1=__shfl_down(Nv1,s), an2=__shfl_down(Nv2,s);
                float aT=__shfl_down(Tv,s);
                if (lane+s < 64) {
                    Quat qb; qb.x=q0; qb.y=q1; qb.z=q2; qb.w=q3;
                    Quat qa; qa.x=a0; qa.y=a1; qa.z=a2; qa.w=a3;
                    Quat qc=qmul(qb,qa);
                    float Rb[9]; quat2mat(qb,Rb);
                    float Mc0=Mv0+Rb[0]*am0+Rb[1]*am1+Rb[2]*am2;
                    float Mc1=Mv1+Rb[3]*am0+Rb[4]*am1+Rb[5]*am2;
                    float Mc2=Mv2+Rb[6]*am0+Rb[7]*am1+Rb[8]*am2;
                    float Nc0=Nv0+Rb[0]*an0+Rb[1]*an1+Rb[2]*an2+aT*Mv0;
                    float Nc1=Nv1+Rb[3]*an0+Rb[4]*an1+Rb[5]*an2+aT*Mv1;
                    float Nc2=Nv2+Rb[6]*an0+Rb[7]*an1+Rb[8]*an2+aT*Mv2;
                    q0=qc.x; q1=qc.y; q2=qc.z; q3=qc.w;
                    Mv0=Mc0; Mv1=Mc1; Mv2=Mc2;
                    Nv0=Nc0; Nv1=Nc1; Nv2=Nc2;
                    Tv+=aT;
                }
            }
            if (wid==1 && lane==0) {
                hand[0]=q0; hand[1]=q1; hand[2]=q2; hand[3]=q3;
                hand[4]=Mv0; hand[5]=Mv1; hand[6]=Mv2;
                hand[7]=Nv0; hand[8]=Nv1; hand[9]=Nv2;
                hand[10]=Tv;
            }
        }
        __syncthreads();
        if (own && wid==0) {
            // append suffix(64..127) to wave0's in-wave suffixes
            Quat qb; qb.x=q0; qb.y=q1; qb.z=q2; qb.w=q3;
            Quat qa; qa.x=hand[0]; qa.y=hand[1]; qa.z=hand[2]; qa.w=hand[3];
            float am0=hand[4],am1=hand[5],am2=hand[6];
            float an0=hand[7],an1=hand[8],an2=hand[9];
            float aT=hand[10];
            Quat qc=qmul(qb,qa);
            float Rb[9]; quat2mat(qb,Rb);
            float Mc0=Mv0+Rb[0]*am0+Rb[1]*am1+Rb[2]*am2;
            float Mc1=Mv1+Rb[3]*am0+Rb[4]*am1+Rb[5]*am2;
            float Mc2=Mv2+Rb[6]*am0+Rb[7]*am1+Rb[8]*am2;
            float Nc0=Nv0+Rb[0]*an0+Rb[1]*an1+Rb[2]*an2+aT*Mv0;
            float Nc1=Nv1+Rb[3]*an0+Rb[4]*an1+Rb[5]*an2+aT*Mv1;
            float Nc2=Nv2+Rb[6]*an0+Rb[7]*an1+Rb[8]*an2+aT*Mv2;
            q0=qc.x; q1=qc.y; q2=qc.z; q3=qc.w;
            Mv0=Mc0; Mv1=Mc1; Mv2=Mc2;
            Nv0=Nc0; Nv1=Nc1; Nv2=Nc2;
            Tv+=aT;
        }
        if (own) {
            sc[tid][0]=q0; sc[tid][1]=q1; sc[tid][2]=q2; sc[tid][3]=q3;
            sc[tid][4]=Mv0; sc[tid][5]=Mv1; sc[tid][6]=Mv2;
            sc[tid][7]=Nv0; sc[tid][8]=Nv1; sc[tid][9]=Nv2;
            sc[tid][10]=Tv;
        }
        __syncthreads();

        // per-chunk: Phi from suffix(tid+1), S reconstruct, congr -> O regs
        float O[45];
        if (own) {
            const float* g = &stg[tid*SLOT];
            Quat qt; qt.x=g[45]; qt.y=g[46]; qt.z=g[47]; qt.w=g[48];
            Quat qp; qp.x=g[49]; qp.y=g[50]; qp.z=g[51]; qp.w=g[52];

            float Phi[28];
            if (tid < NCH-1) {
                Quat qs; qs.x=sc[tid+1][0]; qs.y=sc[tid+1][1]; qs.z=sc[tid+1][2]; qs.w=sc[tid+1][3];
                float Ms0=sc[tid+1][4], Ms1=sc[tid+1][5], Ms2=sc[tid+1][6];
                float Ns0=sc[tid+1][7], Ns1=sc[tid+1][8], Ns2=sc[tid+1][9];
                float Ts=sc[tid+1][10];
                float Rs[9]; quat2mat(qs,Rs);
                Phi[0]=Rs[0]; Phi[1]=Rs[3]; Phi[2]=Rs[6];
                Phi[3]=Rs[1]; Phi[4]=Rs[4]; Phi[5]=Rs[7];
                Phi[6]=Rs[2]; Phi[7]=Rs[5]; Phi[8]=Rs[8];
                Quat qp1=qmul(qp,qt);                 // qpre of chunk tid+1
                float Rp1[9]; quat2mat(qp1,Rp1);
                float Pc[9]; m_skew(Rp1, -Ms0,-Ms1,-Ms2, Pc);
                float Qc[9]; m_skew(Rp1, -Ns0,-Ns1,-Ns2, Qc);
#pragma unroll
                for (int i=0;i<9;i++){ Phi[9+i]=Pc[i]; Phi[18+i]=Qc[i]; }
                Phi[27]=Ts;
            } else {
#pragma unroll
                for (int i=0;i<9;i++){ Phi[i]=(i%4==0)?1.f:0.f; Phi[9+i]=0.f; Phi[18+i]=0.f; }
                Phi[27]=0.f;
            }

            float Rt[9]; quat2mat(qt,Rt);
            float Rp[9]; quat2mat(qp,Rp);
            float S[45];
            {
                float Crv[9],Crp[9],Cvp9[9], e9[9], t9[9], o9[9], o6[6];
#pragma unroll
                for (int i=0;i<9;i++){ Crv[i]=g[i]; Crp[i]=g[9+i]; Cvp9[i]=g[18+i]; }
                mm_tn(Rt, Crv, t9); mm_nt(t9, Rp, o9);
#pragma unroll
                for (int i=0;i<9;i++) S[i]=o9[i];
                mm_tn(Rt, Crp, t9); mm_nt(t9, Rp, o9);
#pragma unroll
                for (int i=0;i<9;i++) S[9+i]=o9[i];
                mm_nn(Rp, Cvp9, t9); mm_nt(t9, Rp, o9);
#pragma unroll
                for (int i=0;i<9;i++) S[18+i]=o9[i];
                expand_sym(g+27, e9); mm_tn(Rt, e9, t9); mm_nn_sym(t9, Rt, o6);
#pragma unroll
                for (int i=0;i<6;i++) S[27+i]=o6[i];
                expand_sym(g+33, e9); mm_nn(Rp, e9, t9); mm_nt_sym(t9, Rp, o6);
#pragma unroll
                for (int i=0;i<6;i++) S[33+i]=o6[i];
                expand_sym(g+39, e9); mm_nn(Rp, e9, t9); mm_nt_sym(t9, Rp, o6);
#pragma unroll
                for (int i=0;i<6;i++) S[39+i]=o6[i];
            }
            congr45(Phi, S, O);

            // in-wave butterfly sum of O (64 chunks per wave)
#pragma unroll
            for (int m=1;m<64;m<<=1) {
#pragma unroll
                for (int i=0;i<45;i++) O[i] += __shfl_xor(O[i], m);
            }
            if (lane==0) {
#pragma unroll
                for (int i=0;i<45;i++) wsum[wid][i] = O[i];
            }
        }
        __syncthreads();

        if (tid < 81) {
            int i = tid/9, j = tid%9;
            int bi = i/3, ii = i%3, bj = j/3, jj = j%3;
            int lo = (ii<jj)?ii:jj, hi = (ii<jj)?jj:ii;
            int tix = (lo==0)?hi:((lo==1)?(2+hi):5);
            int x;
            if      (bi==0 && bj==0) x = 27 + tix;        // Arr
            else if (bi==0 && bj==1) x = 0  + 3*ii + jj;  // Arv
            else if (bi==0 && bj==2) x = 9  + 3*ii + jj;  // Arp
            else if (bi==1 && bj==0) x = 0  + 3*jj + ii;  // Arv^T
            else if (bi==1 && bj==1) x = 33 + tix;        // Avv
            else if (bi==1 && bj==2) x = 18 + 3*ii + jj;  // Avp
            else if (bi==2 && bj==0) x = 9  + 3*jj + ii;  // Arp^T
            else if (bi==2 && bj==1) x = 18 + 3*jj + ii;  // Avp^T
            else                     x = 39 + tix;        // App
            outc[(long)b*81 + tid] = wsum[0][x] + wsum[1][x];
        }
        return;
    }

    // ---- feather-weight emit: RMW partials with chunk offsets ----
    const int ebid = bid - BB;
    const int b = ebid>>5, wg = ebid&31;
    const int c = wg*4+wid;
    const long k = (long)b*FF+(long)c*64+lane;

    float td = dt[k];
#pragma unroll
    for (int s=1;s<64;s<<=1) {
        float p=__shfl_up(td,s);
        if (lane>=s) td+=p;
    }

    const float* vr=vpre+(long)(b*NCH+c)*8;
    float V0=vr[0],V1=vr[1],V2=vr[2],P0=vr[3],P1=vr[4],P2=vr[5];
    float v0x=vel0[3*b+0], v0y=vel0[3*b+1], v0z=vel0[3*b+2];
    float p0x=pos0[3*b+0], p0y=pos0[3*b+1], p0z=pos0[3*b+2];

    float pv0=outv[3*k+0], pv1=outv[3*k+1], pv2=outv[3*k+2];
    float pp0=outp[3*k+0], pp1=outp[3*k+1], pp2=outp[3*k+2];

    outv[3*k+0]=v0x+V0+pv0;
    outv[3*k+1]=v0y+V1+pv1;
    outv[3*k+2]=v0z+V2+pv2;
    outp[3*k+0]=p0x+P0+V0*td+pp0;
    outp[3*k+1]=p0y+P1+V1*td+pp1;
    outp[3*k+2]=p0z+P2+V2*td+pp2;
}

// ---------------------------------------------------------------------------
extern "C" void kernel_launch(void* const* d_in, const int* in_sizes, int n_in,
                              void* d_out, int out_size, void* d_ws, size_t ws_size,
                              hipStream_t stream)
{
    const float* dt   = (const float*)d_in[0];
    const float* gyro = (const float*)d_in[1];
    const float* acc  = (const float*)d_in[2];
    const float* pos0 = (const float*)d_in[3];
    const float* vel0 = (const float*)d_in[4];

    float* out  = (float*)d_out;
    float* outq = out;
    float* outv = out  + (long)BB*FF*4;
    float* outp = outv + (long)BB*FF*3;
    float* outc = outp + (long)BB*FF*3;

    float* ws   = (float*)d_ws;           // 1,441,792 bytes used
    float* cov  = ws + COV_OFF;
    float* vpre = ws + VPRE_OFF;
    float* qtot = ws + QTOT_OFF;
    float* qpre = ws + QPRE_OFF;
    float* vp   = ws + VP_OFF;

    hipLaunchKernelGGL(k_chunktot, dim3(BB*32),    dim3(256), 0, stream, dt, gyro, qtot, outq);
    hipLaunchKernelGGL(k_qpre,     dim3(BB),       dim3(128), 0, stream, qtot, qpre);
    hipLaunchKernelGGL(k_main,     dim3(BB*32),    dim3(256), 0, stream, dt, gyro, acc, qpre, outq, cov, vp, outv, outp);
    hipLaunchKernelGGL(k_vpscan,   dim3(BB),       dim3(128), 0, stream, vp, vpre);
    hipLaunchKernelGGL(k_merged,   dim3(BB*32+BB), dim3(256), 0, stream, dt, pos0, vel0, vpre, cov, outv, outp, outc);
}

// Round 13
// 34.255 us; speedup vs baseline: 1.9221x; 1.0666x over previous
//
#include <hip/hip_runtime.h>

// IMU preintegration, B=32 batches, F=8192 steps. 4-kernel pipeline:
//  A k_chunktot : per-step qexp + chunk-local quat prefix -> qloc staged in
//                 outq region (all lanes) + chunk totals (ws)
//  B k_qpre     : per-batch exclusive scan of 128 chunk quats      (ws)
//  C k_main     : loads qloc, RMW outq=qpre*qloc, partial outv/outp +
//                 chunk partials (ws) + factored cov composites (ws).
//  D k_merged   : blocks 0-31 covcomb (register shfl scan + butterfly);
//                 blocks 32-1055 emit with INLINE V/Pp pair-scan (k_vpscan
//                 eliminated).
// d_ws: cov 32*128*64 + qtot 16384 + qpre 16384 + vp 32768
//       = 327680 floats = 1,310,720 bytes.

#define BB 32
#define FF 8192
#define NCH 128
#define SLOT 64
#define GRAV 9.81007f
#define GCOV (0.0032f*0.0032f)
#define ACOV (0.08f*0.08f)

// ws float offsets
#define COV_OFF  0
#define QTOT_OFF 262144
#define QPRE_OFF 278528
#define VP_OFF   294912

struct Quat { float x, y, z, w; };

__device__ __forceinline__ Quat qmul(const Quat a, const Quat b) {
    Quat r;
    r.x = a.w*b.x + a.x*b.w + a.y*b.z - a.z*b.y;
    r.y = a.w*b.y - a.x*b.z + a.y*b.w + a.z*b.x;
    r.z = a.w*b.z + a.x*b.y - a.y*b.x + a.z*b.w;
    r.w = a.w*b.w - a.x*b.x - a.y*b.y - a.z*b.z;
    return r;
}

__device__ __forceinline__ Quat qshfl_up(const Quat a, int s) {
    Quat r;
    r.x=__shfl_up(a.x,s); r.y=__shfl_up(a.y,s);
    r.z=__shfl_up(a.z,s); r.w=__shfl_up(a.w,s);
    return r;
}

__device__ __forceinline__ Quat qexp3(float px, float py, float pz) {
    float th2 = px*px + py*py + pz*pz;
    float s, w;
    if (th2 < 1e-8f) {
        s = 0.5f - th2 * (1.0f/48.0f);
        w = 1.0f - th2 * 0.125f;
    } else {
        float th = sqrtf(th2);
        s = sinf(0.5f*th) / th;
        w = cosf(0.5f*th);
    }
    Quat q; q.x=px*s; q.y=py*s; q.z=pz*s; q.w=w; return q;
}

__device__ __forceinline__ void quat2mat(const Quat q, float* R) {
    float x=q.x, y=q.y, z=q.z, w=q.w;
    R[0]=1.0f-2.0f*(y*y+z*z); R[1]=2.0f*(x*y-z*w);       R[2]=2.0f*(x*z+y*w);
    R[3]=2.0f*(x*y+z*w);      R[4]=1.0f-2.0f*(x*x+z*z);  R[5]=2.0f*(y*z-x*w);
    R[6]=2.0f*(x*z-y*w);      R[7]=2.0f*(y*z+x*w);       R[8]=1.0f-2.0f*(x*x+y*y);
}

__device__ __forceinline__ void mm_nn(const float* A, const float* B, float* C) {
#pragma unroll
    for (int i=0;i<3;i++)
#pragma unroll
    for (int j=0;j<3;j++)
        C[3*i+j] = A[3*i+0]*B[0+j] + A[3*i+1]*B[3+j] + A[3*i+2]*B[6+j];
}

__device__ __forceinline__ void mm_nt(const float* A, const float* B, float* C) {
#pragma unroll
    for (int i=0;i<3;i++)
#pragma unroll
    for (int j=0;j<3;j++)
        C[3*i+j] = A[3*i+0]*B[3*j+0] + A[3*i+1]*B[3*j+1] + A[3*i+2]*B[3*j+2];
}

__device__ __forceinline__ void mm_tn(const float* A, const float* B, float* C) {
#pragma unroll
    for (int i=0;i<3;i++)
#pragma unroll
    for (int j=0;j<3;j++)
        C[3*i+j] = A[0+i]*B[0+j] + A[3+i]*B[3+j] + A[6+i]*B[6+j];
}

// entries (0,0)(0,1)(0,2)(1,1)(1,2)(2,2) of A*B^T
__device__ __forceinline__ void mm_nt_sym(const float* A, const float* B, float* O6) {
    O6[0]=A[0]*B[0]+A[1]*B[1]+A[2]*B[2];
    O6[1]=A[0]*B[3]+A[1]*B[4]+A[2]*B[5];
    O6[2]=A[0]*B[6]+A[1]*B[7]+A[2]*B[8];
    O6[3]=A[3]*B[3]+A[4]*B[4]+A[5]*B[5];
    O6[4]=A[3]*B[6]+A[4]*B[7]+A[5]*B[8];
    O6[5]=A[6]*B[6]+A[7]*B[7]+A[8]*B[8];
}

// entries (0,0)(0,1)(0,2)(1,1)(1,2)(2,2) of A*B
__device__ __forceinline__ void mm_nn_sym(const float* A, const float* B, float* O6) {
    O6[0]=A[0]*B[0]+A[1]*B[3]+A[2]*B[6];
    O6[1]=A[0]*B[1]+A[1]*B[4]+A[2]*B[7];
    O6[2]=A[0]*B[2]+A[1]*B[5]+A[2]*B[8];
    O6[3]=A[3]*B[1]+A[4]*B[4]+A[5]*B[7];
    O6[4]=A[3]*B[2]+A[4]*B[5]+A[5]*B[8];
    O6[5]=A[6]*B[2]+A[7]*B[5]+A[8]*B[8];
}

__device__ __forceinline__ void expand_sym(const float* t, float* M) {
    M[0]=t[0]; M[1]=t[1]; M[2]=t[2];
    M[3]=t[1]; M[4]=t[3]; M[5]=t[4];
    M[6]=t[2]; M[7]=t[4]; M[8]=t[5];
}

// C = M * skew(v)
__device__ __forceinline__ void m_skew(const float* M, float v0, float v1, float v2, float* C) {
#pragma unroll
    for (int i=0;i<3;i++) {
        C[3*i+0] = M[3*i+1]*v2 - M[3*i+2]*v1;
        C[3*i+1] = M[3*i+2]*v0 - M[3*i+0]*v2;
        C[3*i+2] = M[3*i+0]*v1 - M[3*i+1]*v0;
    }
}

// C = skew(w) * M
__device__ __forceinline__ void skew_m(float w0, float w1, float w2, const float* M, float* C) {
#pragma unroll
    for (int j=0;j<3;j++) {
        C[0+j] = -w2*M[3+j] + w1*M[6+j];
        C[3+j] =  w2*M[0+j] - w0*M[6+j];
        C[6+j] = -w1*M[0+j] + w0*M[3+j];
    }
}

// ---------------------------------------------------------------------------
// A: chunk quat prefix. Writes per-lane qloc to outq region + lane63 totals.
// ---------------------------------------------------------------------------
__global__ __launch_bounds__(256) void k_chunktot(
    const float* __restrict__ dt, const float* __restrict__ gyro,
    float* __restrict__ qtot, float* __restrict__ outq)
{
    const int bid=blockIdx.x, b=bid>>5, wg=bid&31;
    const int tid=threadIdx.x, lane=tid&63, wid=tid>>6;
    const int c=wg*4+wid;
    const long k=(long)b*FF+(long)c*64+lane;
    float d=dt[k];
    Quat inc=qexp3(gyro[3*k+0]*d, gyro[3*k+1]*d, gyro[3*k+2]*d);
#pragma unroll
    for (int s=1;s<64;s<<=1) {
        Quat p=qshfl_up(inc,s);
        if (lane>=s) inc=qmul(p,inc);
    }
    { float4 o; o.x=inc.x; o.y=inc.y; o.z=inc.z; o.w=inc.w;
      reinterpret_cast<float4*>(outq)[k]=o; }
    if (lane==63) {
        float4 o; o.x=inc.x; o.y=inc.y; o.z=inc.z; o.w=inc.w;
        reinterpret_cast<float4*>(qtot)[b*NCH+c]=o;
    }
}

// ---------------------------------------------------------------------------
// B: exclusive scan of 128 chunk quats per batch. 1 WG/batch, 128 threads.
// ---------------------------------------------------------------------------
__global__ __launch_bounds__(128) void k_qpre(
    const float* __restrict__ qtot, float* __restrict__ qpre)
{
    const int b=blockIdx.x, c=threadIdx.x, lane=c&63, w=c>>6;
    __shared__ float4 w0t;
    __shared__ float4 all[NCH];
    float4 t=reinterpret_cast<const float4*>(qtot)[b*NCH+c];
    Quat inc; inc.x=t.x; inc.y=t.y; inc.z=t.z; inc.w=t.w;
#pragma unroll
    for (int s=1;s<64;s<<=1) {
        Quat p=qshfl_up(inc,s);
        if (lane>=s) inc=qmul(p,inc);
    }
    if (w==0 && lane==63) { float4 o; o.x=inc.x;o.y=inc.y;o.z=inc.z;o.w=inc.w; w0t=o; }
    __syncthreads();
    if (w==1) { Quat p; p.x=w0t.x;p.y=w0t.y;p.z=w0t.z;p.w=w0t.w; inc=qmul(p,inc); }
    { float4 o; o.x=inc.x;o.y=inc.y;o.z=inc.z;o.w=inc.w; all[c]=o; }
    __syncthreads();
    float4 pre;
    if (c==0) { pre.x=0.f;pre.y=0.f;pre.z=0.f;pre.w=1.f; }
    else pre=all[c-1];
    reinterpret_cast<float4*>(qpre)[b*NCH+c]=pre;
}

// ---------------------------------------------------------------------------
// C: main fused kernel. Loads staged qloc; no transcendentals, no quat scan.
// ---------------------------------------------------------------------------
#define RSTR 66
__global__ __launch_bounds__(256) void k_main(
    const float* __restrict__ dt, const float* __restrict__ gyro,
    const float* __restrict__ acc, const float* __restrict__ qpre_g,
    float* __restrict__ outq, float* __restrict__ cov, float* __restrict__ vp_g,
    float* __restrict__ outv, float* __restrict__ outp)
{
    __shared__ float red[4][23][RSTR];   // 24,288 B
    const int bid=blockIdx.x, b=bid>>5, wg=bid&31;
    const int tid=threadIdx.x, lane=tid&63, wid=tid>>6;
    const int c=wg*4+wid;
    const long k=(long)b*FF+(long)c*64+lane;

    const float d=dt[k];
    const float wx=gyro[3*k+0]*d, wy=gyro[3*k+1]*d, wz=gyro[3*k+2]*d;

    // staged within-chunk inclusive quat prefix
    Quat qloc;
    { float4 t=reinterpret_cast<const float4*>(outq)[k];
      qloc.x=t.x; qloc.y=t.y; qloc.z=t.z; qloc.w=t.w; }
    float4 tp=reinterpret_cast<const float4*>(qpre_g)[b*NCH+c];
    Quat qpre; qpre.x=tp.x; qpre.y=tp.y; qpre.z=tp.z; qpre.w=tp.w;
    Quat qi=qmul(qpre,qloc);
    { float4 o; o.x=qi.x;o.y=qi.y;o.z=qi.z;o.w=qi.w;
      reinterpret_cast<float4*>(outq)[k]=o; }

    Quat ql1=qshfl_up(qloc,1);
    if (lane==0) { ql1.x=0.f; ql1.y=0.f; ql1.z=0.f; ql1.w=1.f; }
    // dq = conj(ql1) (x) qloc   (per-step increment, for Jr coeffs)
    Quat cq; cq.x=-ql1.x; cq.y=-ql1.y; cq.z=-ql1.z; cq.w=ql1.w;
    Quat dqq=qmul(cq,qloc);

    // a = acc - R(qi)^T g
    float a0=acc[3*k+0]-GRAV*2.0f*(qi.x*qi.z-qi.y*qi.w);
    float a1=acc[3*k+1]-GRAV*2.0f*(qi.y*qi.z+qi.x*qi.w);
    float a2=acc[3*k+2]-GRAV*(1.0f-2.0f*(qi.x*qi.x+qi.y*qi.y));

    // b = R(qloc_excl) * a ;  m = d*b
    float Rl[9]; quat2mat(ql1,Rl);
    float b0=Rl[0]*a0+Rl[1]*a1+Rl[2]*a2;
    float b1=Rl[3]*a0+Rl[4]*a1+Rl[5]*a2;
    float b2=Rl[6]*a0+Rl[7]*a1+Rl[8]*a2;
    float m0=d*b0, m1=d*b1, m2=d*b2;

    // inclusive prefix scans: td (dt), M (m)
    float td=d, M0=m0, M1=m1, M2=m2;
#pragma unroll
    for (int s=1;s<64;s<<=1) {
        float p3=__shfl_up(td,s), p0=__shfl_up(M0,s), p1=__shfl_up(M1,s), p2=__shfl_up(M2,s);
        if (lane>=s) { td+=p3; M0+=p0; M1+=p1; M2+=p2; }
    }
    float Dtot=__shfl(td,63);
    float tau = Dtot - td;                 // exclusive suffix dt sum
    float cn = 0.5f*d + tau;
    float n0=cn*m0, n1=cn*m1, n2=cn*m2;
    float N0=n0, N1=n1, N2=n2;
#pragma unroll
    for (int s=1;s<64;s<<=1) {
        float p0=__shfl_up(N0,s),p1=__shfl_up(N1,s),p2=__shfl_up(N2,s);
        if (lane>=s){ N0+=p0; N1+=p1; N2+=p2; }
    }
    // u for pos partial: u = (M - 0.5 m) * d  (prefix scan)
    float u0=(M0-0.5f*m0)*d, u1=(M1-0.5f*m1)*d, u2=(M2-0.5f*m2)*d;
    float U0=u0, U1=u1, U2=u2;
#pragma unroll
    for (int s=1;s<64;s<<=1) {
        float p0=__shfl_up(U0,s),p1=__shfl_up(U1,s),p2=__shfl_up(U2,s);
        if (lane>=s){ U0+=p0; U1+=p1; U2+=p2; }
    }
    float Mt0=__shfl(M0,63), Mt1=__shfl(M1,63), Mt2=__shfl(M2,63);
    float Nt0=__shfl(N0,63), Nt1=__shfl(N1,63), Nt2=__shfl(N2,63);
    float mp0=Mt0-M0, mp1=Mt1-M1, mp2=Mt2-M2;   // m-psi (exclusive suffix)
    float np0=Nt0-N0, np1=Nt1-N1, np2=Nt2-N2;   // n-psi

    // partial outputs: outv = R(qpre)*M, outp = R(qpre)*U  (emit adds offsets)
    float Rp9[9]; quat2mat(qpre,Rp9);
    float pv0=Rp9[0]*M0+Rp9[1]*M1+Rp9[2]*M2;
    float pv1=Rp9[3]*M0+Rp9[4]*M1+Rp9[5]*M2;
    float pv2=Rp9[6]*M0+Rp9[7]*M1+Rp9[8]*M2;
    float pp0=Rp9[0]*U0+Rp9[1]*U1+Rp9[2]*U2;
    float pp1=Rp9[3]*U0+Rp9[4]*U1+Rp9[5]*U2;
    float pp2=Rp9[6]*U0+Rp9[7]*U1+Rp9[8]*U2;
    outv[3*k+0]=pv0; outv[3*k+1]=pv1; outv[3*k+2]=pv2;
    outp[3*k+0]=pp0; outp[3*k+1]=pp1; outp[3*k+2]=pp2;

    const long wsbase=((long)b*NCH+c)*SLOT;
    if (lane==63) {
        float* vp=vp_g+(long)(b*NCH+c)*8;
        vp[0]=pv0; vp[1]=pv1; vp[2]=pv2;
        vp[3]=pp0; vp[4]=pp1; vp[5]=pp2;
        vp[6]=td; vp[7]=0.f;
        // chunk params: qtot (= own qloc), qpre, Mtot, Ntot, Dtot
        cov[wsbase+45]=qloc.x; cov[wsbase+46]=qloc.y; cov[wsbase+47]=qloc.z; cov[wsbase+48]=qloc.w;
        cov[wsbase+49]=qpre.x; cov[wsbase+50]=qpre.y; cov[wsbase+51]=qpre.z; cov[wsbase+52]=qpre.w;
        cov[wsbase+53]=M0; cov[wsbase+54]=M1; cov[wsbase+55]=M2;
        cov[wsbase+56]=N0; cov[wsbase+57]=N1; cov[wsbase+58]=N2;
        cov[wsbase+59]=td;
    }

    // Jr coeffs from dq (no transcendentals)
    float th2 = wx*wx + wy*wy + wz*wz;
    float c1, c2;
    if (th2 < 1e-8f) { c1 = 0.5f - th2*(1.0f/24.0f); c2 = (1.0f/6.0f) - th2*(1.0f/120.0f); }
    else {
        float s2q = dqq.x*dqq.x + dqq.y*dqq.y + dqq.z*dqq.z;
        c1 = 2.0f*s2q/th2;
        float th = sqrtf(th2);
        float snt = 2.0f*sqrtf(s2q)*dqq.w;
        c2 = (th - snt)/(th2*th);
    }
    float J[9];
    {
        float dg = 1.0f - c2*th2;
        J[0]=dg + c2*wx*wx;      J[1]= c1*wz + c2*wx*wy;  J[2]=-c1*wy + c2*wx*wz;
        J[3]=-c1*wz + c2*wx*wy;  J[4]=dg + c2*wy*wy;      J[5]= c1*wx + c2*wy*wz;
        J[6]= c1*wy + c2*wx*wz;  J[7]=-c1*wx + c2*wy*wz;  J[8]=dg + c2*wz*wz;
    }
    float Rj[9]; quat2mat(qloc,Rj);
    float H[9]; mm_nn(Rj,J,H);
    const float gs = GCOV*d*d;
    float Gp[9];
    Gp[0]=gs*(H[0]*H[0]+H[1]*H[1]+H[2]*H[2]);
    Gp[1]=gs*(H[0]*H[3]+H[1]*H[4]+H[2]*H[5]);
    Gp[2]=gs*(H[0]*H[6]+H[1]*H[7]+H[2]*H[8]);
    Gp[4]=gs*(H[3]*H[3]+H[4]*H[4]+H[5]*H[5]);
    Gp[5]=gs*(H[3]*H[6]+H[4]*H[7]+H[5]*H[8]);
    Gp[8]=gs*(H[6]*H[6]+H[7]*H[7]+H[8]*H[8]);
    Gp[3]=Gp[1]; Gp[6]=Gp[2]; Gp[7]=Gp[5];

    const float av  = ACOV*d*d;
    const float bv  = 0.5f*ACOV*d*d*d;
    const float cv  = 0.25f*ACOV*d*d*d*d;
    const float vpd = av*tau + bv;
    const float ppd = av*tau*tau + 2.0f*bv*tau + cv;

    // core blocks
    float Crv[9], Crp[9], Cvv[9], Cvp[9], Cpp[9];
    m_skew(Gp, mp0,mp1,mp2, Crv);          // G' skew(m-psi)
    m_skew(Gp, np0,np1,np2, Crp);          // G' skew(n-psi)
    skew_m(-mp0,-mp1,-mp2, Crv, Cvv);      // skew(-m) G' skew(m)
    skew_m(-mp0,-mp1,-mp2, Crp, Cvp);
    skew_m(-np0,-np1,-np2, Crp, Cpp);

    float S45[45];
#pragma unroll
    for (int i=0;i<9;i++){ S45[i]=Crv[i]; S45[9+i]=Crp[i]; S45[18+i]=Cvp[i]; }
    S45[18]+=vpd; S45[22]+=vpd; S45[26]+=vpd;
    S45[27]=Gp[0];  S45[28]=Gp[1];  S45[29]=Gp[2];  S45[30]=Gp[4];  S45[31]=Gp[5];  S45[32]=Gp[8];
    S45[33]=Cvv[0]+av; S45[34]=Cvv[1]; S45[35]=Cvv[2]; S45[36]=Cvv[4]+av; S45[37]=Cvv[5]; S45[38]=Cvv[8]+av;
    S45[39]=Cpp[0]+ppd; S45[40]=Cpp[1]; S45[41]=Cpp[2]; S45[42]=Cpp[4]+ppd; S45[43]=Cpp[5]; S45[44]=Cpp[8]+ppd;

    // per-wave LDS transpose reduction over lanes, two rounds (23 + 22 elems)
#pragma unroll
    for (int e=0;e<23;e++) red[wid][e][lane] = S45[e];
    __syncthreads();
    float r1 = 0.f;
    if (lane < 23) {
        const float* row = &red[wid][lane][0];
        float ax=0.f, ay=0.f;
#pragma unroll
        for (int i=0;i<32;i++) {
            float2 v = reinterpret_cast<const float2*>(row)[i];
            ax += v.x; ay += v.y;
        }
        r1 = ax + ay;
    }
    __syncthreads();
#pragma unroll
    for (int e=0;e<22;e++) red[wid][e][lane] = S45[23+e];
    __syncthreads();
    float r2 = 0.f;
    if (lane < 22) {
        const float* row = &red[wid][lane][0];
        float ax=0.f, ay=0.f;
#pragma unroll
        for (int i=0;i<32;i++) {
            float2 v = reinterpret_cast<const float2*>(row)[i];
            ax += v.x; ay += v.y;
        }
        r2 = ax + ay;
    }
    if (lane < 23) cov[wsbase+lane] = r1;
    if (lane < 22) cov[wsbase+23+lane] = r2;
}

// ---------------------------------------------------------------------------
// K4 combine math (compact layout). Phi[0..27]=D,P,Q,T.
// S (45): Arv0 Arp9 Avp18 Arr27t Avv33t App39t.
// ---------------------------------------------------------------------------
__device__ __forceinline__ void congr45(const float* Phi, const float* S, float* O)
{
    const float* D=Phi; const float* P=Phi+9; const float* Q=Phi+18; const float T=Phi[27];
    const float* Arv=S+0; const float* Arp=S+9; const float* Avp=S+18;
    float Arr[9], Avv[9], App[9];
    expand_sym(S+27,Arr); expand_sym(S+33,Avv); expand_sym(S+39,App);

    float M1[9], M2[9], M3[9], t1[9], t6[6];
    mm_nn(D,Arr,M1); mm_nn(D,Arv,M2); mm_nn(D,Arp,M3);
    mm_nt_sym(M1, D, O+27);                          // O_rr (tri)
    mm_nt(M1, P, t1);
#pragma unroll
    for (int i=0;i<9;i++) O[0+i] = t1[i] + M2[i];    // O_rv
    mm_nt(M1, Q, t1);
#pragma unroll
    for (int i=0;i<9;i++) O[9+i] = t1[i] + T*M2[i] + M3[i];  // O_rp

    float W1[9], W2[9], W3[9];
    mm_nn(P, Arr, W1);
#pragma unroll
    for (int i=0;i<3;i++)
#pragma unroll
    for (int j=0;j<3;j++) W1[3*i+j] += Arv[3*j+i];
    mm_nn(P, Arv, W2);
#pragma unroll
    for (int i=0;i<9;i++) W2[i] += Avv[i];
    mm_nn(P, Arp, W3);
#pragma unroll
    for (int i=0;i<9;i++) W3[i] += Avp[i];
    mm_nt_sym(W1, P, t6);                            // O_vv (tri)
    O[33+0]=t6[0]+W2[0]; O[33+1]=t6[1]+W2[1]; O[33+2]=t6[2]+W2[2];
    O[33+3]=t6[3]+W2[4]; O[33+4]=t6[4]+W2[5]; O[33+5]=t6[5]+W2[8];
    mm_nt(W1, Q, t1);
#pragma unroll
    for (int i=0;i<9;i++) O[18+i] = t1[i] + T*W2[i] + W3[i];  // O_vp

    float U1[9], U2[9], U3[9];
    mm_nn(Q, Arr, U1);
#pragma unroll
    for (int i=0;i<3;i++)
#pragma unroll
    for (int j=0;j<3;j++) U1[3*i+j] += T*Arv[3*j+i] + Arp[3*j+i];
    mm_nn(Q, Arv, U2);
#pragma unroll
    for (int i=0;i<3;i++)
#pragma unroll
    for (int j=0;j<3;j++) U2[3*i+j] += T*Avv[3*i+j] + Avp[3*j+i];
    mm_nn(Q, Arp, U3);
#pragma unroll
    for (int i=0;i<9;i++) U3[i] += T*Avp[i] + App[i];
    mm_nt_sym(U1, Q, t6);                            // O_pp (tri)
    O[39+0]=t6[0]+T*U2[0]+U3[0]; O[39+1]=t6[1]+T*U2[1]+U3[1]; O[39+2]=t6[2]+T*U2[2]+U3[2];
    O[39+3]=t6[3]+T*U2[4]+U3[4]; O[39+4]=t6[4]+T*U2[5]+U3[5]; O[39+5]=t6[5]+T*U2[8]+U3[8];
}

// ---------------------------------------------------------------------------
// D (merged): blocks 0..31 covcomb; blocks 32..1055 emit w/ inline V/Pp.
// ---------------------------------------------------------------------------
__global__ __launch_bounds__(256) void k_merged(
    const float* __restrict__ dt, const float* __restrict__ pos0,
    const float* __restrict__ vel0, const float* __restrict__ vp_g,
    const float* __restrict__ cov,
    float* __restrict__ outv, float* __restrict__ outp, float* __restrict__ outc)
{
    __shared__ float stg[NCH*SLOT];  // 32,768 B compact slots (covcomb only)
    __shared__ float sc[NCH][12];    //  6,144 B published suffix params
    __shared__ float hand[12];       //  cross-wave handoff
    __shared__ float wsum[2][45];    //  wave partial sums
    const int bid=blockIdx.x;
    const int tid=threadIdx.x, lane=tid&63, wid=tid>>6;

    if (bid < BB) {
        const int b = bid;
        // vectorized coalesced load: 8192 floats = 2048 float4 (8/thread)
        const float4* src=reinterpret_cast<const float4*>(cov + (long)b*NCH*SLOT);
        float4* dst=reinterpret_cast<float4*>(stg);
#pragma unroll
        for (int j=0;j<8;j++) dst[j*256+tid]=src[j*256+tid];
        __syncthreads();

        const bool own = tid < NCH;   // waves 0,1 own chunks

        // register suffix scan of factored (q,M,N,T)
        float q0,q1,q2,q3, Mv0,Mv1,Mv2, Nv0,Nv1,Nv2, Tv;
        if (own) {
            const float* g=&stg[tid*SLOT];
            q0=g[45]; q1=g[46]; q2=g[47]; q3=g[48];
            Mv0=g[53]; Mv1=g[54]; Mv2=g[55];
            Nv0=g[56]; Nv1=g[57]; Nv2=g[58];
            Tv=g[59];
        } else { q0=q1=q2=0.f; q3=1.f; Mv0=Mv1=Mv2=Nv0=Nv1=Nv2=0.f; Tv=0.f; }

        if (own) {
#pragma unroll
            for (int s=1;s<64;s<<=1) {
                float a0=__shfl_down(q0,s), a1=__shfl_down(q1,s), a2=__shfl_down(q2,s), a3=__shfl_down(q3,s);
                float am0=__shfl_down(Mv0,s), am1=__shfl_down(Mv1,s), am2=__shfl_down(Mv2,s);
                float an0=__shfl_down(Nv0,s), an1=__shfl_down(Nv1,s), an2=__shfl_down(Nv2,s);
                float aT=__shfl_down(Tv,s);
                if (lane+s < 64) {
                    Quat qb; qb.x=q0; qb.y=q1; qb.z=q2; qb.w=q3;
                    Quat qa; qa.x=a0; qa.y=a1; qa.z=a2; qa.w=a3;
                    Quat qc=qmul(qb,qa);
                    float Rb[9]; quat2mat(qb,Rb);
                    float Mc0=Mv0+Rb[0]*am0+Rb[1]*am1+Rb[2]*am2;
                    float Mc1=Mv1+Rb[3]*am0+Rb[4]*am1+Rb[5]*am2;
                    float Mc2=Mv2+Rb[6]*am0+Rb[7]*am1+Rb[8]*am2;
                    float Nc0=Nv0+Rb[0]*an0+Rb[1]*an1+Rb[2]*an2+aT*Mv0;
                    float Nc1=Nv1+Rb[3]*an0+Rb[4]*an1+Rb[5]*an2+aT*Mv1;
                    float Nc2=Nv2+Rb[6]*an0+Rb[7]*an1+Rb[8]*an2+aT*Mv2;
                    q0=qc.x; q1=qc.y; q2=qc.z; q3=qc.w;
                    Mv0=Mc0; Mv1=Mc1; Mv2=Mc2;
                    Nv0=Nc0; Nv1=Nc1; Nv2=Nc2;
                    Tv+=aT;
                }
            }
            if (wid==1 && lane==0) {
                hand[0]=q0; hand[1]=q1; hand[2]=q2; hand[3]=q3;
                hand[4]=Mv0; hand[5]=Mv1; hand[6]=Mv2;
                hand[7]=Nv0; hand[8]=Nv1; hand[9]=Nv2;
                hand[10]=Tv;
            }
        }
        __syncthreads();
        if (own && wid==0) {
            Quat qb; qb.x=q0; qb.y=q1; qb.z=q2; qb.w=q3;
            Quat qa; qa.x=hand[0]; qa.y=hand[1]; qa.z=hand[2]; qa.w=hand[3];
            float am0=hand[4],am1=hand[5],am2=hand[6];
            float an0=hand[7],an1=hand[8],an2=hand[9];
            float aT=hand[10];
            Quat qc=qmul(qb,qa);
            float Rb[9]; quat2mat(qb,Rb);
            float Mc0=Mv0+Rb[0]*am0+Rb[1]*am1+Rb[2]*am2;
            float Mc1=Mv1+Rb[3]*am0+Rb[4]*am1+Rb[5]*am2;
            float Mc2=Mv2+Rb[6]*am0+Rb[7]*am1+Rb[8]*am2;
            float Nc0=Nv0+Rb[0]*an0+Rb[1]*an1+Rb[2]*an2+aT*Mv0;
            float Nc1=Nv1+Rb[3]*an0+Rb[4]*an1+Rb[5]*an2+aT*Mv1;
            float Nc2=Nv2+Rb[6]*an0+Rb[7]*an1+Rb[8]*an2+aT*Mv2;
            q0=qc.x; q1=qc.y; q2=qc.z; q3=qc.w;
            Mv0=Mc0; Mv1=Mc1; Mv2=Mc2;
            Nv0=Nc0; Nv1=Nc1; Nv2=Nc2;
            Tv+=aT;
        }
        if (own) {
            sc[tid][0]=q0; sc[tid][1]=q1; sc[tid][2]=q2; sc[tid][3]=q3;
            sc[tid][4]=Mv0; sc[tid][5]=Mv1; sc[tid][6]=Mv2;
            sc[tid][7]=Nv0; sc[tid][8]=Nv1; sc[tid][9]=Nv2;
            sc[tid][10]=Tv;
        }
        __syncthreads();

        float O[45];
        if (own) {
            const float* g = &stg[tid*SLOT];
            Quat qt; qt.x=g[45]; qt.y=g[46]; qt.z=g[47]; qt.w=g[48];
            Quat qp; qp.x=g[49]; qp.y=g[50]; qp.z=g[51]; qp.w=g[52];

            float Phi[28];
            if (tid < NCH-1) {
                Quat qs; qs.x=sc[tid+1][0]; qs.y=sc[tid+1][1]; qs.z=sc[tid+1][2]; qs.w=sc[tid+1][3];
                float Ms0=sc[tid+1][4], Ms1=sc[tid+1][5], Ms2=sc[tid+1][6];
                float Ns0=sc[tid+1][7], Ns1=sc[tid+1][8], Ns2=sc[tid+1][9];
                float Ts=sc[tid+1][10];
                float Rs[9]; quat2mat(qs,Rs);
                Phi[0]=Rs[0]; Phi[1]=Rs[3]; Phi[2]=Rs[6];
                Phi[3]=Rs[1]; Phi[4]=Rs[4]; Phi[5]=Rs[7];
                Phi[6]=Rs[2]; Phi[7]=Rs[5]; Phi[8]=Rs[8];
                Quat qp1=qmul(qp,qt);                 // qpre of chunk tid+1
                float Rp1[9]; quat2mat(qp1,Rp1);
                float Pc[9]; m_skew(Rp1, -Ms0,-Ms1,-Ms2, Pc);
                float Qc[9]; m_skew(Rp1, -Ns0,-Ns1,-Ns2, Qc);
#pragma unroll
                for (int i=0;i<9;i++){ Phi[9+i]=Pc[i]; Phi[18+i]=Qc[i]; }
                Phi[27]=Ts;
            } else {
#pragma unroll
                for (int i=0;i<9;i++){ Phi[i]=(i%4==0)?1.f:0.f; Phi[9+i]=0.f; Phi[18+i]=0.f; }
                Phi[27]=0.f;
            }

            float Rt[9]; quat2mat(qt,Rt);
            float Rp[9]; quat2mat(qp,Rp);
            float S[45];
            {
                float Crv[9],Crp[9],Cvp9[9], e9[9], t9[9], o9[9], o6[6];
#pragma unroll
                for (int i=0;i<9;i++){ Crv[i]=g[i]; Crp[i]=g[9+i]; Cvp9[i]=g[18+i]; }
                mm_tn(Rt, Crv, t9); mm_nt(t9, Rp, o9);
#pragma unroll
                for (int i=0;i<9;i++) S[i]=o9[i];
                mm_tn(Rt, Crp, t9); mm_nt(t9, Rp, o9);
#pragma unroll
                for (int i=0;i<9;i++) S[9+i]=o9[i];
                mm_nn(Rp, Cvp9, t9); mm_nt(t9, Rp, o9);
#pragma unroll
                for (int i=0;i<9;i++) S[18+i]=o9[i];
                expand_sym(g+27, e9); mm_tn(Rt, e9, t9); mm_nn_sym(t9, Rt, o6);
#pragma unroll
                for (int i=0;i<6;i++) S[27+i]=o6[i];
                expand_sym(g+33, e9); mm_nn(Rp, e9, t9); mm_nt_sym(t9, Rp, o6);
#pragma unroll
                for (int i=0;i<6;i++) S[33+i]=o6[i];
                expand_sym(g+39, e9); mm_nn(Rp, e9, t9); mm_nt_sym(t9, Rp, o6);
#pragma unroll
                for (int i=0;i<6;i++) S[39+i]=o6[i];
            }
            congr45(Phi, S, O);

            // in-wave butterfly sum of O (64 chunks per wave)
#pragma unroll
            for (int m=1;m<64;m<<=1) {
#pragma unroll
                for (int i=0;i<45;i++) O[i] += __shfl_xor(O[i], m);
            }
            if (lane==0) {
#pragma unroll
                for (int i=0;i<45;i++) wsum[wid][i] = O[i];
            }
        }
        __syncthreads();

        if (tid < 81) {
            int i = tid/9, j = tid%9;
            int bi = i/3, ii = i%3, bj = j/3, jj = j%3;
            int lo = (ii<jj)?ii:jj, hi = (ii<jj)?jj:ii;
            int tix = (lo==0)?hi:((lo==1)?(2+hi):5);
            int x;
            if      (bi==0 && bj==0) x = 27 + tix;        // Arr
            else if (bi==0 && bj==1) x = 0  + 3*ii + jj;  // Arv
            else if (bi==0 && bj==2) x = 9  + 3*ii + jj;  // Arp
            else if (bi==1 && bj==0) x = 0  + 3*jj + ii;  // Arv^T
            else if (bi==1 && bj==1) x = 33 + tix;        // Avv
            else if (bi==1 && bj==2) x = 18 + 3*ii + jj;  // Avp
            else if (bi==2 && bj==0) x = 9  + 3*jj + ii;  // Arp^T
            else if (bi==2 && bj==1) x = 18 + 3*jj + ii;  // Avp^T
            else                     x = 39 + tix;        // App
            outc[(long)b*81 + tid] = wsum[0][x] + wsum[1][x];
        }
        return;
    }

    // ---- emit with inline V/Pp: lane handles batch chunks 2*lane, 2*lane+1 ----
    const int ebid = bid - BB;
    const int b = ebid>>5, wg = ebid&31;
    const int c = wg*4+wid;
    const long k = (long)b*FF+(long)c*64+lane;

    const float4* vpb = reinterpret_cast<const float4*>(vp_g + (long)b*NCH*8);
    float4 A0=vpb[4*lane+0], A1=vpb[4*lane+1];   // chunk e0=2*lane: Lv, Sw, Td
    float4 B0=vpb[4*lane+2], B1=vpb[4*lane+3];   // chunk e1=2*lane+1

    // pair scan of Lv -> V at e0/e1
    float pl0=A0.x+B0.x, pl1=A0.y+B0.y, pl2=A0.z+B0.z;
    float i0=pl0,i1=pl1,i2=pl2;
#pragma unroll
    for (int s=1;s<64;s<<=1) {
        float p0=__shfl_up(i0,s),p1=__shfl_up(i1,s),p2=__shfl_up(i2,s);
        if (lane>=s){ i0+=p0; i1+=p1; i2+=p2; }
    }
    float e0V0=i0-pl0, e0V1=i1-pl1, e0V2=i2-pl2;
    float e1V0=e0V0+A0.x, e1V1=e0V1+A0.y, e1V2=e0V2+A0.z;
    // u = V*Td + Sw per element; pair scan -> Pp at e0/e1
    float u00=e0V0*A1.z+A0.w, u01=e0V1*A1.z+A1.x, u02=e0V2*A1.z+A1.y;
    float u10=e1V0*B1.z+B0.w, u11=e1V1*B1.z+B1.x, u12=e1V2*B1.z+B1.y;
    float pu0=u00+u10, pu1=u01+u11, pu2=u02+u12;
    float j0=pu0,j1=pu1,j2=pu2;
#pragma unroll
    for (int s=1;s<64;s<<=1) {
        float p0=__shfl_up(j0,s),p1=__shfl_up(j1,s),p2=__shfl_up(j2,s);
        if (lane>=s){ j0+=p0; j1+=p1; j2+=p2; }
    }
    float e0P0=j0-pu0, e0P1=j1-pu1, e0P2=j2-pu2;
    float e1P0=e0P0+u00, e1P1=e0P1+u01, e1P2=e0P2+u02;

    // select own chunk's (V, Pp); c is wave-uniform
    const int srcl = c>>1;
    float sV0=(c&1)? e1V0:e0V0, sV1=(c&1)? e1V1:e0V1, sV2=(c&1)? e1V2:e0V2;
    float sP0=(c&1)? e1P0:e0P0, sP1=(c&1)? e1P1:e0P1, sP2=(c&1)? e1P2:e0P2;
    float V0=__shfl(sV0,srcl), V1=__shfl(sV1,srcl), V2=__shfl(sV2,srcl);
    float P0=__shfl(sP0,srcl), P1=__shfl(sP1,srcl), P2=__shfl(sP2,srcl);

    float td = dt[k];
#pragma unroll
    for (int s=1;s<64;s<<=1) {
        float p=__shfl_up(td,s);
        if (lane>=s) td+=p;
    }

    float v0x=vel0[3*b+0], v0y=vel0[3*b+1], v0z=vel0[3*b+2];
    float p0x=pos0[3*b+0], p0y=pos0[3*b+1], p0z=pos0[3*b+2];

    float pv0=outv[3*k+0], pv1=outv[3*k+1], pv2=outv[3*k+2];
    float pp0=outp[3*k+0], pp1=outp[3*k+1], pp2=outp[3*k+2];

    outv[3*k+0]=v0x+V0+pv0;
    outv[3*k+1]=v0y+V1+pv1;
    outv[3*k+2]=v0z+V2+pv2;
    outp[3*k+0]=p0x+P0+V0*td+pp0;
    outp[3*k+1]=p0y+P1+V1*td+pp1;
    outp[3*k+2]=p0z+P2+V2*td+pp2;
}

// ---------------------------------------------------------------------------
extern "C" void kernel_launch(void* const* d_in, const int* in_sizes, int n_in,
                              void* d_out, int out_size, void* d_ws, size_t ws_size,
                              hipStream_t stream)
{
    const float* dt   = (const float*)d_in[0];
    const float* gyro = (const float*)d_in[1];
    const float* acc  = (const float*)d_in[2];
    const float* pos0 = (const float*)d_in[3];
    const float* vel0 = (const float*)d_in[4];

    float* out  = (float*)d_out;
    float* outq = out;
    float* outv = out  + (long)BB*FF*4;
    float* outp = outv + (long)BB*FF*3;
    float* outc = outp + (long)BB*FF*3;

    float* ws   = (float*)d_ws;           // 1,310,720 bytes used
    float* cov  = ws + COV_OFF;
    float* qtot = ws + QTOT_OFF;
    float* qpre = ws + QPRE_OFF;
    float* vp   = ws + VP_OFF;

    hipLaunchKernelGGL(k_chunktot, dim3(BB*32),    dim3(256), 0, stream, dt, gyro, qtot, outq);
    hipLaunchKernelGGL(k_qpre,     dim3(BB),       dim3(128), 0, stream, qtot, qpre);
    hipLaunchKernelGGL(k_main,     dim3(BB*32),    dim3(256), 0, stream, dt, gyro, acc, qpre, outq, cov, vp, outv, outp);
    hipLaunchKernelGGL(k_merged,   dim3(BB*32+BB), dim3(256), 0, stream, dt, pos0, vel0, vp, cov, outv, outp, outc);
}

// Round 14
// 32.572 us; speedup vs baseline: 2.0213x; 1.0516x over previous
//
#include <hip/hip_runtime.h>

// IMU preintegration, B=32 batches, F=8192 steps. 4-kernel pipeline:
//  A k_chunktot : per-step qexp + chunk-local quat prefix -> qloc staged in
//                 outq region (all lanes) + chunk totals (ws)
//  B k_qpre     : per-batch exclusive scan of 128 chunk quats      (ws)
//  C k_main     : loads qloc, RMW outq=qpre*qloc, partial outv/outp +
//                 chunk partials (ws) + factored cov composites (ws).
//  D k_merged   : blocks 0-31 covcomb (direct-global slot reads, register
//                 shfl scan + butterfly; NO LDS staging -> no bank conflicts);
//                 blocks 32-1055 emit with inline V/Pp pair-scan.
// d_ws: cov 32*128*64 + qtot 16384 + qpre 16384 + vp 32768
//       = 327680 floats = 1,310,720 bytes.

#define BB 32
#define FF 8192
#define NCH 128
#define SLOT 64
#define GRAV 9.81007f
#define GCOV (0.0032f*0.0032f)
#define ACOV (0.08f*0.08f)

// ws float offsets
#define COV_OFF  0
#define QTOT_OFF 262144
#define QPRE_OFF 278528
#define VP_OFF   294912

struct Quat { float x, y, z, w; };

__device__ __forceinline__ Quat qmul(const Quat a, const Quat b) {
    Quat r;
    r.x = a.w*b.x + a.x*b.w + a.y*b.z - a.z*b.y;
    r.y = a.w*b.y - a.x*b.z + a.y*b.w + a.z*b.x;
    r.z = a.w*b.z + a.x*b.y - a.y*b.x + a.z*b.w;
    r.w = a.w*b.w - a.x*b.x - a.y*b.y - a.z*b.z;
    return r;
}

__device__ __forceinline__ Quat qshfl_up(const Quat a, int s) {
    Quat r;
    r.x=__shfl_up(a.x,s); r.y=__shfl_up(a.y,s);
    r.z=__shfl_up(a.z,s); r.w=__shfl_up(a.w,s);
    return r;
}

__device__ __forceinline__ Quat qexp3(float px, float py, float pz) {
    float th2 = px*px + py*py + pz*pz;
    float s, w;
    if (th2 < 1e-8f) {
        s = 0.5f - th2 * (1.0f/48.0f);
        w = 1.0f - th2 * 0.125f;
    } else {
        float th = sqrtf(th2);
        s = sinf(0.5f*th) / th;
        w = cosf(0.5f*th);
    }
    Quat q; q.x=px*s; q.y=py*s; q.z=pz*s; q.w=w; return q;
}

__device__ __forceinline__ void quat2mat(const Quat q, float* R) {
    float x=q.x, y=q.y, z=q.z, w=q.w;
    R[0]=1.0f-2.0f*(y*y+z*z); R[1]=2.0f*(x*y-z*w);       R[2]=2.0f*(x*z+y*w);
    R[3]=2.0f*(x*y+z*w);      R[4]=1.0f-2.0f*(x*x+z*z);  R[5]=2.0f*(y*z-x*w);
    R[6]=2.0f*(x*z-y*w);      R[7]=2.0f*(y*z+x*w);       R[8]=1.0f-2.0f*(x*x+y*y);
}

__device__ __forceinline__ void mm_nn(const float* A, const float* B, float* C) {
#pragma unroll
    for (int i=0;i<3;i++)
#pragma unroll
    for (int j=0;j<3;j++)
        C[3*i+j] = A[3*i+0]*B[0+j] + A[3*i+1]*B[3+j] + A[3*i+2]*B[6+j];
}

__device__ __forceinline__ void mm_nt(const float* A, const float* B, float* C) {
#pragma unroll
    for (int i=0;i<3;i++)
#pragma unroll
    for (int j=0;j<3;j++)
        C[3*i+j] = A[3*i+0]*B[3*j+0] + A[3*i+1]*B[3*j+1] + A[3*i+2]*B[3*j+2];
}

__device__ __forceinline__ void mm_tn(const float* A, const float* B, float* C) {
#pragma unroll
    for (int i=0;i<3;i++)
#pragma unroll
    for (int j=0;j<3;j++)
        C[3*i+j] = A[0+i]*B[0+j] + A[3+i]*B[3+j] + A[6+i]*B[6+j];
}

// entries (0,0)(0,1)(0,2)(1,1)(1,2)(2,2) of A*B^T
__device__ __forceinline__ void mm_nt_sym(const float* A, const float* B, float* O6) {
    O6[0]=A[0]*B[0]+A[1]*B[1]+A[2]*B[2];
    O6[1]=A[0]*B[3]+A[1]*B[4]+A[2]*B[5];
    O6[2]=A[0]*B[6]+A[1]*B[7]+A[2]*B[8];
    O6[3]=A[3]*B[3]+A[4]*B[4]+A[5]*B[5];
    O6[4]=A[3]*B[6]+A[4]*B[7]+A[5]*B[8];
    O6[5]=A[6]*B[6]+A[7]*B[7]+A[8]*B[8];
}

// entries (0,0)(0,1)(0,2)(1,1)(1,2)(2,2) of A*B
__device__ __forceinline__ void mm_nn_sym(const float* A, const float* B, float* O6) {
    O6[0]=A[0]*B[0]+A[1]*B[3]+A[2]*B[6];
    O6[1]=A[0]*B[1]+A[1]*B[4]+A[2]*B[7];
    O6[2]=A[0]*B[2]+A[1]*B[5]+A[2]*B[8];
    O6[3]=A[3]*B[1]+A[4]*B[4]+A[5]*B[7];
    O6[4]=A[3]*B[2]+A[4]*B[5]+A[5]*B[8];
    O6[5]=A[6]*B[2]+A[7]*B[5]+A[8]*B[8];
}

__device__ __forceinline__ void expand_sym(const float* t, float* M) {
    M[0]=t[0]; M[1]=t[1]; M[2]=t[2];
    M[3]=t[1]; M[4]=t[3]; M[5]=t[4];
    M[6]=t[2]; M[7]=t[4]; M[8]=t[5];
}

// C = M * skew(v)
__device__ __forceinline__ void m_skew(const float* M, float v0, float v1, float v2, float* C) {
#pragma unroll
    for (int i=0;i<3;i++) {
        C[3*i+0] = M[3*i+1]*v2 - M[3*i+2]*v1;
        C[3*i+1] = M[3*i+2]*v0 - M[3*i+0]*v2;
        C[3*i+2] = M[3*i+0]*v1 - M[3*i+1]*v0;
    }
}

// C = skew(w) * M
__device__ __forceinline__ void skew_m(float w0, float w1, float w2, const float* M, float* C) {
#pragma unroll
    for (int j=0;j<3;j++) {
        C[0+j] = -w2*M[3+j] + w1*M[6+j];
        C[3+j] =  w2*M[0+j] - w0*M[6+j];
        C[6+j] = -w1*M[0+j] + w0*M[3+j];
    }
}

// ---------------------------------------------------------------------------
// A: chunk quat prefix. Writes per-lane qloc to outq region + lane63 totals.
// ---------------------------------------------------------------------------
__global__ __launch_bounds__(256) void k_chunktot(
    const float* __restrict__ dt, const float* __restrict__ gyro,
    float* __restrict__ qtot, float* __restrict__ outq)
{
    const int bid=blockIdx.x, b=bid>>5, wg=bid&31;
    const int tid=threadIdx.x, lane=tid&63, wid=tid>>6;
    const int c=wg*4+wid;
    const long k=(long)b*FF+(long)c*64+lane;
    float d=dt[k];
    Quat inc=qexp3(gyro[3*k+0]*d, gyro[3*k+1]*d, gyro[3*k+2]*d);
#pragma unroll
    for (int s=1;s<64;s<<=1) {
        Quat p=qshfl_up(inc,s);
        if (lane>=s) inc=qmul(p,inc);
    }
    { float4 o; o.x=inc.x; o.y=inc.y; o.z=inc.z; o.w=inc.w;
      reinterpret_cast<float4*>(outq)[k]=o; }
    if (lane==63) {
        float4 o; o.x=inc.x; o.y=inc.y; o.z=inc.z; o.w=inc.w;
        reinterpret_cast<float4*>(qtot)[b*NCH+c]=o;
    }
}

// ---------------------------------------------------------------------------
// B: exclusive scan of 128 chunk quats per batch. 1 WG/batch, 128 threads.
// ---------------------------------------------------------------------------
__global__ __launch_bounds__(128) void k_qpre(
    const float* __restrict__ qtot, float* __restrict__ qpre)
{
    const int b=blockIdx.x, c=threadIdx.x, lane=c&63, w=c>>6;
    __shared__ float4 w0t;
    __shared__ float4 all[NCH];
    float4 t=reinterpret_cast<const float4*>(qtot)[b*NCH+c];
    Quat inc; inc.x=t.x; inc.y=t.y; inc.z=t.z; inc.w=t.w;
#pragma unroll
    for (int s=1;s<64;s<<=1) {
        Quat p=qshfl_up(inc,s);
        if (lane>=s) inc=qmul(p,inc);
    }
    if (w==0 && lane==63) { float4 o; o.x=inc.x;o.y=inc.y;o.z=inc.z;o.w=inc.w; w0t=o; }
    __syncthreads();
    if (w==1) { Quat p; p.x=w0t.x;p.y=w0t.y;p.z=w0t.z;p.w=w0t.w; inc=qmul(p,inc); }
    { float4 o; o.x=inc.x;o.y=inc.y;o.z=inc.z;o.w=inc.w; all[c]=o; }
    __syncthreads();
    float4 pre;
    if (c==0) { pre.x=0.f;pre.y=0.f;pre.z=0.f;pre.w=1.f; }
    else pre=all[c-1];
    reinterpret_cast<float4*>(qpre)[b*NCH+c]=pre;
}

// ---------------------------------------------------------------------------
// C: main fused kernel. Loads staged qloc; no transcendentals, no quat scan.
// ---------------------------------------------------------------------------
#define RSTR 66
__global__ __launch_bounds__(256) void k_main(
    const float* __restrict__ dt, const float* __restrict__ gyro,
    const float* __restrict__ acc, const float* __restrict__ qpre_g,
    float* __restrict__ outq, float* __restrict__ cov, float* __restrict__ vp_g,
    float* __restrict__ outv, float* __restrict__ outp)
{
    __shared__ float red[4][23][RSTR];   // 24,288 B
    const int bid=blockIdx.x, b=bid>>5, wg=bid&31;
    const int tid=threadIdx.x, lane=tid&63, wid=tid>>6;
    const int c=wg*4+wid;
    const long k=(long)b*FF+(long)c*64+lane;

    const float d=dt[k];
    const float wx=gyro[3*k+0]*d, wy=gyro[3*k+1]*d, wz=gyro[3*k+2]*d;

    // staged within-chunk inclusive quat prefix
    Quat qloc;
    { float4 t=reinterpret_cast<const float4*>(outq)[k];
      qloc.x=t.x; qloc.y=t.y; qloc.z=t.z; qloc.w=t.w; }
    float4 tp=reinterpret_cast<const float4*>(qpre_g)[b*NCH+c];
    Quat qpre; qpre.x=tp.x; qpre.y=tp.y; qpre.z=tp.z; qpre.w=tp.w;
    Quat qi=qmul(qpre,qloc);
    { float4 o; o.x=qi.x;o.y=qi.y;o.z=qi.z;o.w=qi.w;
      reinterpret_cast<float4*>(outq)[k]=o; }

    Quat ql1=qshfl_up(qloc,1);
    if (lane==0) { ql1.x=0.f; ql1.y=0.f; ql1.z=0.f; ql1.w=1.f; }
    // dq = conj(ql1) (x) qloc   (per-step increment, for Jr coeffs)
    Quat cq; cq.x=-ql1.x; cq.y=-ql1.y; cq.z=-ql1.z; cq.w=ql1.w;
    Quat dqq=qmul(cq,qloc);

    // a = acc - R(qi)^T g
    float a0=acc[3*k+0]-GRAV*2.0f*(qi.x*qi.z-qi.y*qi.w);
    float a1=acc[3*k+1]-GRAV*2.0f*(qi.y*qi.z+qi.x*qi.w);
    float a2=acc[3*k+2]-GRAV*(1.0f-2.0f*(qi.x*qi.x+qi.y*qi.y));

    // b = R(qloc_excl) * a ;  m = d*b
    float Rl[9]; quat2mat(ql1,Rl);
    float b0=Rl[0]*a0+Rl[1]*a1+Rl[2]*a2;
    float b1=Rl[3]*a0+Rl[4]*a1+Rl[5]*a2;
    float b2=Rl[6]*a0+Rl[7]*a1+Rl[8]*a2;
    float m0=d*b0, m1=d*b1, m2=d*b2;

    // inclusive prefix scans: td (dt), M (m)
    float td=d, M0=m0, M1=m1, M2=m2;
#pragma unroll
    for (int s=1;s<64;s<<=1) {
        float p3=__shfl_up(td,s), p0=__shfl_up(M0,s), p1=__shfl_up(M1,s), p2=__shfl_up(M2,s);
        if (lane>=s) { td+=p3; M0+=p0; M1+=p1; M2+=p2; }
    }
    float Dtot=__shfl(td,63);
    float tau = Dtot - td;                 // exclusive suffix dt sum
    float cn = 0.5f*d + tau;
    float n0=cn*m0, n1=cn*m1, n2=cn*m2;
    float N0=n0, N1=n1, N2=n2;
#pragma unroll
    for (int s=1;s<64;s<<=1) {
        float p0=__shfl_up(N0,s),p1=__shfl_up(N1,s),p2=__shfl_up(N2,s);
        if (lane>=s){ N0+=p0; N1+=p1; N2+=p2; }
    }
    // u for pos partial: u = (M - 0.5 m) * d  (prefix scan)
    float u0=(M0-0.5f*m0)*d, u1=(M1-0.5f*m1)*d, u2=(M2-0.5f*m2)*d;
    float U0=u0, U1=u1, U2=u2;
#pragma unroll
    for (int s=1;s<64;s<<=1) {
        float p0=__shfl_up(U0,s),p1=__shfl_up(U1,s),p2=__shfl_up(U2,s);
        if (lane>=s){ U0+=p0; U1+=p1; U2+=p2; }
    }
    float Mt0=__shfl(M0,63), Mt1=__shfl(M1,63), Mt2=__shfl(M2,63);
    float Nt0=__shfl(N0,63), Nt1=__shfl(N1,63), Nt2=__shfl(N2,63);
    float mp0=Mt0-M0, mp1=Mt1-M1, mp2=Mt2-M2;   // m-psi (exclusive suffix)
    float np0=Nt0-N0, np1=Nt1-N1, np2=Nt2-N2;   // n-psi

    // partial outputs: outv = R(qpre)*M, outp = R(qpre)*U  (emit adds offsets)
    float Rp9[9]; quat2mat(qpre,Rp9);
    float pv0=Rp9[0]*M0+Rp9[1]*M1+Rp9[2]*M2;
    float pv1=Rp9[3]*M0+Rp9[4]*M1+Rp9[5]*M2;
    float pv2=Rp9[6]*M0+Rp9[7]*M1+Rp9[8]*M2;
    float pp0=Rp9[0]*U0+Rp9[1]*U1+Rp9[2]*U2;
    float pp1=Rp9[3]*U0+Rp9[4]*U1+Rp9[5]*U2;
    float pp2=Rp9[6]*U0+Rp9[7]*U1+Rp9[8]*U2;
    outv[3*k+0]=pv0; outv[3*k+1]=pv1; outv[3*k+2]=pv2;
    outp[3*k+0]=pp0; outp[3*k+1]=pp1; outp[3*k+2]=pp2;

    const long wsbase=((long)b*NCH+c)*SLOT;
    if (lane==63) {
        float* vp=vp_g+(long)(b*NCH+c)*8;
        vp[0]=pv0; vp[1]=pv1; vp[2]=pv2;
        vp[3]=pp0; vp[4]=pp1; vp[5]=pp2;
        vp[6]=td; vp[7]=0.f;
        // chunk params: qtot (= own qloc), qpre, Mtot, Ntot, Dtot
        cov[wsbase+45]=qloc.x; cov[wsbase+46]=qloc.y; cov[wsbase+47]=qloc.z; cov[wsbase+48]=qloc.w;
        cov[wsbase+49]=qpre.x; cov[wsbase+50]=qpre.y; cov[wsbase+51]=qpre.z; cov[wsbase+52]=qpre.w;
        cov[wsbase+53]=M0; cov[wsbase+54]=M1; cov[wsbase+55]=M2;
        cov[wsbase+56]=N0; cov[wsbase+57]=N1; cov[wsbase+58]=N2;
        cov[wsbase+59]=td;
    }

    // Jr coeffs from dq (no transcendentals)
    float th2 = wx*wx + wy*wy + wz*wz;
    float c1, c2;
    if (th2 < 1e-8f) { c1 = 0.5f - th2*(1.0f/24.0f); c2 = (1.0f/6.0f) - th2*(1.0f/120.0f); }
    else {
        float s2q = dqq.x*dqq.x + dqq.y*dqq.y + dqq.z*dqq.z;
        c1 = 2.0f*s2q/th2;
        float th = sqrtf(th2);
        float snt = 2.0f*sqrtf(s2q)*dqq.w;
        c2 = (th - snt)/(th2*th);
    }
    float J[9];
    {
        float dg = 1.0f - c2*th2;
        J[0]=dg + c2*wx*wx;      J[1]= c1*wz + c2*wx*wy;  J[2]=-c1*wy + c2*wx*wz;
        J[3]=-c1*wz + c2*wx*wy;  J[4]=dg + c2*wy*wy;      J[5]= c1*wx + c2*wy*wz;
        J[6]= c1*wy + c2*wx*wz;  J[7]=-c1*wx + c2*wy*wz;  J[8]=dg + c2*wz*wz;
    }
    float Rj[9]; quat2mat(qloc,Rj);
    float H[9]; mm_nn(Rj,J,H);
    const float gs = GCOV*d*d;
    float Gp[9];
    Gp[0]=gs*(H[0]*H[0]+H[1]*H[1]+H[2]*H[2]);
    Gp[1]=gs*(H[0]*H[3]+H[1]*H[4]+H[2]*H[5]);
    Gp[2]=gs*(H[0]*H[6]+H[1]*H[7]+H[2]*H[8]);
    Gp[4]=gs*(H[3]*H[3]+H[4]*H[4]+H[5]*H[5]);
    Gp[5]=gs*(H[3]*H[6]+H[4]*H[7]+H[5]*H[8]);
    Gp[8]=gs*(H[6]*H[6]+H[7]*H[7]+H[8]*H[8]);
    Gp[3]=Gp[1]; Gp[6]=Gp[2]; Gp[7]=Gp[5];

    const float av  = ACOV*d*d;
    const float bv  = 0.5f*ACOV*d*d*d;
    const float cv  = 0.25f*ACOV*d*d*d*d;
    const float vpd = av*tau + bv;
    const float ppd = av*tau*tau + 2.0f*bv*tau + cv;

    // core blocks
    float Crv[9], Crp[9], Cvv[9], Cvp[9], Cpp[9];
    m_skew(Gp, mp0,mp1,mp2, Crv);          // G' skew(m-psi)
    m_skew(Gp, np0,np1,np2, Crp);          // G' skew(n-psi)
    skew_m(-mp0,-mp1,-mp2, Crv, Cvv);      // skew(-m) G' skew(m)
    skew_m(-mp0,-mp1,-mp2, Crp, Cvp);
    skew_m(-np0,-np1,-np2, Crp, Cpp);

    float S45[45];
#pragma unroll
    for (int i=0;i<9;i++){ S45[i]=Crv[i]; S45[9+i]=Crp[i]; S45[18+i]=Cvp[i]; }
    S45[18]+=vpd; S45[22]+=vpd; S45[26]+=vpd;
    S45[27]=Gp[0];  S45[28]=Gp[1];  S45[29]=Gp[2];  S45[30]=Gp[4];  S45[31]=Gp[5];  S45[32]=Gp[8];
    S45[33]=Cvv[0]+av; S45[34]=Cvv[1]; S45[35]=Cvv[2]; S45[36]=Cvv[4]+av; S45[37]=Cvv[5]; S45[38]=Cvv[8]+av;
    S45[39]=Cpp[0]+ppd; S45[40]=Cpp[1]; S45[41]=Cpp[2]; S45[42]=Cpp[4]+ppd; S45[43]=Cpp[5]; S45[44]=Cpp[8]+ppd;

    // per-wave LDS transpose reduction over lanes, two rounds (23 + 22 elems)
#pragma unroll
    for (int e=0;e<23;e++) red[wid][e][lane] = S45[e];
    __syncthreads();
    float r1 = 0.f;
    if (lane < 23) {
        const float* row = &red[wid][lane][0];
        float ax=0.f, ay=0.f;
#pragma unroll
        for (int i=0;i<32;i++) {
            float2 v = reinterpret_cast<const float2*>(row)[i];
            ax += v.x; ay += v.y;
        }
        r1 = ax + ay;
    }
    __syncthreads();
#pragma unroll
    for (int e=0;e<22;e++) red[wid][e][lane] = S45[23+e];
    __syncthreads();
    float r2 = 0.f;
    if (lane < 22) {
        const float* row = &red[wid][lane][0];
        float ax=0.f, ay=0.f;
#pragma unroll
        for (int i=0;i<32;i++) {
            float2 v = reinterpret_cast<const float2*>(row)[i];
            ax += v.x; ay += v.y;
        }
        r2 = ax + ay;
    }
    if (lane < 23) cov[wsbase+lane] = r1;
    if (lane < 22) cov[wsbase+23+lane] = r2;
}

// ---------------------------------------------------------------------------
// K4 combine math (compact layout). Phi[0..27]=D,P,Q,T.
// S (45): Arv0 Arp9 Avp18 Arr27t Avv33t App39t.
// ---------------------------------------------------------------------------
__device__ __forceinline__ void congr45(const float* Phi, const float* S, float* O)
{
    const float* D=Phi; const float* P=Phi+9; const float* Q=Phi+18; const float T=Phi[27];
    const float* Arv=S+0; const float* Arp=S+9; const float* Avp=S+18;
    float Arr[9], Avv[9], App[9];
    expand_sym(S+27,Arr); expand_sym(S+33,Avv); expand_sym(S+39,App);

    float M1[9], M2[9], M3[9], t1[9], t6[6];
    mm_nn(D,Arr,M1); mm_nn(D,Arv,M2); mm_nn(D,Arp,M3);
    mm_nt_sym(M1, D, O+27);                          // O_rr (tri)
    mm_nt(M1, P, t1);
#pragma unroll
    for (int i=0;i<9;i++) O[0+i] = t1[i] + M2[i];    // O_rv
    mm_nt(M1, Q, t1);
#pragma unroll
    for (int i=0;i<9;i++) O[9+i] = t1[i] + T*M2[i] + M3[i];  // O_rp

    float W1[9], W2[9], W3[9];
    mm_nn(P, Arr, W1);
#pragma unroll
    for (int i=0;i<3;i++)
#pragma unroll
    for (int j=0;j<3;j++) W1[3*i+j] += Arv[3*j+i];
    mm_nn(P, Arv, W2);
#pragma unroll
    for (int i=0;i<9;i++) W2[i] += Avv[i];
    mm_nn(P, Arp, W3);
#pragma unroll
    for (int i=0;i<9;i++) W3[i] += Avp[i];
    mm_nt_sym(W1, P, t6);                            // O_vv (tri)
    O[33+0]=t6[0]+W2[0]; O[33+1]=t6[1]+W2[1]; O[33+2]=t6[2]+W2[2];
    O[33+3]=t6[3]+W2[4]; O[33+4]=t6[4]+W2[5]; O[33+5]=t6[5]+W2[8];
    mm_nt(W1, Q, t1);
#pragma unroll
    for (int i=0;i<9;i++) O[18+i] = t1[i] + T*W2[i] + W3[i];  // O_vp

    float U1[9], U2[9], U3[9];
    mm_nn(Q, Arr, U1);
#pragma unroll
    for (int i=0;i<3;i++)
#pragma unroll
    for (int j=0;j<3;j++) U1[3*i+j] += T*Arv[3*j+i] + Arp[3*j+i];
    mm_nn(Q, Arv, U2);
#pragma unroll
    for (int i=0;i<3;i++)
#pragma unroll
    for (int j=0;j<3;j++) U2[3*i+j] += T*Avv[3*i+j] + Avp[3*j+i];
    mm_nn(Q, Arp, U3);
#pragma unroll
    for (int i=0;i<9;i++) U3[i] += T*Avp[i] + App[i];
    mm_nt_sym(U1, Q, t6);                            // O_pp (tri)
    O[39+0]=t6[0]+T*U2[0]+U3[0]; O[39+1]=t6[1]+T*U2[1]+U3[1]; O[39+2]=t6[2]+T*U2[2]+U3[2];
    O[39+3]=t6[3]+T*U2[4]+U3[4]; O[39+4]=t6[4]+T*U2[5]+U3[5]; O[39+5]=t6[5]+T*U2[8]+U3[8];
}

// ---------------------------------------------------------------------------
// D (merged): blocks 0..31 covcomb (direct-global, no LDS staging);
//             blocks 32..1055 emit w/ inline V/Pp.
// ---------------------------------------------------------------------------
__global__ __launch_bounds__(256) void k_merged(
    const float* __restrict__ dt, const float* __restrict__ pos0,
    const float* __restrict__ vel0, const float* __restrict__ vp_g,
    const float* __restrict__ cov,
    float* __restrict__ outv, float* __restrict__ outp, float* __restrict__ outc)
{
    __shared__ float sc[NCH][13];    //  6,656 B published suffix params (stride 13: conflict-free)
    __shared__ float hand[12];       //  cross-wave handoff
    __shared__ float wsum[2][45];    //  wave partial sums
    const int bid=blockIdx.x;
    const int tid=threadIdx.x, lane=tid&63, wid=tid>>6;

    if (bid < BB) {
        const int b = bid;
        const bool own = tid < NCH;              // wave-uniform: waves 0,1
        const float* g = cov + (long)b*NCH*SLOT + (long)tid*SLOT;

        // chunk params direct from global (L2-hot); save qt/qp for later
        float qt0=0.f,qt1=0.f,qt2=0.f,qt3=1.f, qp0=0.f,qp1=0.f,qp2=0.f,qp3=1.f;
        float q0,q1,q2,q3, Mv0,Mv1,Mv2, Nv0,Nv1,Nv2, Tv;
        if (own) {
            qt0=g[45]; qt1=g[46]; qt2=g[47]; qt3=g[48];
            qp0=g[49]; qp1=g[50]; qp2=g[51]; qp3=g[52];
            Mv0=g[53]; Mv1=g[54]; Mv2=g[55];
            Nv0=g[56]; Nv1=g[57]; Nv2=g[58];
            Tv=g[59];
            q0=qt0; q1=qt1; q2=qt2; q3=qt3;
        } else { q0=q1=q2=0.f; q3=1.f; Mv0=Mv1=Mv2=Nv0=Nv1=Nv2=0.f; Tv=0.f; }

        if (own) {
            // in-wave register suffix scan of factored (q,M,N,T)
#pragma unroll
            for (int s=1;s<64;s<<=1) {
                float a0=__shfl_down(q0,s), a1=__shfl_down(q1,s), a2=__shfl_down(q2,s), a3=__shfl_down(q3,s);
                float am0=__shfl_down(Mv0,s), am1=__shfl_down(Mv1,s), am2=__shfl_down(Mv2,s);
                float an0=__shfl_down(Nv0,s), an1=__shfl_down(Nv1,s), an2=__shfl_down(Nv2,s);
                float aT=__shfl_down(Tv,s);
                if (lane+s < 64) {
                    Quat qb; qb.x=q0; qb.y=q1; qb.z=q2; qb.w=q3;
                    Quat qa; qa.x=a0; qa.y=a1; qa.z=a2; qa.w=a3;
                    Quat qc=qmul(qb,qa);
                    float Rb[9]; quat2mat(qb,Rb);
                    float Mc0=Mv0+Rb[0]*am0+Rb[1]*am1+Rb[2]*am2;
                    float Mc1=Mv1+Rb[3]*am0+Rb[4]*am1+Rb[5]*am2;
                    float Mc2=Mv2+Rb[6]*am0+Rb[7]*am1+Rb[8]*am2;
                    float Nc0=Nv0+Rb[0]*an0+Rb[1]*an1+Rb[2]*an2+aT*Mv0;
                    float Nc1=Nv1+Rb[3]*an0+Rb[4]*an1+Rb[5]*an2+aT*Mv1;
                    float Nc2=Nv2+Rb[6]*an0+Rb[7]*an1+Rb[8]*an2+aT*Mv2;
                    q0=qc.x; q1=qc.y; q2=qc.z; q3=qc.w;
                    Mv0=Mc0; Mv1=Mc1; Mv2=Mc2;
                    Nv0=Nc0; Nv1=Nc1; Nv2=Nc2;
                    Tv+=aT;
                }
            }
            if (wid==1 && lane==0) {
                hand[0]=q0; hand[1]=q1; hand[2]=q2; hand[3]=q3;
                hand[4]=Mv0; hand[5]=Mv1; hand[6]=Mv2;
                hand[7]=Nv0; hand[8]=Nv1; hand[9]=Nv2;
                hand[10]=Tv;
            }
        }
        __syncthreads();
        if (own && wid==0) {
            Quat qb; qb.x=q0; qb.y=q1; qb.z=q2; qb.w=q3;
            Quat qa; qa.x=hand[0]; qa.y=hand[1]; qa.z=hand[2]; qa.w=hand[3];
            float am0=hand[4],am1=hand[5],am2=hand[6];
            float an0=hand[7],an1=hand[8],an2=hand[9];
            float aT=hand[10];
            Quat qc=qmul(qb,qa);
            float Rb[9]; quat2mat(qb,Rb);
            float Mc0=Mv0+Rb[0]*am0+Rb[1]*am1+Rb[2]*am2;
            float Mc1=Mv1+Rb[3]*am0+Rb[4]*am1+Rb[5]*am2;
            float Mc2=Mv2+Rb[6]*am0+Rb[7]*am1+Rb[8]*am2;
            float Nc0=Nv0+Rb[0]*an0+Rb[1]*an1+Rb[2]*an2+aT*Mv0;
            float Nc1=Nv1+Rb[3]*an0+Rb[4]*an1+Rb[5]*an2+aT*Mv1;
            float Nc2=Nv2+Rb[6]*an0+Rb[7]*an1+Rb[8]*an2+aT*Mv2;
            q0=qc.x; q1=qc.y; q2=qc.z; q3=qc.w;
            Mv0=Mc0; Mv1=Mc1; Mv2=Mc2;
            Nv0=Nc0; Nv1=Nc1; Nv2=Nc2;
            Tv+=aT;
        }
        if (own) {
            sc[tid][0]=q0; sc[tid][1]=q1; sc[tid][2]=q2; sc[tid][3]=q3;
            sc[tid][4]=Mv0; sc[tid][5]=Mv1; sc[tid][6]=Mv2;
            sc[tid][7]=Nv0; sc[tid][8]=Nv1; sc[tid][9]=Nv2;
            sc[tid][10]=Tv;
        }
        __syncthreads();

        float O[45];
        if (own) {
            Quat qt; qt.x=qt0; qt.y=qt1; qt.z=qt2; qt.w=qt3;
            Quat qp; qp.x=qp0; qp.y=qp1; qp.z=qp2; qp.w=qp3;

            float Phi[28];
            if (tid < NCH-1) {
                Quat qs; qs.x=sc[tid+1][0]; qs.y=sc[tid+1][1]; qs.z=sc[tid+1][2]; qs.w=sc[tid+1][3];
                float Ms0=sc[tid+1][4], Ms1=sc[tid+1][5], Ms2=sc[tid+1][6];
                float Ns0=sc[tid+1][7], Ns1=sc[tid+1][8], Ns2=sc[tid+1][9];
                float Ts=sc[tid+1][10];
                float Rs[9]; quat2mat(qs,Rs);
                Phi[0]=Rs[0]; Phi[1]=Rs[3]; Phi[2]=Rs[6];
                Phi[3]=Rs[1]; Phi[4]=Rs[4]; Phi[5]=Rs[7];
                Phi[6]=Rs[2]; Phi[7]=Rs[5]; Phi[8]=Rs[8];
                Quat qp1=qmul(qp,qt);                 // qpre of chunk tid+1
                float Rp1[9]; quat2mat(qp1,Rp1);
                float Pc[9]; m_skew(Rp1, -Ms0,-Ms1,-Ms2, Pc);
                float Qc[9]; m_skew(Rp1, -Ns0,-Ns1,-Ns2, Qc);
#pragma unroll
                for (int i=0;i<9;i++){ Phi[9+i]=Pc[i]; Phi[18+i]=Qc[i]; }
                Phi[27]=Ts;
            } else {
#pragma unroll
                for (int i=0;i<9;i++){ Phi[i]=(i%4==0)?1.f:0.f; Phi[9+i]=0.f; Phi[18+i]=0.f; }
                Phi[27]=0.f;
            }

            float Rt[9]; quat2mat(qt,Rt);
            float Rp[9]; quat2mat(qp,Rp);
            float S[45];
            {
                float Crv[9],Crp[9],Cvp9[9], e9[9], t9[9], o9[9], o6[6];
#pragma unroll
                for (int i=0;i<9;i++){ Crv[i]=g[i]; Crp[i]=g[9+i]; Cvp9[i]=g[18+i]; }
                mm_tn(Rt, Crv, t9); mm_nt(t9, Rp, o9);
#pragma unroll
                for (int i=0;i<9;i++) S[i]=o9[i];
                mm_tn(Rt, Crp, t9); mm_nt(t9, Rp, o9);
#pragma unroll
                for (int i=0;i<9;i++) S[9+i]=o9[i];
                mm_nn(Rp, Cvp9, t9); mm_nt(t9, Rp, o9);
#pragma unroll
                for (int i=0;i<9;i++) S[18+i]=o9[i];
                expand_sym(g+27, e9); mm_tn(Rt, e9, t9); mm_nn_sym(t9, Rt, o6);
#pragma unroll
                for (int i=0;i<6;i++) S[27+i]=o6[i];
                expand_sym(g+33, e9); mm_nn(Rp, e9, t9); mm_nt_sym(t9, Rp, o6);
#pragma unroll
                for (int i=0;i<6;i++) S[33+i]=o6[i];
                expand_sym(g+39, e9); mm_nn(Rp, e9, t9); mm_nt_sym(t9, Rp, o6);
#pragma unroll
                for (int i=0;i<6;i++) S[39+i]=o6[i];
            }
            congr45(Phi, S, O);

            // in-wave butterfly sum of O (64 chunks per wave)
#pragma unroll
            for (int m=1;m<64;m<<=1) {
#pragma unroll
                for (int i=0;i<45;i++) O[i] += __shfl_xor(O[i], m);
            }
            if (lane==0) {
#pragma unroll
                for (int i=0;i<45;i++) wsum[wid][i] = O[i];
            }
        }
        __syncthreads();

        if (tid < 81) {
            int i = tid/9, j = tid%9;
            int bi = i/3, ii = i%3, bj = j/3, jj = j%3;
            int lo = (ii<jj)?ii:jj, hi = (ii<jj)?jj:ii;
            int tix = (lo==0)?hi:((lo==1)?(2+hi):5);
            int x;
            if      (bi==0 && bj==0) x = 27 + tix;        // Arr
            else if (bi==0 && bj==1) x = 0  + 3*ii + jj;  // Arv
            else if (bi==0 && bj==2) x = 9  + 3*ii + jj;  // Arp
            else if (bi==1 && bj==0) x = 0  + 3*jj + ii;  // Arv^T
            else if (bi==1 && bj==1) x = 33 + tix;        // Avv
            else if (bi==1 && bj==2) x = 18 + 3*ii + jj;  // Avp
            else if (bi==2 && bj==0) x = 9  + 3*jj + ii;  // Arp^T
            else if (bi==2 && bj==1) x = 18 + 3*jj + ii;  // Avp^T
            else                     x = 39 + tix;        // App
            outc[(long)b*81 + tid] = wsum[0][x] + wsum[1][x];
        }
        return;
    }

    // ---- emit with inline V/Pp: lane handles batch chunks 2*lane, 2*lane+1 ----
    const int ebid = bid - BB;
    const int b = ebid>>5, wg = ebid&31;
    const int c = wg*4+wid;
    const long k = (long)b*FF+(long)c*64+lane;

    const float4* vpb = reinterpret_cast<const float4*>(vp_g + (long)b*NCH*8);
    float4 A0=vpb[4*lane+0], A1=vpb[4*lane+1];   // chunk e0=2*lane: Lv, Sw, Td
    float4 B0=vpb[4*lane+2], B1=vpb[4*lane+3];   // chunk e1=2*lane+1

    // pair scan of Lv -> V at e0/e1
    float pl0=A0.x+B0.x, pl1=A0.y+B0.y, pl2=A0.z+B0.z;
    float i0=pl0,i1=pl1,i2=pl2;
#pragma unroll
    for (int s=1;s<64;s<<=1) {
        float p0=__shfl_up(i0,s),p1=__shfl_up(i1,s),p2=__shfl_up(i2,s);
        if (lane>=s){ i0+=p0; i1+=p1; i2+=p2; }
    }
    float e0V0=i0-pl0, e0V1=i1-pl1, e0V2=i2-pl2;
    float e1V0=e0V0+A0.x, e1V1=e0V1+A0.y, e1V2=e0V2+A0.z;
    // u = V*Td + Sw per element; pair scan -> Pp at e0/e1
    float u00=e0V0*A1.z+A0.w, u01=e0V1*A1.z+A1.x, u02=e0V2*A1.z+A1.y;
    float u10=e1V0*B1.z+B0.w, u11=e1V1*B1.z+B1.x, u12=e1V2*B1.z+B1.y;
    float pu0=u00+u10, pu1=u01+u11, pu2=u02+u12;
    float j0=pu0,j1=pu1,j2=pu2;
#pragma unroll
    for (int s=1;s<64;s<<=1) {
        float p0=__shfl_up(j0,s),p1=__shfl_up(j1,s),p2=__shfl_up(j2,s);
        if (lane>=s){ j0+=p0; j1+=p1; j2+=p2; }
    }
    float e0P0=j0-pu0, e0P1=j1-pu1, e0P2=j2-pu2;
    float e1P0=e0P0+u00, e1P1=e0P1+u01, e1P2=e0P2+u02;

    // select own chunk's (V, Pp); c is wave-uniform
    const int srcl = c>>1;
    float sV0=(c&1)? e1V0:e0V0, sV1=(c&1)? e1V1:e0V1, sV2=(c&1)? e1V2:e0V2;
    float sP0=(c&1)? e1P0:e0P0, sP1=(c&1)? e1P1:e0P1, sP2=(c&1)? e1P2:e0P2;
    float V0=__shfl(sV0,srcl), V1=__shfl(sV1,srcl), V2=__shfl(sV2,srcl);
    float P0=__shfl(sP0,srcl), P1=__shfl(sP1,srcl), P2=__shfl(sP2,srcl);

    float td = dt[k];
#pragma unroll
    for (int s=1;s<64;s<<=1) {
        float p=__shfl_up(td,s);
        if (lane>=s) td+=p;
    }

    float v0x=vel0[3*b+0], v0y=vel0[3*b+1], v0z=vel0[3*b+2];
    float p0x=pos0[3*b+0], p0y=pos0[3*b+1], p0z=pos0[3*b+2];

    float pv0=outv[3*k+0], pv1=outv[3*k+1], pv2=outv[3*k+2];
    float pp0=outp[3*k+0], pp1=outp[3*k+1], pp2=outp[3*k+2];

    outv[3*k+0]=v0x+V0+pv0;
    outv[3*k+1]=v0y+V1+pv1;
    outv[3*k+2]=v0z+V2+pv2;
    outp[3*k+0]=p0x+P0+V0*td+pp0;
    outp[3*k+1]=p0y+P1+V1*td+pp1;
    outp[3*k+2]=p0z+P2+V2*td+pp2;
}

// ---------------------------------------------------------------------------
extern "C" void kernel_launch(void* const* d_in, const int* in_sizes, int n_in,
                              void* d_out, int out_size, void* d_ws, size_t ws_size,
                              hipStream_t stream)
{
    const float* dt   = (const float*)d_in[0];
    const float* gyro = (const float*)d_in[1];
    const float* acc  = (const float*)d_in[2];
    const float* pos0 = (const float*)d_in[3];
    const float* vel0 = (const float*)d_in[4];

    float* out  = (float*)d_out;
    float* outq = out;
    float* outv = out  + (long)BB*FF*4;
    float* outp = outv + (long)BB*FF*3;
    float* outc = outp + (long)BB*FF*3;

    float* ws   = (float*)d_ws;           // 1,310,720 bytes used
    float* cov  = ws + COV_OFF;
    float* qtot = ws + QTOT_OFF;
    float* qpre = ws + QPRE_OFF;
    float* vp   = ws + VP_OFF;

    hipLaunchKernelGGL(k_chunktot, dim3(BB*32),    dim3(256), 0, stream, dt, gyro, qtot, outq);
    hipLaunchKernelGGL(k_qpre,     dim3(BB),       dim3(128), 0, stream, qtot, qpre);
    hipLaunchKernelGGL(k_main,     dim3(BB*32),    dim3(256), 0, stream, dt, gyro, acc, qpre, outq, cov, vp, outv, outp);
    hipLaunchKernelGGL(k_merged,   dim3(BB*32+BB), dim3(256), 0, stream, dt, pos0, vel0, vp, cov, outv, outp, outc);
}